// Round 1
// 714.613 us; speedup vs baseline: 1.0515x; 1.0515x over previous
//
#include <hip/hip_runtime.h>
#include <math.h>

#define HID      2048
#define STATE    128
#define HEADS    64
#define HEADDIM  64
#define INTER    4096
#define CONV_DIM 4352
#define PROJ     8512
#define NBATCH   2
#define SEQ      2048
#define BS       (NBATCH*SEQ)   /* 4096 token rows */
#define EPS      1e-5f
#define YN_COL   4160           /* YN lives in PRJ cols [4160, 8256) after conv/dt are dead */

typedef __attribute__((ext_vector_type(8))) short short8;
typedef __attribute__((ext_vector_type(4))) float f32x4;

__device__ inline unsigned short f2bf(float f) {
  union { float f; unsigned int u; } v; v.f = f;
  unsigned int r = v.u + 0x7fffu + ((v.u >> 16) & 1u);   // RNE
  return (unsigned short)(r >> 16);
}
__device__ inline float bf2f(unsigned short b) {
  union { unsigned int u; float f; } v; v.u = ((unsigned int)b) << 16;
  return v.f;
}

// ---------------- f32 -> bf16 cast (weights) ----------------
__global__ __launch_bounds__(256)
void cast_bf16_kernel(const float4* __restrict__ src, ushort4* __restrict__ dst, int n4) {
  int i = blockIdx.x * 256 + threadIdx.x;
  if (i >= n4) return;
  float4 v = src[i];
  ushort4 o;
  o.x = f2bf(v.x); o.y = f2bf(v.y); o.z = f2bf(v.z); o.w = f2bf(v.w);
  dst[i] = o;
}

// ---------------- input RMSNorm -> bf16 ----------------
__global__ __launch_bounds__(256)
void rmsnorm_in_kernel(const float* __restrict__ x, const float* __restrict__ w,
                       unsigned short* __restrict__ xn) {
  int row = blockIdx.x;
  int t = threadIdx.x;
  const float* xr = x + (size_t)row * HID;
  float4 a = ((const float4*)xr)[t];
  float4 b = ((const float4*)xr)[t + 256];
  float ss = a.x*a.x + a.y*a.y + a.z*a.z + a.w*a.w
           + b.x*b.x + b.y*b.y + b.z*b.z + b.w*b.w;
  for (int o = 32; o > 0; o >>= 1) ss += __shfl_down(ss, o);
  __shared__ float red[4];
  __shared__ float scl;
  if ((t & 63) == 0) red[t >> 6] = ss;
  __syncthreads();
  if (t == 0) scl = rsqrtf((red[0]+red[1]+red[2]+red[3]) / (float)HID + EPS);
  __syncthreads();
  float s = scl;
  float4 w0 = ((const float4*)w)[t];
  float4 w1 = ((const float4*)w)[t + 256];
  ushort4 o0, o1;
  o0.x = f2bf(a.x*s*w0.x); o0.y = f2bf(a.y*s*w0.y); o0.z = f2bf(a.z*s*w0.z); o0.w = f2bf(a.w*s*w0.w);
  o1.x = f2bf(b.x*s*w1.x); o1.y = f2bf(b.y*s*w1.y); o1.z = f2bf(b.z*s*w1.z); o1.w = f2bf(b.w*s*w1.w);
  ushort4* dst = (ushort4*)(xn + (size_t)row * HID);
  dst[t] = o0;
  dst[t + 256] = o1;
}

// ---------------- 256x256 / BK=64 / 8-wave / 8-phase bf16 BT-GEMM ----------------
// C[M,N] = A[M,K] * B[N,K]^T.  Template: T1 (XCD swizzle) + T2 (8-slot XOR swizzle,
// 2-way=free) + T3/T4 (8 phases, 1 half-tile staged/phase, vmcnt(2) only at p3/p7)
// + T5 (setprio around MFMA cluster).  LDS 128 KiB double-buffered, 1 block/CU.

__device__ __forceinline__ void stage_half(const unsigned short* __restrict__ G, int ld,
                                           int row0, int rmax, int kt,
                                           unsigned short* lbase, int half, int t) {
  // half-tile = 128 rows x 64 cols bf16 = 16 KB = 1024 x 16B chunks; 2 loads/thread.
  // LDS linear; global source column-chunk pre-swizzled: chunk (rl, sl) <- col (sl ^ (rl&7)).
  const int w = t >> 6;
#pragma unroll
  for (int it = 0; it < 2; ++it) {
    int id = it * 512 + t;          // chunk id 0..1023
    int rl = id >> 3;               // local row 0..127
    int sl = id & 7;                // 16B slot 0..7
    int grow = row0 + half * 128 + rl;
    if (grow > rmax) grow = rmax;
    const unsigned short* g = G + (size_t)grow * ld + kt * 64 + ((sl ^ (rl & 7)) << 3);
    unsigned short* l = lbase + half * (128 * 64) + (it * 512 + w * 64) * 8;  // wave-uniform
    __builtin_amdgcn_global_load_lds((const __attribute__((address_space(1))) void*)g,
                                     (__attribute__((address_space(3))) void*)l, 16, 0, 0);
  }
}

#define VMW2 asm volatile("s_waitcnt vmcnt(2)" ::: "memory")

#define PHASE(BUF, MH, NH, RA, RB, STG, VMW_)                                        \
  {                                                                                  \
    const unsigned short* bufA = lds + (BUF)*32768;                                  \
    const unsigned short* bufB = lds + (BUF)*32768 + 16384;                          \
    if (RA) {                                                                        \
      _Pragma("unroll")                                                              \
      for (int mf = 0; mf < 4; ++mf) {                                               \
        _Pragma("unroll")                                                            \
        for (int kk = 0; kk < 2; ++kk) {                                             \
          const int r = wr*128 + (MH)*64 + mf*16 + tq;                               \
          aR[mf][kk] = *(const short8*)(bufA + r*64 + (((kk<<2)|quad)^(r&7))*8);     \
        }                                                                            \
      }                                                                              \
    }                                                                                \
    if (RB) {                                                                        \
      _Pragma("unroll")                                                              \
      for (int nf = 0; nf < 2; ++nf) {                                               \
        _Pragma("unroll")                                                            \
        for (int kk = 0; kk < 2; ++kk) {                                             \
          const int r = wc*64 + (NH)*32 + nf*16 + tq;                                \
          bR[NH][nf][kk] = *(const short8*)(bufB + r*64 + (((kk<<2)|quad)^(r&7))*8); \
        }                                                                            \
      }                                                                              \
    }                                                                                \
    STG;                                                                             \
    __builtin_amdgcn_s_barrier();                                                    \
    asm volatile("s_waitcnt lgkmcnt(0)" ::: "memory");                               \
    __builtin_amdgcn_sched_barrier(0);                                               \
    __builtin_amdgcn_s_setprio(1);                                                   \
    _Pragma("unroll")                                                                \
    for (int mf = 0; mf < 4; ++mf) {                                                 \
      _Pragma("unroll")                                                              \
      for (int nf = 0; nf < 2; ++nf) {                                               \
        _Pragma("unroll")                                                            \
        for (int kk = 0; kk < 2; ++kk) {                                             \
          acc[(MH)*4+mf][(NH)*2+nf] = __builtin_amdgcn_mfma_f32_16x16x32_bf16(       \
              aR[mf][kk], bR[NH][nf][kk], acc[(MH)*4+mf][(NH)*2+nf], 0, 0, 0);       \
        }                                                                            \
      }                                                                              \
    }                                                                                \
    __builtin_amdgcn_s_setprio(0);                                                   \
    VMW_;                                                                            \
    __builtin_amdgcn_s_barrier();                                                    \
  }

__global__ __launch_bounds__(512, 1)
void gemm256_kernel(const unsigned short* __restrict__ A, int lda,
                    const unsigned short* __restrict__ B,
                    float* __restrict__ Cf, unsigned short* __restrict__ Cb, int ldc,
                    int M, int N, int Kd, const float* __restrict__ residual) {
  __shared__ unsigned short lds[65536];   // 128 KiB: [buf][A|B][256][64]
  const int t = threadIdx.x;
  const int lane = t & 63;
  const int quad = lane >> 4;
  const int tq = lane & 15;
  const int w = t >> 6;
  const int wr = w >> 2;    // 2 M-waves x 4 N-waves; per-wave C = 128x64
  const int wc = w & 3;

  // T1: bijective XCD swizzle (nwg % 8 == 0 for both call sites)
  const int Mtiles = M >> 8;
  const int nwg = (int)gridDim.x;
  const int cpx = nwg >> 3;
  const int bid = (int)blockIdx.x;
  const int sw = (bid & 7) * cpx + (bid >> 3);
  const int m0 = (sw % Mtiles) << 8;
  const int n0 = (sw / Mtiles) << 8;

  f32x4 acc[8][4];
#pragma unroll
  for (int i = 0; i < 8; ++i)
#pragma unroll
    for (int j = 0; j < 4; ++j) acc[i][j] = (f32x4){0.f, 0.f, 0.f, 0.f};

  short8 aR[4][2];      // current MH quarter: 4 m-frags x 2 k-steps
  short8 bR[2][2][2];   // both NH halves kept live: [NH][nf][kk]

  unsigned short* A0 = lds;
  unsigned short* B0 = lds + 16384;
  unsigned short* A1 = lds + 32768;
  unsigned short* B1 = lds + 32768 + 16384;

  const int kIters = Kd >> 6;      // K-tiles of 64 (even for K=2048/4096)
  const int nIter  = kIters >> 1;

  // prologue: K-tile 0 fully + K-tile 1 half0 (mimics steady-state p7 stage)
  stage_half(A, lda, m0, M - 1, 0, A0, 0, t);
  stage_half(A, lda, m0, M - 1, 0, A0, 1, t);
  stage_half(B, Kd,  n0, N - 1, 0, B0, 0, t);
  stage_half(B, Kd,  n0, N - 1, 0, B0, 1, t);
  stage_half(A, lda, m0, M - 1, 1, A1, 0, t);
  VMW2;                              // K0's 8 loads done; K1h0 may stay in flight
  __builtin_amdgcn_s_barrier();

  for (int i = 0; i < nIter; ++i) {
    const int k1 = 2 * i + 1;
    int k2 = 2 * i + 2; if (k2 > kIters - 1) k2 = kIters - 1;   // tail: harmless re-stage
    int k3 = 2 * i + 3; if (k3 > kIters - 1) k3 = kIters - 1;
    // phases 0-3: compute K-tile 2i (buf0); finish staging K1(buf1), start K2(buf0)
    PHASE(0, 0, 0, 1, 1, stage_half(A, lda, m0, M - 1, k1, A1, 1, t), ((void)0))
    PHASE(0, 0, 1, 0, 1, stage_half(B, Kd,  n0, N - 1, k1, B1, 0, t), ((void)0))
    PHASE(0, 1, 1, 1, 0, stage_half(B, Kd,  n0, N - 1, k1, B1, 1, t), ((void)0))
    PHASE(0, 1, 0, 0, 0, stage_half(A, lda, m0, M - 1, k2, A0, 0, t), VMW2)
    // phases 4-7: compute K-tile 2i+1 (buf1); finish K2(buf0), start K3(buf1)
    PHASE(1, 0, 0, 1, 1, stage_half(A, lda, m0, M - 1, k2, A0, 1, t), ((void)0))
    PHASE(1, 0, 1, 0, 1, stage_half(B, Kd,  n0, N - 1, k2, B0, 0, t), ((void)0))
    PHASE(1, 1, 1, 1, 0, stage_half(B, Kd,  n0, N - 1, k2, B0, 1, t), ((void)0))
    PHASE(1, 1, 0, 0, 0, stage_half(A, lda, m0, M - 1, k3, A1, 0, t), VMW2)
  }
  asm volatile("s_waitcnt vmcnt(0)" ::: "memory");   // drain LDS-DMA before exit

#pragma unroll
  for (int mfg = 0; mfg < 8; ++mfg) {
    const int rowb = m0 + wr * 128 + mfg * 16 + quad * 4;
#pragma unroll
    for (int nfg = 0; nfg < 4; ++nfg) {
      const int col = n0 + wc * 64 + nfg * 16 + tq;
      if (col < N) {
        if (Cb) {
#pragma unroll
          for (int r = 0; r < 4; ++r)
            Cb[(size_t)(rowb + r) * ldc + col] = f2bf(acc[mfg][nfg][r]);
        } else {
#pragma unroll
          for (int r = 0; r < 4; ++r) {
            size_t idx = (size_t)(rowb + r) * N + col;
            float v = acc[mfg][nfg][r];
            if (residual) v += residual[idx];
            Cf[idx] = v;
          }
        }
      }
    }
  }
}

// ---------------- fused causal conv(K=4)+SiLU and dt=softplus ----------------
__global__ __launch_bounds__(256)
void conv_dt_kernel(const unsigned short* __restrict__ proj, const float* __restrict__ cw,
                    const float* __restrict__ cb, const float* __restrict__ dtb,
                    const float* __restrict__ A_log,
                    unsigned short* __restrict__ convo, float2* __restrict__ dts) {
  int idx = blockIdx.x * 256 + threadIdx.x;
  if (idx < BS * CONV_DIM) {
    int c  = idx % CONV_DIM;
    int rs = idx / CONV_DIM;
    int s  = rs & (SEQ - 1);
    const unsigned short* col = proj + (size_t)rs * PROJ + INTER + c;
    float acc = cb[c];
#pragma unroll
    for (int k = 0; k < 4; k++) {
      int sp = s - 3 + k;
      if (sp >= 0) acc += bf2f(col[(ptrdiff_t)(k - 3) * PROJ]) * cw[c * 4 + k];
    }
    convo[idx] = f2bf(acc / (1.f + expf(-acc)));   // SiLU
  } else {
    int k = idx - BS * CONV_DIM;
    if (k < BS * HEADS) {
      int h  = k & 63;
      int rs = k >> 6;
      float x = bf2f(proj[(size_t)rs * PROJ + INTER + CONV_DIM + h]) + dtb[h];
      float dt = (x > 20.f) ? x : log1pf(expf(x));
      float Ah = -expf(A_log[h]);
      dts[k] = make_float2(dt, dt * Ah);   // {dt, log-decay increment}
    }
  }
}

// ---------------- SSD chunked scan (MFMA), 8 waves: Y-path || S-path ----------------
// Block = (b, h, p-half): 256 blocks, 512 threads.
// Waves 0-3 (Y): G=C*B^T -> Ms (masked decay) -> Y = Pex*(C*Sb^T) + Ms*x^T
// Waves 4-7 (S): ax = (x^T weighted by exp(tot-cum)*dt) in regs -> S = Ptot*S + ax*Btt
// Sb double-buffered; cumsum distributed per-wave via shuffles (no extra barrier).
// 2 barriers per chunk.
#define LCH 64
#define CST 136   /* row stride (shorts) for Cst/Bst/Sb */
#define TST 72    /* row stride (shorts) for Btt/xtT/Msh */

__global__ __launch_bounds__(512)
void ssd_scan_kernel(const unsigned short* __restrict__ convo, const float2* __restrict__ dts,
                     unsigned short* __restrict__ yp) {
  __shared__ unsigned short Cst[64 * CST];
  __shared__ unsigned short Bst[64 * CST];
  __shared__ unsigned short Btt[128 * TST];   // B transposed [n][j]
  __shared__ unsigned short xtT[32 * TST];    // x transposed [p_local][j]
  __shared__ unsigned short Msh[64 * TST];    // masked decay-weighted G [i][j]
  __shared__ unsigned short Sb[2][32 * CST];  // state bf16 [p_local][n], double-buffered
  __shared__ float dtaL[64], dtvL[64];

  const int ph = blockIdx.x & 1;
  const int h  = (blockIdx.x >> 1) & 63;
  const int b  = blockIdx.x >> 7;
  const int t  = threadIdx.x;
  const int wv = t >> 6;
  const int lane = t & 63;
  const int quad = lane >> 4;
  const int tq   = lane & 15;
  const size_t row0 = (size_t)b * SEQ;
  const int xcol = h * 64 + ph * 32;

  for (int i = t; i < 32 * CST; i += 512) Sb[0][i] = 0;

  // S-wave (wv>=4) persistent state accumulators
  f32x4 s_acc[4];
#pragma unroll
  for (int c = 0; c < 4; c++) s_acc[c] = (f32x4){0.f, 0.f, 0.f, 0.f};
  const int pt  = wv & 1;               // S-wave p-tile (0/1)
  const int ntb = ((wv >> 1) & 1) * 4;  // S-wave n-tile base (x16)

  int pp = 0;
  for (int c0 = 0; c0 < SEQ; c0 += LCH, pp ^= 1) {
    __syncthreads();   // B0: prior chunk's compute reads done before restaging
    // ---- stage B, C (natural), B^T, x^T, dt ----
#pragma unroll
    for (int it = 0; it < 2; ++it) {
      int id = t + 512 * it;           // [0,1024): row 0..63, cc 0..15
      int row = id >> 4, cc = id & 15;
      size_t g = (row0 + c0 + row) * CONV_DIM + INTER;
      short8 vb = *(const short8*)&convo[g + cc * 8];
      short8 vc = *(const short8*)&convo[g + STATE + cc * 8];
      *(short8*)&Bst[row * CST + cc * 8] = vb;
      *(short8*)&Cst[row * CST + cc * 8] = vc;
#pragma unroll
      for (int e = 0; e < 8; e++)
        Btt[(cc * 8 + e) * TST + row] = (unsigned short)vb[e];
    }
    {
      int row = t >> 3, c = t & 7;     // 64 rows x 8 chunks of 4
      ushort4 vx = *(const ushort4*)&convo[(row0 + c0 + row) * CONV_DIM + xcol + c * 4];
      xtT[(c * 4 + 0) * TST + row] = vx.x;
      xtT[(c * 4 + 1) * TST + row] = vx.y;
      xtT[(c * 4 + 2) * TST + row] = vx.z;
      xtT[(c * 4 + 3) * TST + row] = vx.w;
    }
    if (t < 64) {
      float2 dv = dts[((row0 + c0 + t) << 6) + h];
      dtvL[t] = dv.x; dtaL[t] = dv.y;
    }
    __syncthreads();   // S1: staging visible

    // ---- per-wave cumulative log-decay scan (lane l holds cum[l]) ----
    float v = dtaL[lane];
#pragma unroll
    for (int off = 1; off < 64; off <<= 1) {
      float u = __shfl_up(v, off);
      if (lane >= off) v += u;
    }
    float tot = __shfl(v, 63);

    if (wv < 4) {
      // ================= Y-path =================
      short8 afC[4];
#pragma unroll
      for (int kt = 0; kt < 4; kt++)
        afC[kt] = *(const short8*)&Cst[(16 * wv + tq) * CST + kt * 32 + quad * 8];
      f32x4 g_acc[4];
#pragma unroll
      for (int nj = 0; nj < 4; nj++) g_acc[nj] = (f32x4){0.f, 0.f, 0.f, 0.f};
#pragma unroll
      for (int kt = 0; kt < 4; kt++) {
#pragma unroll
        for (int nj = 0; nj < 4; nj++) {
          short8 bfr = *(const short8*)&Bst[(16 * nj + tq) * CST + kt * 32 + quad * 8];
          g_acc[nj] = __builtin_amdgcn_mfma_f32_16x16x32_bf16(afC[kt], bfr, g_acc[nj], 0, 0, 0);
        }
      }
      float ci[4], pex[4];
#pragma unroll
      for (int r = 0; r < 4; r++) {
        ci[r] = __shfl(v, 16 * wv + quad * 4 + r);
        pex[r] = expf(ci[r]);
      }
#pragma unroll
      for (int nj = 0; nj < 4; nj++) {
        int j = 16 * nj + tq;
        float cj = __shfl(v, j);
        float dj = dtvL[j];
#pragma unroll
        for (int r = 0; r < 4; r++) {
          int i = 16 * wv + quad * 4 + r;
          float val = (j <= i) ? g_acc[nj][r] * expf(ci[r] - cj) * dj : 0.f;
          Msh[i * TST + j] = f2bf(val);
        }
      }
      // Y = Pex*(C*Sb^T) + Ms*x^T
      f32x4 yac[2];
      yac[0] = (f32x4){0.f, 0.f, 0.f, 0.f};
      yac[1] = (f32x4){0.f, 0.f, 0.f, 0.f};
#pragma unroll
      for (int kt = 0; kt < 4; kt++) {
#pragma unroll
        for (int np = 0; np < 2; np++) {
          short8 bs = *(const short8*)&Sb[pp][(16 * np + tq) * CST + kt * 32 + quad * 8];
          yac[np] = __builtin_amdgcn_mfma_f32_16x16x32_bf16(afC[kt], bs, yac[np], 0, 0, 0);
        }
      }
#pragma unroll
      for (int np = 0; np < 2; np++)
#pragma unroll
        for (int r = 0; r < 4; r++) yac[np][r] *= pex[r];
#pragma unroll
      for (int kt2 = 0; kt2 < 2; kt2++) {
        short8 am = *(const short8*)&Msh[(16 * wv + tq) * TST + kt2 * 32 + quad * 8];
#pragma unroll
        for (int np = 0; np < 2; np++) {
          short8 bx = *(const short8*)&xtT[(16 * np + tq) * TST + kt2 * 32 + quad * 8];
          yac[np] = __builtin_amdgcn_mfma_f32_16x16x32_bf16(am, bx, yac[np], 0, 0, 0);
        }
      }
#pragma unroll
      for (int np = 0; np < 2; np++) {
#pragma unroll
        for (int r = 0; r < 4; r++) {
          int i = 16 * wv + quad * 4 + r;
          int p = ph * 32 + 16 * np + tq;
          yp[(row0 + c0 + i) * INTER + h * 64 + p] = f2bf(yac[np][r]);
        }
      }
    } else {
      // ================= S-path =================
      float ptot = expf(tot);
      short8 ax[2];
#pragma unroll
      for (int kt2 = 0; kt2 < 2; kt2++) {
        short8 xv = *(const short8*)&xtT[(16 * pt + tq) * TST + kt2 * 32 + quad * 8];
#pragma unroll
        for (int e = 0; e < 8; e++) {
          int j = kt2 * 32 + quad * 8 + e;
          float cj = __shfl(v, j);
          float wj = expf(tot - cj) * dtvL[j];
          ax[kt2][e] = (short)f2bf(bf2f((unsigned short)xv[e]) * wj);
        }
      }
#pragma unroll
      for (int c = 0; c < 4; c++)
#pragma unroll
        for (int r = 0; r < 4; r++) s_acc[c][r] *= ptot;
#pragma unroll
      for (int kt2 = 0; kt2 < 2; kt2++) {
#pragma unroll
        for (int c = 0; c < 4; c++) {
          short8 bb = *(const short8*)&Btt[(16 * (ntb + c) + tq) * TST + kt2 * 32 + quad * 8];
          s_acc[c] = __builtin_amdgcn_mfma_f32_16x16x32_bf16(ax[kt2], bb, s_acc[c], 0, 0, 0);
        }
      }
#pragma unroll
      for (int c = 0; c < 4; c++)
#pragma unroll
        for (int r = 0; r < 4; r++) {
          int p = 16 * pt + quad * 4 + r;
          int n = 16 * (ntb + c) + tq;
          Sb[pp ^ 1][p * CST + n] = f2bf(s_acc[c][r]);
        }
    }
    // next chunk's B0 protects Sb[pp^1] writes before Y reads them
  }
}

// ---------------- y = yp + D*x; gated RMSNorm -> bf16 (registers, no LDS buf) ----------------
__global__ __launch_bounds__(256)
void gated_norm_kernel(const unsigned short* __restrict__ yp,
                       const unsigned short* __restrict__ convo, const unsigned short* __restrict__ proj,
                       const float* __restrict__ Dv, const float* __restrict__ gnw,
                       unsigned short* __restrict__ yn) {
  int row = blockIdx.x;
  int t = threadIdx.x;
  __shared__ float red[4];
  __shared__ float scl;
  size_t yo = (size_t)row * INTER;
  size_t co = (size_t)row * CONV_DIM;
  size_t po = (size_t)row * PROJ;
  float vv[16];
  float ss = 0.f;
#pragma unroll
  for (int c = 0; c < 4; c++) {
    int i = t * 4 + c * 1024;
    ushort4 y0 = *(const ushort4*)&yp[yo + i];
    ushort4 xs = *(const ushort4*)&convo[co + i];
    ushort4 g  = *(const ushort4*)&proj[po + i];
    float Dh = Dv[i >> 6];
    float yv[4] = { bf2f(y0.x) + Dh * bf2f(xs.x),
                    bf2f(y0.y) + Dh * bf2f(xs.y),
                    bf2f(y0.z) + Dh * bf2f(xs.z),
                    bf2f(y0.w) + Dh * bf2f(xs.w) };
    float gv[4] = { bf2f(g.x), bf2f(g.y), bf2f(g.z), bf2f(g.w) };
#pragma unroll
    for (int k = 0; k < 4; k++) {
      float val = yv[k] * (gv[k] / (1.f + expf(-gv[k])));
      vv[c * 4 + k] = val;
      ss += val * val;
    }
  }
  for (int o = 32; o > 0; o >>= 1) ss += __shfl_down(ss, o);
  if ((t & 63) == 0) red[t >> 6] = ss;
  __syncthreads();
  if (t == 0) scl = rsqrtf((red[0]+red[1]+red[2]+red[3]) / (float)INTER + EPS);
  __syncthreads();
  float s = scl;
#pragma unroll
  for (int c = 0; c < 4; c++) {
    int i = t * 4 + c * 1024;
    ushort4 o;
    o.x = f2bf(vv[c*4+0] * s * gnw[i + 0]);
    o.y = f2bf(vv[c*4+1] * s * gnw[i + 1]);
    o.z = f2bf(vv[c*4+2] * s * gnw[i + 2]);
    o.w = f2bf(vv[c*4+3] * s * gnw[i + 3]);
    *(ushort4*)&yn[po + i] = o;
  }
}

// ---------------- launch ----------------
extern "C" void kernel_launch(void* const* d_in, const int* in_sizes, int n_in,
                              void* d_out, int out_size, void* d_ws, size_t ws_size,
                              hipStream_t stream) {
  const float* hidden  = (const float*)d_in[0];
  const float* norm_w  = (const float*)d_in[1];
  const float* w1      = (const float*)d_in[2];
  const float* convw   = (const float*)d_in[3];
  const float* convb   = (const float*)d_in[4];
  const float* dt_bias = (const float*)d_in[5];
  const float* A_log   = (const float*)d_in[6];
  const float* Dv      = (const float*)d_in[7];
  const float* gnw     = (const float*)d_in[8];
  const float* w2      = (const float*)d_in[9];
  float* out = (float*)d_out;

  char* ws = (char*)d_ws;
  size_t off = 0;
  auto alloc = [&](size_t bytes) {
    void* p = ws + off;
    off += (bytes + 255) & ~(size_t)255;
    return p;
  };
  unsigned short* XN  = (unsigned short*)alloc((size_t)BS * HID * 2);      // 16.8 MB
  unsigned short* W1B = (unsigned short*)alloc((size_t)PROJ * HID * 2);    // 34.9 MB
  unsigned short* W2B = (unsigned short*)alloc((size_t)HID * INTER * 2);   // 16.8 MB
  unsigned short* PRJ = (unsigned short*)alloc((size_t)BS * PROJ * 2);     // 69.7 MB
  unsigned short* CVO = (unsigned short*)alloc((size_t)BS * CONV_DIM * 2); // 35.7 MB
  float2*         DTS = (float2*)alloc((size_t)BS * HEADS * 8);            //  2.1 MB
  unsigned short* YP  = XN;                    // overlay: XN+W1B dead after GEMM1
  unsigned short* YN  = PRJ + YN_COL;          // in-row overlay, stride PROJ
  if (off > ws_size) return;
  (void)in_sizes; (void)n_in; (void)out_size;

  int n1 = PROJ * HID / 4;
  cast_bf16_kernel<<<(n1 + 255) / 256, 256, 0, stream>>>((const float4*)w1, (ushort4*)W1B, n1);
  int n2 = HID * INTER / 4;
  cast_bf16_kernel<<<(n2 + 255) / 256, 256, 0, stream>>>((const float4*)w2, (ushort4*)W2B, n2);

  rmsnorm_in_kernel<<<BS, 256, 0, stream>>>(hidden, norm_w, XN);

  // GEMM1: [4096 x 8512] = XN[4096 x 2048] * W1B^T ; 16 x 34 = 544 blocks (544 % 8 == 0)
  gemm256_kernel<<<dim3((BS / 256) * ((PROJ + 255) / 256)), 512, 0, stream>>>(
      XN, HID, W1B, nullptr, PRJ, PROJ, BS, PROJ, HID, nullptr);

  conv_dt_kernel<<<(BS * (CONV_DIM + HEADS) + 255) / 256, 256, 0, stream>>>(
      PRJ, convw, convb, dt_bias, A_log, CVO, DTS);

  ssd_scan_kernel<<<256, 512, 0, stream>>>(CVO, DTS, YP);

  gated_norm_kernel<<<BS, 256, 0, stream>>>(YP, CVO, PRJ, Dv, gnw, YN);

  // GEMM2: [4096 x 2048] = YN[4096 x 4096] * W2B^T + residual ; 16 x 8 = 128 blocks
  gemm256_kernel<<<dim3((BS / 256) * (HID / 256)), 512, 0, stream>>>(
      YN, PROJ, W2B, out, nullptr, HID, BS, HID, INTER, hidden);
}

// Round 2
// 712.908 us; speedup vs baseline: 1.0540x; 1.0024x over previous
//
#include <hip/hip_runtime.h>
#include <math.h>

#define HID      2048
#define STATE    128
#define HEADS    64
#define HEADDIM  64
#define INTER    4096
#define CONV_DIM 4352
#define PROJ     8512
#define NBATCH   2
#define SEQ      2048
#define BS       (NBATCH*SEQ)   /* 4096 token rows */
#define EPS      1e-5f
#define YN_COL   4160           /* YN lives in PRJ cols [4160, 8256) after conv/dt are dead */

typedef __attribute__((ext_vector_type(8))) short short8;
typedef __attribute__((ext_vector_type(4))) float f32x4;

__device__ inline unsigned short f2bf(float f) {
  union { float f; unsigned int u; } v; v.f = f;
  unsigned int r = v.u + 0x7fffu + ((v.u >> 16) & 1u);   // RNE
  return (unsigned short)(r >> 16);
}
__device__ inline float bf2f(unsigned short b) {
  union { unsigned int u; float f; } v; v.u = ((unsigned int)b) << 16;
  return v.f;
}

// ---------------- f32 -> bf16 cast (weights) ----------------
__global__ __launch_bounds__(256)
void cast_bf16_kernel(const float4* __restrict__ src, ushort4* __restrict__ dst, int n4) {
  int i = blockIdx.x * 256 + threadIdx.x;
  if (i >= n4) return;
  float4 v = src[i];
  ushort4 o;
  o.x = f2bf(v.x); o.y = f2bf(v.y); o.z = f2bf(v.z); o.w = f2bf(v.w);
  dst[i] = o;
}

// ---------------- input RMSNorm -> bf16 ----------------
__global__ __launch_bounds__(256)
void rmsnorm_in_kernel(const float* __restrict__ x, const float* __restrict__ w,
                       unsigned short* __restrict__ xn) {
  int row = blockIdx.x;
  int t = threadIdx.x;
  const float* xr = x + (size_t)row * HID;
  float4 a = ((const float4*)xr)[t];
  float4 b = ((const float4*)xr)[t + 256];
  float ss = a.x*a.x + a.y*a.y + a.z*a.z + a.w*a.w
           + b.x*b.x + b.y*b.y + b.z*b.z + b.w*b.w;
  for (int o = 32; o > 0; o >>= 1) ss += __shfl_down(ss, o);
  __shared__ float red[4];
  __shared__ float scl;
  if ((t & 63) == 0) red[t >> 6] = ss;
  __syncthreads();
  if (t == 0) scl = rsqrtf((red[0]+red[1]+red[2]+red[3]) / (float)HID + EPS);
  __syncthreads();
  float s = scl;
  float4 w0 = ((const float4*)w)[t];
  float4 w1 = ((const float4*)w)[t + 256];
  ushort4 o0, o1;
  o0.x = f2bf(a.x*s*w0.x); o0.y = f2bf(a.y*s*w0.y); o0.z = f2bf(a.z*s*w0.z); o0.w = f2bf(a.w*s*w0.w);
  o1.x = f2bf(b.x*s*w1.x); o1.y = f2bf(b.y*s*w1.y); o1.z = f2bf(b.z*s*w1.z); o1.w = f2bf(b.w*s*w1.w);
  ushort4* dst = (ushort4*)(xn + (size_t)row * HID);
  dst[t] = o0;
  dst[t + 256] = o1;
}

// ---------------- 256x128 / BK=64 / 8-wave / 8-phase bf16 BT-GEMM ----------------
// C[M,N] = A[M,K] * B[N,K]^T.  Same proven schedule (T1 XCD swizzle + T2 XOR swizzle +
// T3/T4 8 phases w/ vmcnt(2) at p3/p7 + T5 setprio), reshaped to BM=256 x BN=128 so
// grids pack evenly: GEMM1 16x67=1072 blocks (2.5 rounds vs 3), GEMM2 16x16=256 (1 round).
// LDS 96 KiB (A 32K + B 16K per buf, x2), 1 block/CU. 8 waves = 4M x 2N, per-wave C 64x64.
// Stages per K-tile: A-h0, A-h1, B (3); placed at phases {0,1,3 | 4,5,7} so each stage
// lands strictly after the last ds_read of the region it overwrites.

__device__ __forceinline__ void stage_half(const unsigned short* __restrict__ G, int ld,
                                           int row0, int rmax, int kt,
                                           unsigned short* lbase, int half, int t) {
  // half-tile = 128 rows x 64 cols bf16 = 16 KB = 1024 x 16B chunks; 2 loads/thread.
  // LDS linear; global source column-chunk pre-swizzled: chunk (rl, sl) <- col (sl ^ (rl&7)).
  const int w = t >> 6;
#pragma unroll
  for (int it = 0; it < 2; ++it) {
    int id = it * 512 + t;          // chunk id 0..1023
    int rl = id >> 3;               // local row 0..127
    int sl = id & 7;                // 16B slot 0..7
    int grow = row0 + half * 128 + rl;
    if (grow > rmax) grow = rmax;
    const unsigned short* g = G + (size_t)grow * ld + kt * 64 + ((sl ^ (rl & 7)) << 3);
    unsigned short* l = lbase + half * (128 * 64) + (it * 512 + w * 64) * 8;  // wave-uniform
    __builtin_amdgcn_global_load_lds((const __attribute__((address_space(1))) void*)g,
                                     (__attribute__((address_space(3))) void*)l, 16, 0, 0);
  }
}

#define VMW2 asm volatile("s_waitcnt vmcnt(2)" ::: "memory")

#define PHASE(BUF, MH, NH, RA, RB, STG, VMW_)                                        \
  {                                                                                  \
    const unsigned short* bufA = lds + (BUF)*24576;                                  \
    const unsigned short* bufB = lds + (BUF)*24576 + 16384;                          \
    if (RA) {                                                                        \
      _Pragma("unroll")                                                              \
      for (int ml = 0; ml < 2; ++ml) {                                               \
        _Pragma("unroll")                                                            \
        for (int kk = 0; kk < 2; ++kk) {                                             \
          const int r = wr*64 + (MH)*32 + ml*16 + tq;                                \
          aR[ml][kk] = *(const short8*)(bufA + r*64 + (((kk<<2)|quad)^(r&7))*8);     \
        }                                                                            \
      }                                                                              \
    }                                                                                \
    if (RB) {                                                                        \
      _Pragma("unroll")                                                              \
      for (int nl = 0; nl < 2; ++nl) {                                               \
        _Pragma("unroll")                                                            \
        for (int kk = 0; kk < 2; ++kk) {                                             \
          const int r = wc*64 + (NH)*32 + nl*16 + tq;                                \
          bR[NH][nl][kk] = *(const short8*)(bufB + r*64 + (((kk<<2)|quad)^(r&7))*8); \
        }                                                                            \
      }                                                                              \
    }                                                                                \
    STG;                                                                             \
    __builtin_amdgcn_s_barrier();                                                    \
    asm volatile("s_waitcnt lgkmcnt(0)" ::: "memory");                               \
    __builtin_amdgcn_sched_barrier(0);                                               \
    __builtin_amdgcn_s_setprio(1);                                                   \
    _Pragma("unroll")                                                                \
    for (int ml = 0; ml < 2; ++ml) {                                                 \
      _Pragma("unroll")                                                              \
      for (int nl = 0; nl < 2; ++nl) {                                               \
        _Pragma("unroll")                                                            \
        for (int kk = 0; kk < 2; ++kk) {                                             \
          acc[(MH)*2+ml][(NH)*2+nl] = __builtin_amdgcn_mfma_f32_16x16x32_bf16(       \
              aR[ml][kk], bR[NH][nl][kk], acc[(MH)*2+ml][(NH)*2+nl], 0, 0, 0);       \
        }                                                                            \
      }                                                                              \
    }                                                                                \
    __builtin_amdgcn_s_setprio(0);                                                   \
    VMW_;                                                                            \
    __builtin_amdgcn_s_barrier();                                                    \
  }

__global__ __launch_bounds__(512, 1)
void gemm128n_kernel(const unsigned short* __restrict__ A, int lda,
                     const unsigned short* __restrict__ B,
                     float* __restrict__ Cf, unsigned short* __restrict__ Cb, int ldc,
                     int M, int N, int Kd, const float* __restrict__ residual) {
  __shared__ unsigned short lds[49152];   // 96 KiB: [buf][A(256x64)|B(128x64)]
  const int t = threadIdx.x;
  const int lane = t & 63;
  const int quad = lane >> 4;
  const int tq = lane & 15;
  const int w = t >> 6;
  const int wr = w >> 1;    // 4 M-waves x 2 N-waves; per-wave C = 64x64
  const int wc = w & 1;

  // T1: bijective XCD swizzle (nwg % 8 == 0 for both call sites)
  const int Mtiles = M >> 8;
  const int nwg = (int)gridDim.x;
  const int cpx = nwg >> 3;
  const int bid = (int)blockIdx.x;
  const int sw = (bid & 7) * cpx + (bid >> 3);
  const int m0 = (sw % Mtiles) << 8;
  const int n0 = (sw / Mtiles) << 7;

  f32x4 acc[4][4];
#pragma unroll
  for (int i = 0; i < 4; ++i)
#pragma unroll
    for (int j = 0; j < 4; ++j) acc[i][j] = (f32x4){0.f, 0.f, 0.f, 0.f};

  short8 aR[2][2];      // current MH half: 2 m-frags x 2 k-steps
  short8 bR[2][2][2];   // both NH halves kept live: [NH][nl][kk]

  unsigned short* A0 = lds;
  unsigned short* B0 = lds + 16384;
  unsigned short* A1 = lds + 24576;
  unsigned short* B1 = lds + 24576 + 16384;

  const int kIters = Kd >> 6;      // K-tiles of 64 (even for K=2048/4096)
  const int nIter  = kIters >> 1;

  // prologue: K-tile 0 fully + K-tile 1 A-h0 (mirrors steady-state p7 stage)
  stage_half(A, lda, m0, M - 1, 0, A0, 0, t);
  stage_half(A, lda, m0, M - 1, 0, A0, 1, t);
  stage_half(B, Kd,  n0, N - 1, 0, B0, 0, t);
  stage_half(A, lda, m0, M - 1, 1, A1, 0, t);
  VMW2;                              // K0's 6 loads done; K1 A-h0 may stay in flight
  __builtin_amdgcn_s_barrier();

  for (int i = 0; i < nIter; ++i) {
    const int k1 = 2 * i + 1;
    int k2 = 2 * i + 2; if (k2 > kIters - 1) k2 = kIters - 1;   // tail: harmless re-stage
    int k3 = 2 * i + 3; if (k3 > kIters - 1) k3 = kIters - 1;
    // phases 0-3: compute K-tile 2i (buf0); finish staging K1(buf1), start K2(buf0)
    PHASE(0, 0, 0, 1, 1, stage_half(A, lda, m0, M - 1, k1, A1, 1, t), ((void)0))
    PHASE(0, 0, 1, 0, 1, stage_half(B, Kd,  n0, N - 1, k1, B1, 0, t), ((void)0))
    PHASE(0, 1, 1, 1, 0, ((void)0), ((void)0))
    PHASE(0, 1, 0, 0, 0, stage_half(A, lda, m0, M - 1, k2, A0, 0, t), VMW2)
    // phases 4-7: compute K-tile 2i+1 (buf1); finish K2(buf0), start K3(buf1)
    PHASE(1, 0, 0, 1, 1, stage_half(A, lda, m0, M - 1, k2, A0, 1, t), ((void)0))
    PHASE(1, 0, 1, 0, 1, stage_half(B, Kd,  n0, N - 1, k2, B0, 0, t), ((void)0))
    PHASE(1, 1, 1, 1, 0, ((void)0), ((void)0))
    PHASE(1, 1, 0, 0, 0, stage_half(A, lda, m0, M - 1, k3, A1, 0, t), VMW2)
  }
  asm volatile("s_waitcnt vmcnt(0)" ::: "memory");   // drain LDS-DMA before exit

#pragma unroll
  for (int mf = 0; mf < 4; ++mf) {
    const int rowb = m0 + wr * 64 + mf * 16 + quad * 4;
#pragma unroll
    for (int nf = 0; nf < 4; ++nf) {
      const int col = n0 + wc * 64 + nf * 16 + tq;
      if (col < N) {
        if (Cb) {
#pragma unroll
          for (int r = 0; r < 4; ++r)
            Cb[(size_t)(rowb + r) * ldc + col] = f2bf(acc[mf][nf][r]);
        } else {
#pragma unroll
          for (int r = 0; r < 4; ++r) {
            size_t idx = (size_t)(rowb + r) * N + col;
            float v = acc[mf][nf][r];
            if (residual) v += residual[idx];
            Cf[idx] = v;
          }
        }
      }
    }
  }
}

// ---------------- fused causal conv(K=4)+SiLU and dt=softplus ----------------
// Vectorized: 8 channels/thread, short8 loads/stores (G13).
__global__ __launch_bounds__(256)
void conv_dt_kernel(const unsigned short* __restrict__ proj, const float* __restrict__ cw,
                    const float* __restrict__ cb, const float* __restrict__ dtb,
                    const float* __restrict__ A_log,
                    unsigned short* __restrict__ convo, float2* __restrict__ dts) {
  const int NV = BS * (CONV_DIM / 8);
  int idx = blockIdx.x * 256 + threadIdx.x;
  if (idx < NV) {
    int c8 = idx % (CONV_DIM / 8);
    int rs = idx / (CONV_DIM / 8);
    int s  = rs & (SEQ - 1);
    int c0 = c8 * 8;
    const unsigned short* base = proj + (size_t)rs * PROJ + INTER + c0;
    float acc[8];
#pragma unroll
    for (int e = 0; e < 8; e++) acc[e] = cb[c0 + e];
#pragma unroll
    for (int k = 0; k < 4; k++) {
      int sp = s - 3 + k;
      if (sp >= 0) {
        short8 v = *(const short8*)(base + (ptrdiff_t)(k - 3) * PROJ);
#pragma unroll
        for (int e = 0; e < 8; e++)
          acc[e] += bf2f((unsigned short)v[e]) * cw[(c0 + e) * 4 + k];
      }
    }
    short8 o;
#pragma unroll
    for (int e = 0; e < 8; e++) {
      float a = acc[e];
      o[e] = (short)f2bf(a / (1.f + expf(-a)));   // SiLU
    }
    *(short8*)&convo[(size_t)rs * CONV_DIM + c0] = o;
  } else {
    int k = idx - NV;
    if (k < BS * HEADS) {
      int h  = k & 63;
      int rs = k >> 6;
      float x = bf2f(proj[(size_t)rs * PROJ + INTER + CONV_DIM + h]) + dtb[h];
      float dt = (x > 20.f) ? x : log1pf(expf(x));
      float Ah = -expf(A_log[h]);
      dts[k] = make_float2(dt, dt * Ah);   // {dt, log-decay increment}
    }
  }
}

// ---------------- SSD chunked scan (MFMA), 8 waves: Y-path || S-path ----------------
// Block = (b, h, p-half): 256 blocks, 512 threads.
// Waves 0-3 (Y): G=C*B^T -> Ms (masked decay) -> Y = Pex*(C*Sb^T) + Ms*x^T
// Waves 4-7 (S): ax = (x^T weighted by exp(tot-cum)*dt) in regs -> S = Ptot*S + ax*Btt
// Sb double-buffered; cumsum distributed per-wave via shuffles (no extra barrier).
// 2 barriers per chunk.
#define LCH 64
#define CST 136   /* row stride (shorts) for Cst/Bst/Sb */
#define TST 72    /* row stride (shorts) for Btt/xtT/Msh */

__global__ __launch_bounds__(512)
void ssd_scan_kernel(const unsigned short* __restrict__ convo, const float2* __restrict__ dts,
                     unsigned short* __restrict__ yp) {
  __shared__ unsigned short Cst[64 * CST];
  __shared__ unsigned short Bst[64 * CST];
  __shared__ unsigned short Btt[128 * TST];   // B transposed [n][j]
  __shared__ unsigned short xtT[32 * TST];    // x transposed [p_local][j]
  __shared__ unsigned short Msh[64 * TST];    // masked decay-weighted G [i][j]
  __shared__ unsigned short Sb[2][32 * CST];  // state bf16 [p_local][n], double-buffered
  __shared__ float dtaL[64], dtvL[64];

  const int ph = blockIdx.x & 1;
  const int h  = (blockIdx.x >> 1) & 63;
  const int b  = blockIdx.x >> 7;
  const int t  = threadIdx.x;
  const int wv = t >> 6;
  const int lane = t & 63;
  const int quad = lane >> 4;
  const int tq   = lane & 15;
  const size_t row0 = (size_t)b * SEQ;
  const int xcol = h * 64 + ph * 32;

  for (int i = t; i < 32 * CST; i += 512) Sb[0][i] = 0;

  // S-wave (wv>=4) persistent state accumulators
  f32x4 s_acc[4];
#pragma unroll
  for (int c = 0; c < 4; c++) s_acc[c] = (f32x4){0.f, 0.f, 0.f, 0.f};
  const int pt  = wv & 1;               // S-wave p-tile (0/1)
  const int ntb = ((wv >> 1) & 1) * 4;  // S-wave n-tile base (x16)

  int pp = 0;
  for (int c0 = 0; c0 < SEQ; c0 += LCH, pp ^= 1) {
    __syncthreads();   // B0: prior chunk's compute reads done before restaging
    // ---- stage B, C (natural), B^T, x^T, dt ----
#pragma unroll
    for (int it = 0; it < 2; ++it) {
      int id = t + 512 * it;           // [0,1024): row 0..63, cc 0..15
      int row = id >> 4, cc = id & 15;
      size_t g = (row0 + c0 + row) * CONV_DIM + INTER;
      short8 vb = *(const short8*)&convo[g + cc * 8];
      short8 vc = *(const short8*)&convo[g + STATE + cc * 8];
      *(short8*)&Bst[row * CST + cc * 8] = vb;
      *(short8*)&Cst[row * CST + cc * 8] = vc;
#pragma unroll
      for (int e = 0; e < 8; e++)
        Btt[(cc * 8 + e) * TST + row] = (unsigned short)vb[e];
    }
    {
      int row = t >> 3, c = t & 7;     // 64 rows x 8 chunks of 4
      ushort4 vx = *(const ushort4*)&convo[(row0 + c0 + row) * CONV_DIM + xcol + c * 4];
      xtT[(c * 4 + 0) * TST + row] = vx.x;
      xtT[(c * 4 + 1) * TST + row] = vx.y;
      xtT[(c * 4 + 2) * TST + row] = vx.z;
      xtT[(c * 4 + 3) * TST + row] = vx.w;
    }
    if (t < 64) {
      float2 dv = dts[((row0 + c0 + t) << 6) + h];
      dtvL[t] = dv.x; dtaL[t] = dv.y;
    }
    __syncthreads();   // S1: staging visible

    // ---- per-wave cumulative log-decay scan (lane l holds cum[l]) ----
    float v = dtaL[lane];
#pragma unroll
    for (int off = 1; off < 64; off <<= 1) {
      float u = __shfl_up(v, off);
      if (lane >= off) v += u;
    }
    float tot = __shfl(v, 63);

    if (wv < 4) {
      // ================= Y-path =================
      short8 afC[4];
#pragma unroll
      for (int kt = 0; kt < 4; kt++)
        afC[kt] = *(const short8*)&Cst[(16 * wv + tq) * CST + kt * 32 + quad * 8];
      f32x4 g_acc[4];
#pragma unroll
      for (int nj = 0; nj < 4; nj++) g_acc[nj] = (f32x4){0.f, 0.f, 0.f, 0.f};
#pragma unroll
      for (int kt = 0; kt < 4; kt++) {
#pragma unroll
        for (int nj = 0; nj < 4; nj++) {
          short8 bfr = *(const short8*)&Bst[(16 * nj + tq) * CST + kt * 32 + quad * 8];
          g_acc[nj] = __builtin_amdgcn_mfma_f32_16x16x32_bf16(afC[kt], bfr, g_acc[nj], 0, 0, 0);
        }
      }
      float ci[4], pex[4];
#pragma unroll
      for (int r = 0; r < 4; r++) {
        ci[r] = __shfl(v, 16 * wv + quad * 4 + r);
        pex[r] = expf(ci[r]);
      }
#pragma unroll
      for (int nj = 0; nj < 4; nj++) {
        int j = 16 * nj + tq;
        float cj = __shfl(v, j);
        float dj = dtvL[j];
#pragma unroll
        for (int r = 0; r < 4; r++) {
          int i = 16 * wv + quad * 4 + r;
          float val = (j <= i) ? g_acc[nj][r] * expf(ci[r] - cj) * dj : 0.f;
          Msh[i * TST + j] = f2bf(val);
        }
      }
      // Y = Pex*(C*Sb^T) + Ms*x^T
      f32x4 yac[2];
      yac[0] = (f32x4){0.f, 0.f, 0.f, 0.f};
      yac[1] = (f32x4){0.f, 0.f, 0.f, 0.f};
#pragma unroll
      for (int kt = 0; kt < 4; kt++) {
#pragma unroll
        for (int np = 0; np < 2; np++) {
          short8 bs = *(const short8*)&Sb[pp][(16 * np + tq) * CST + kt * 32 + quad * 8];
          yac[np] = __builtin_amdgcn_mfma_f32_16x16x32_bf16(afC[kt], bs, yac[np], 0, 0, 0);
        }
      }
#pragma unroll
      for (int np = 0; np < 2; np++)
#pragma unroll
        for (int r = 0; r < 4; r++) yac[np][r] *= pex[r];
#pragma unroll
      for (int kt2 = 0; kt2 < 2; kt2++) {
        short8 am = *(const short8*)&Msh[(16 * wv + tq) * TST + kt2 * 32 + quad * 8];
#pragma unroll
        for (int np = 0; np < 2; np++) {
          short8 bx = *(const short8*)&xtT[(16 * np + tq) * TST + kt2 * 32 + quad * 8];
          yac[np] = __builtin_amdgcn_mfma_f32_16x16x32_bf16(am, bx, yac[np], 0, 0, 0);
        }
      }
#pragma unroll
      for (int np = 0; np < 2; np++) {
#pragma unroll
        for (int r = 0; r < 4; r++) {
          int i = 16 * wv + quad * 4 + r;
          int p = ph * 32 + 16 * np + tq;
          yp[(row0 + c0 + i) * INTER + h * 64 + p] = f2bf(yac[np][r]);
        }
      }
    } else {
      // ================= S-path =================
      float ptot = expf(tot);
      short8 ax[2];
#pragma unroll
      for (int kt2 = 0; kt2 < 2; kt2++) {
        short8 xv = *(const short8*)&xtT[(16 * pt + tq) * TST + kt2 * 32 + quad * 8];
#pragma unroll
        for (int e = 0; e < 8; e++) {
          int j = kt2 * 32 + quad * 8 + e;
          float cj = __shfl(v, j);
          float wj = expf(tot - cj) * dtvL[j];
          ax[kt2][e] = (short)f2bf(bf2f((unsigned short)xv[e]) * wj);
        }
      }
#pragma unroll
      for (int c = 0; c < 4; c++)
#pragma unroll
        for (int r = 0; r < 4; r++) s_acc[c][r] *= ptot;
#pragma unroll
      for (int kt2 = 0; kt2 < 2; kt2++) {
#pragma unroll
        for (int c = 0; c < 4; c++) {
          short8 bb = *(const short8*)&Btt[(16 * (ntb + c) + tq) * TST + kt2 * 32 + quad * 8];
          s_acc[c] = __builtin_amdgcn_mfma_f32_16x16x32_bf16(ax[kt2], bb, s_acc[c], 0, 0, 0);
        }
      }
#pragma unroll
      for (int c = 0; c < 4; c++)
#pragma unroll
        for (int r = 0; r < 4; r++) {
          int p = 16 * pt + quad * 4 + r;
          int n = 16 * (ntb + c) + tq;
          Sb[pp ^ 1][p * CST + n] = f2bf(s_acc[c][r]);
        }
    }
    // next chunk's B0 protects Sb[pp^1] writes before Y reads them
  }
}

// ---------------- y = yp + D*x; gated RMSNorm -> bf16 (registers, no LDS buf) ----------------
__global__ __launch_bounds__(256)
void gated_norm_kernel(const unsigned short* __restrict__ yp,
                       const unsigned short* __restrict__ convo, const unsigned short* __restrict__ proj,
                       const float* __restrict__ Dv, const float* __restrict__ gnw,
                       unsigned short* __restrict__ yn) {
  int row = blockIdx.x;
  int t = threadIdx.x;
  __shared__ float red[4];
  __shared__ float scl;
  size_t yo = (size_t)row * INTER;
  size_t co = (size_t)row * CONV_DIM;
  size_t po = (size_t)row * PROJ;
  float vv[16];
  float ss = 0.f;
#pragma unroll
  for (int c = 0; c < 4; c++) {
    int i = t * 4 + c * 1024;
    ushort4 y0 = *(const ushort4*)&yp[yo + i];
    ushort4 xs = *(const ushort4*)&convo[co + i];
    ushort4 g  = *(const ushort4*)&proj[po + i];
    float Dh = Dv[i >> 6];
    float yv[4] = { bf2f(y0.x) + Dh * bf2f(xs.x),
                    bf2f(y0.y) + Dh * bf2f(xs.y),
                    bf2f(y0.z) + Dh * bf2f(xs.z),
                    bf2f(y0.w) + Dh * bf2f(xs.w) };
    float gv[4] = { bf2f(g.x), bf2f(g.y), bf2f(g.z), bf2f(g.w) };
#pragma unroll
    for (int k = 0; k < 4; k++) {
      float val = yv[k] * (gv[k] / (1.f + expf(-gv[k])));
      vv[c * 4 + k] = val;
      ss += val * val;
    }
  }
  for (int o = 32; o > 0; o >>= 1) ss += __shfl_down(ss, o);
  if ((t & 63) == 0) red[t >> 6] = ss;
  __syncthreads();
  if (t == 0) scl = rsqrtf((red[0]+red[1]+red[2]+red[3]) / (float)INTER + EPS);
  __syncthreads();
  float s = scl;
#pragma unroll
  for (int c = 0; c < 4; c++) {
    int i = t * 4 + c * 1024;
    ushort4 o;
    o.x = f2bf(vv[c*4+0] * s * gnw[i + 0]);
    o.y = f2bf(vv[c*4+1] * s * gnw[i + 1]);
    o.z = f2bf(vv[c*4+2] * s * gnw[i + 2]);
    o.w = f2bf(vv[c*4+3] * s * gnw[i + 3]);
    *(ushort4*)&yn[po + i] = o;
  }
}

// ---------------- launch ----------------
extern "C" void kernel_launch(void* const* d_in, const int* in_sizes, int n_in,
                              void* d_out, int out_size, void* d_ws, size_t ws_size,
                              hipStream_t stream) {
  const float* hidden  = (const float*)d_in[0];
  const float* norm_w  = (const float*)d_in[1];
  const float* w1      = (const float*)d_in[2];
  const float* convw   = (const float*)d_in[3];
  const float* convb   = (const float*)d_in[4];
  const float* dt_bias = (const float*)d_in[5];
  const float* A_log   = (const float*)d_in[6];
  const float* Dv      = (const float*)d_in[7];
  const float* gnw     = (const float*)d_in[8];
  const float* w2      = (const float*)d_in[9];
  float* out = (float*)d_out;

  char* ws = (char*)d_ws;
  size_t off = 0;
  auto alloc = [&](size_t bytes) {
    void* p = ws + off;
    off += (bytes + 255) & ~(size_t)255;
    return p;
  };
  unsigned short* XN  = (unsigned short*)alloc((size_t)BS * HID * 2);      // 16.8 MB
  unsigned short* W1B = (unsigned short*)alloc((size_t)PROJ * HID * 2);    // 34.9 MB
  unsigned short* W2B = (unsigned short*)alloc((size_t)HID * INTER * 2);   // 16.8 MB
  unsigned short* PRJ = (unsigned short*)alloc((size_t)BS * PROJ * 2);     // 69.7 MB
  unsigned short* CVO = (unsigned short*)alloc((size_t)BS * CONV_DIM * 2); // 35.7 MB
  float2*         DTS = (float2*)alloc((size_t)BS * HEADS * 8);            //  2.1 MB
  unsigned short* YP  = XN;                    // overlay: XN+W1B dead after GEMM1
  unsigned short* YN  = PRJ + YN_COL;          // in-row overlay, stride PROJ
  if (off > ws_size) return;
  (void)in_sizes; (void)n_in; (void)out_size;

  int n1 = PROJ * HID / 4;
  cast_bf16_kernel<<<(n1 + 255) / 256, 256, 0, stream>>>((const float4*)w1, (ushort4*)W1B, n1);
  int n2 = HID * INTER / 4;
  cast_bf16_kernel<<<(n2 + 255) / 256, 256, 0, stream>>>((const float4*)w2, (ushort4*)W2B, n2);

  rmsnorm_in_kernel<<<BS, 256, 0, stream>>>(hidden, norm_w, XN);

  // GEMM1: [4096 x 8512] = XN[4096 x 2048] * W1B^T ; 16 x 67 = 1072 blocks (1072 % 8 == 0)
  gemm128n_kernel<<<dim3((BS / 256) * ((PROJ + 127) / 128)), 512, 0, stream>>>(
      XN, HID, W1B, nullptr, PRJ, PROJ, BS, PROJ, HID, nullptr);

  conv_dt_kernel<<<(BS * (CONV_DIM / 8) + BS * HEADS + 255) / 256, 256, 0, stream>>>(
      PRJ, convw, convb, dt_bias, A_log, CVO, DTS);

  ssd_scan_kernel<<<256, 512, 0, stream>>>(CVO, DTS, YP);

  gated_norm_kernel<<<BS, 256, 0, stream>>>(YP, CVO, PRJ, Dv, gnw, YN);

  // GEMM2: [4096 x 2048] = YN[4096 x 4096] * W2B^T + residual ; 16 x 16 = 256 blocks (1 round)
  gemm128n_kernel<<<dim3((BS / 256) * (HID / 128)), 512, 0, stream>>>(
      YN, PROJ, W2B, out, nullptr, HID, BS, HID, INTER, hidden);
}

// Round 3
// 599.411 us; speedup vs baseline: 1.2536x; 1.1893x over previous
//
#include <hip/hip_runtime.h>
#include <math.h>

#define HID      2048
#define STATE    128
#define HEADS    64
#define HEADDIM  64
#define INTER    4096
#define CONV_DIM 4352
#define PROJ     8512
#define NBATCH   2
#define SEQ      2048
#define BS       (NBATCH*SEQ)   /* 4096 token rows */
#define EPS      1e-5f
#define YN_COL   4160           /* YN lives in PRJ cols [4160, 8256) after conv/dt are dead */

typedef __attribute__((ext_vector_type(8))) short short8;
typedef __attribute__((ext_vector_type(4))) float f32x4;

__device__ inline unsigned short f2bf(float f) {
  union { float f; unsigned int u; } v; v.f = f;
  unsigned int r = v.u + 0x7fffu + ((v.u >> 16) & 1u);   // RNE
  return (unsigned short)(r >> 16);
}
__device__ inline float bf2f(unsigned short b) {
  union { unsigned int u; float f; } v; v.u = ((unsigned int)b) << 16;
  return v.f;
}

// ---------------- f32 -> bf16 cast (weights) ----------------
__global__ __launch_bounds__(256)
void cast_bf16_kernel(const float4* __restrict__ src, ushort4* __restrict__ dst, int n4) {
  int i = blockIdx.x * 256 + threadIdx.x;
  if (i >= n4) return;
  float4 v = src[i];
  ushort4 o;
  o.x = f2bf(v.x); o.y = f2bf(v.y); o.z = f2bf(v.z); o.w = f2bf(v.w);
  dst[i] = o;
}

// ---------------- input RMSNorm -> bf16 ----------------
__global__ __launch_bounds__(256)
void rmsnorm_in_kernel(const float* __restrict__ x, const float* __restrict__ w,
                       unsigned short* __restrict__ xn) {
  int row = blockIdx.x;
  int t = threadIdx.x;
  const float* xr = x + (size_t)row * HID;
  float4 a = ((const float4*)xr)[t];
  float4 b = ((const float4*)xr)[t + 256];
  float ss = a.x*a.x + a.y*a.y + a.z*a.z + a.w*a.w
           + b.x*b.x + b.y*b.y + b.z*b.z + b.w*b.w;
  for (int o = 32; o > 0; o >>= 1) ss += __shfl_down(ss, o);
  __shared__ float red[4];
  __shared__ float scl;
  if ((t & 63) == 0) red[t >> 6] = ss;
  __syncthreads();
  if (t == 0) scl = rsqrtf((red[0]+red[1]+red[2]+red[3]) / (float)HID + EPS);
  __syncthreads();
  float s = scl;
  float4 w0 = ((const float4*)w)[t];
  float4 w1 = ((const float4*)w)[t + 256];
  ushort4 o0, o1;
  o0.x = f2bf(a.x*s*w0.x); o0.y = f2bf(a.y*s*w0.y); o0.z = f2bf(a.z*s*w0.z); o0.w = f2bf(a.w*s*w0.w);
  o1.x = f2bf(b.x*s*w1.x); o1.y = f2bf(b.y*s*w1.y); o1.z = f2bf(b.z*s*w1.z); o1.w = f2bf(b.w*s*w1.w);
  ushort4* dst = (ushort4*)(xn + (size_t)row * HID);
  dst[t] = o0;
  dst[t + 256] = o1;
}

// ---------------- 256x128 / BK=64 / 8-wave / 8-phase bf16 BT-GEMM ----------------
// Inner schedule identical to the verified round-2 kernel (T2 swizzle, 8-phase,
// vmcnt(2) at p3/p7, setprio). Only the block->tile map changed: 4Mx8N bricks
// within the XCD chunk so the ~32 concurrent blocks per XCD share 4 A-panels +
// 8 B-panels (8 MB active vs 17 MB before) -> panel re-reads hit XCD L2.

__device__ __forceinline__ void stage_half(const unsigned short* __restrict__ G, int ld,
                                           int row0, int rmax, int kt,
                                           unsigned short* lbase, int half, int t) {
  const int w = t >> 6;
#pragma unroll
  for (int it = 0; it < 2; ++it) {
    int id = it * 512 + t;          // chunk id 0..1023
    int rl = id >> 3;               // local row 0..127
    int sl = id & 7;                // 16B slot 0..7
    int grow = row0 + half * 128 + rl;
    if (grow > rmax) grow = rmax;
    const unsigned short* g = G + (size_t)grow * ld + kt * 64 + ((sl ^ (rl & 7)) << 3);
    unsigned short* l = lbase + half * (128 * 64) + (it * 512 + w * 64) * 8;  // wave-uniform
    __builtin_amdgcn_global_load_lds((const __attribute__((address_space(1))) void*)g,
                                     (__attribute__((address_space(3))) void*)l, 16, 0, 0);
  }
}

#define VMW2 asm volatile("s_waitcnt vmcnt(2)" ::: "memory")

#define PHASE(BUF, MH, NH, RA, RB, STG, VMW_)                                        \
  {                                                                                  \
    const unsigned short* bufA = lds + (BUF)*24576;                                  \
    const unsigned short* bufB = lds + (BUF)*24576 + 16384;                          \
    if (RA) {                                                                        \
      _Pragma("unroll")                                                              \
      for (int ml = 0; ml < 2; ++ml) {                                               \
        _Pragma("unroll")                                                            \
        for (int kk = 0; kk < 2; ++kk) {                                             \
          const int r = wr*64 + (MH)*32 + ml*16 + tq;                                \
          aR[ml][kk] = *(const short8*)(bufA + r*64 + (((kk<<2)|quad)^(r&7))*8);     \
        }                                                                            \
      }                                                                              \
    }                                                                                \
    if (RB) {                                                                        \
      _Pragma("unroll")                                                              \
      for (int nl = 0; nl < 2; ++nl) {                                               \
        _Pragma("unroll")                                                            \
        for (int kk = 0; kk < 2; ++kk) {                                             \
          const int r = wc*64 + (NH)*32 + nl*16 + tq;                                \
          bR[NH][nl][kk] = *(const short8*)(bufB + r*64 + (((kk<<2)|quad)^(r&7))*8); \
        }                                                                            \
      }                                                                              \
    }                                                                                \
    STG;                                                                             \
    __builtin_amdgcn_s_barrier();                                                    \
    asm volatile("s_waitcnt lgkmcnt(0)" ::: "memory");                               \
    __builtin_amdgcn_sched_barrier(0);                                               \
    __builtin_amdgcn_s_setprio(1);                                                   \
    _Pragma("unroll")                                                                \
    for (int ml = 0; ml < 2; ++ml) {                                                 \
      _Pragma("unroll")                                                              \
      for (int nl = 0; nl < 2; ++nl) {                                               \
        _Pragma("unroll")                                                            \
        for (int kk = 0; kk < 2; ++kk) {                                             \
          acc[(MH)*2+ml][(NH)*2+nl] = __builtin_amdgcn_mfma_f32_16x16x32_bf16(       \
              aR[ml][kk], bR[NH][nl][kk], acc[(MH)*2+ml][(NH)*2+nl], 0, 0, 0);       \
        }                                                                            \
      }                                                                              \
    }                                                                                \
    __builtin_amdgcn_s_setprio(0);                                                   \
    VMW_;                                                                            \
    __builtin_amdgcn_s_barrier();                                                    \
  }

__global__ __launch_bounds__(512, 1)
void gemm128n_kernel(const unsigned short* __restrict__ A, int lda,
                     const unsigned short* __restrict__ B,
                     float* __restrict__ Cf, unsigned short* __restrict__ Cb, int ldc,
                     int M, int N, int Kd, const float* __restrict__ residual) {
  __shared__ unsigned short lds[49152];   // 96 KiB: [buf][A(256x64)|B(128x64)]
  const int t = threadIdx.x;
  const int lane = t & 63;
  const int quad = lane >> 4;
  const int tq = lane & 15;
  const int w = t >> 6;
  const int wr = w >> 1;    // 4 M-waves x 2 N-waves; per-wave C = 64x64
  const int wc = w & 1;

  // T1: bijective XCD swizzle + 4Mx8N brick map (L2 working-set reduction)
  const int Mtiles = M >> 8;
  const int Ntiles = (N + 127) >> 7;
  const int nwg = (int)gridDim.x;
  const int cpx = nwg >> 3;            // nwg % 8 == 0 for both call sites
  const int bid = (int)blockIdx.x;
  const int sw = (bid & 7) * cpx + (bid >> 3);
  const int NBfull = Ntiles & ~7;      // n-tiles covered by full 8-wide bricks
  int m0, n0;
  if (sw < Mtiles * NBfull) {
    int brick = sw >> 5;               // 32 tiles per 4x8 brick
    int inner = sw & 31;               // m-fastest within brick
    int bm = brick % (Mtiles >> 2);
    int bn = brick / (Mtiles >> 2);
    m0 = (bm * 4 + (inner & 3)) << 8;
    n0 = (bn * 8 + (inner >> 2)) << 7;
  } else {                             // ragged n-tail: m-major
    int r = sw - Mtiles * NBfull;
    m0 = (r % Mtiles) << 8;
    n0 = (NBfull + r / Mtiles) << 7;
  }

  f32x4 acc[4][4];
#pragma unroll
  for (int i = 0; i < 4; ++i)
#pragma unroll
    for (int j = 0; j < 4; ++j) acc[i][j] = (f32x4){0.f, 0.f, 0.f, 0.f};

  short8 aR[2][2];      // current MH half: 2 m-frags x 2 k-steps
  short8 bR[2][2][2];   // both NH halves kept live: [NH][nl][kk]

  unsigned short* A0 = lds;
  unsigned short* B0 = lds + 16384;
  unsigned short* A1 = lds + 24576;
  unsigned short* B1 = lds + 24576 + 16384;

  const int kIters = Kd >> 6;      // K-tiles of 64 (even for K=2048/4096)
  const int nIter  = kIters >> 1;

  // prologue: K-tile 0 fully + K-tile 1 A-h0 (mirrors steady-state p7 stage)
  stage_half(A, lda, m0, M - 1, 0, A0, 0, t);
  stage_half(A, lda, m0, M - 1, 0, A0, 1, t);
  stage_half(B, Kd,  n0, N - 1, 0, B0, 0, t);
  stage_half(A, lda, m0, M - 1, 1, A1, 0, t);
  VMW2;                              // K0's 6 loads done; K1 A-h0 may stay in flight
  __builtin_amdgcn_s_barrier();

  for (int i = 0; i < nIter; ++i) {
    const int k1 = 2 * i + 1;
    int k2 = 2 * i + 2; if (k2 > kIters - 1) k2 = kIters - 1;   // tail: harmless re-stage
    int k3 = 2 * i + 3; if (k3 > kIters - 1) k3 = kIters - 1;
    // phases 0-3: compute K-tile 2i (buf0); finish staging K1(buf1), start K2(buf0)
    PHASE(0, 0, 0, 1, 1, stage_half(A, lda, m0, M - 1, k1, A1, 1, t), ((void)0))
    PHASE(0, 0, 1, 0, 1, stage_half(B, Kd,  n0, N - 1, k1, B1, 0, t), ((void)0))
    PHASE(0, 1, 1, 1, 0, ((void)0), ((void)0))
    PHASE(0, 1, 0, 0, 0, stage_half(A, lda, m0, M - 1, k2, A0, 0, t), VMW2)
    // phases 4-7: compute K-tile 2i+1 (buf1); finish K2(buf0), start K3(buf1)
    PHASE(1, 0, 0, 1, 1, stage_half(A, lda, m0, M - 1, k2, A0, 1, t), ((void)0))
    PHASE(1, 0, 1, 0, 1, stage_half(B, Kd,  n0, N - 1, k2, B0, 0, t), ((void)0))
    PHASE(1, 1, 1, 1, 0, ((void)0), ((void)0))
    PHASE(1, 1, 0, 0, 0, stage_half(A, lda, m0, M - 1, k3, A1, 0, t), VMW2)
  }
  asm volatile("s_waitcnt vmcnt(0)" ::: "memory");   // drain LDS-DMA before exit

#pragma unroll
  for (int mf = 0; mf < 4; ++mf) {
    const int rowb = m0 + wr * 64 + mf * 16 + quad * 4;
#pragma unroll
    for (int nf = 0; nf < 4; ++nf) {
      const int col = n0 + wc * 64 + nf * 16 + tq;
      if (col < N) {
        if (Cb) {
#pragma unroll
          for (int r = 0; r < 4; ++r)
            Cb[(size_t)(rowb + r) * ldc + col] = f2bf(acc[mf][nf][r]);
        } else {
#pragma unroll
          for (int r = 0; r < 4; ++r) {
            size_t idx = (size_t)(rowb + r) * N + col;
            float v = acc[mf][nf][r];
            if (residual) v += residual[idx];
            Cf[idx] = v;
          }
        }
      }
    }
  }
}

// ---------------- fused causal conv(K=4)+SiLU (LDS row-tiled) and dt=softplus ----------------
// Block covers 64 s-rows x 128 channels; stages 67 input rows once into LDS
// (read amplification 4x -> 1.05x). c8 is constant per thread -> conv weights in regs.
#define CONV_BC 128
#define CONV_BS 64
#define CXS 136   /* padded LDS row stride (shorts): +4 banks per row */

__global__ __launch_bounds__(256)
void conv_dt_kernel(const unsigned short* __restrict__ proj, const float* __restrict__ cw,
                    const float* __restrict__ cb, const float* __restrict__ dtb,
                    const float* __restrict__ A_log,
                    unsigned short* __restrict__ convo, float2* __restrict__ dts) {
  const int NCB = CONV_DIM / CONV_BC;            // 34 channel-blocks
  const int NCONVB = NCB * (BS / CONV_BS);       // 34*64 = 2176 conv blocks
  int blk = blockIdx.x;
  int t = threadIdx.x;
  if (blk < NCONVB) {
    __shared__ unsigned short xs[67 * CXS];
    int cblk = blk % NCB;
    int rblk = blk / NCB;
    int ch0 = cblk * CONV_BC;
    int rs0 = rblk * CONV_BS;                    // global token row (b*SEQ+s)
    int s0 = rs0 & (SEQ - 1);
    // per-thread fixed channel group
    const int c8 = t & 15;                       // tasks stride 256 => c8 const
    const int co = c8 * 8;
    float cwr[4][8], cbr[8];
#pragma unroll
    for (int e = 0; e < 8; e++) {
      cbr[e] = cb[ch0 + co + e];
#pragma unroll
      for (int k = 0; k < 4; k++) cwr[k][e] = cw[(ch0 + co + e) * 4 + k];
    }
    // stage rows s0-3 .. s0+63 (67 rows x 128 ch)
    for (int i = t; i < 67 * 16; i += 256) {
      int row = i >> 4, sl = i & 15;
      short8 v;
      if (s0 == 0 && row < 3) v = (short8){0,0,0,0,0,0,0,0};
      else v = *(const short8*)&proj[(size_t)(rs0 - 3 + row) * PROJ + INTER + ch0 + sl * 8];
      *(short8*)&xs[row * CXS + sl * 8] = v;
    }
    __syncthreads();
    // compute: row r needs LDS rows r..r+3 (tap k at row r+k)
#pragma unroll
    for (int it = 0; it < 4; ++it) {
      int r = (t >> 4) + it * 16;
      float acc[8];
#pragma unroll
      for (int e = 0; e < 8; e++) acc[e] = cbr[e];
#pragma unroll
      for (int k = 0; k < 4; k++) {
        short8 v = *(const short8*)&xs[(r + k) * CXS + co];
#pragma unroll
        for (int e = 0; e < 8; e++) acc[e] += bf2f((unsigned short)v[e]) * cwr[k][e];
      }
      short8 o;
#pragma unroll
      for (int e = 0; e < 8; e++) {
        float a = acc[e];
        o[e] = (short)f2bf(a / (1.f + expf(-a)));   // SiLU
      }
      *(short8*)&convo[(size_t)(rs0 + r) * CONV_DIM + ch0 + co] = o;
    }
  } else {
    int k = (blk - NCONVB) * 256 + t;
    if (k < BS * HEADS) {
      int h  = k & 63;
      int rs = k >> 6;
      float x = bf2f(proj[(size_t)rs * PROJ + INTER + CONV_DIM + h]) + dtb[h];
      float dt = (x > 20.f) ? x : log1pf(expf(x));
      float Ah = -expf(A_log[h]);
      dts[k] = make_float2(dt, dt * Ah);   // {dt, log-decay increment}
    }
  }
}

// ---------------- SSD chunked scan (MFMA), 8 waves: Y-path || S-path ----------------
// T14 async-stage: next chunk's global reads issued right after S1 (held in regs),
// written to LDS after the following B0 -> HBM latency hides under compute.
#define LCH 64
#define CST 136   /* row stride (shorts) for Cst/Bst/Sb */
#define TST 72    /* row stride (shorts) for Btt/xtT/Msh */

__global__ __launch_bounds__(512)
void ssd_scan_kernel(const unsigned short* __restrict__ convo, const float2* __restrict__ dts,
                     unsigned short* __restrict__ yp) {
  __shared__ unsigned short Cst[64 * CST];
  __shared__ unsigned short Bst[64 * CST];
  __shared__ unsigned short Btt[128 * TST];   // B transposed [n][j]
  __shared__ unsigned short xtT[32 * TST];    // x transposed [p_local][j]
  __shared__ unsigned short Msh[64 * TST];    // masked decay-weighted G [i][j]
  __shared__ unsigned short Sb[2][32 * CST];  // state bf16 [p_local][n], double-buffered
  __shared__ float dtaL[64], dtvL[64];

  const int ph = blockIdx.x & 1;
  const int h  = (blockIdx.x >> 1) & 63;
  const int b  = blockIdx.x >> 7;
  const int t  = threadIdx.x;
  const int wv = t >> 6;
  const int lane = t & 63;
  const int quad = lane >> 4;
  const int tq   = lane & 15;
  const size_t row0 = (size_t)b * SEQ;
  const int xcol = h * 64 + ph * 32;

  for (int i = t; i < 32 * CST; i += 512) Sb[0][i] = 0;

  // S-wave (wv>=4) persistent state accumulators
  f32x4 s_acc[4];
#pragma unroll
  for (int c = 0; c < 4; c++) s_acc[c] = (f32x4){0.f, 0.f, 0.f, 0.f};
  const int pt  = wv & 1;               // S-wave p-tile (0/1)
  const int ntb = ((wv >> 1) & 1) * 4;  // S-wave n-tile base (x16)

  // ---- prefetch chunk 0 into registers ----
  short8 vb_r[2], vc_r[2]; ushort4 vx_r; float2 dv_r = make_float2(0.f, 0.f);
  {
#pragma unroll
    for (int it = 0; it < 2; ++it) {
      int id = t + 512 * it;
      int row = id >> 4, cc = id & 15;
      size_t g = (row0 + row) * CONV_DIM + INTER;
      vb_r[it] = *(const short8*)&convo[g + cc * 8];
      vc_r[it] = *(const short8*)&convo[g + STATE + cc * 8];
    }
    int row = t >> 3, c = t & 7;
    vx_r = *(const ushort4*)&convo[(row0 + row) * CONV_DIM + xcol + c * 4];
    if (t < 64) dv_r = dts[((row0 + t) << 6) + h];
  }

  int pp = 0;
  for (int c0 = 0; c0 < SEQ; c0 += LCH, pp ^= 1) {
    __syncthreads();   // B0: prior chunk's compute reads done before restaging
    // ---- write register-staged B, C, B^T, x^T, dt into LDS ----
#pragma unroll
    for (int it = 0; it < 2; ++it) {
      int id = t + 512 * it;
      int row = id >> 4, cc = id & 15;
      *(short8*)&Bst[row * CST + cc * 8] = vb_r[it];
      *(short8*)&Cst[row * CST + cc * 8] = vc_r[it];
#pragma unroll
      for (int e = 0; e < 8; e++)
        Btt[(cc * 8 + e) * TST + row] = (unsigned short)vb_r[it][e];
    }
    {
      int row = t >> 3, c = t & 7;
      xtT[(c * 4 + 0) * TST + row] = vx_r.x;
      xtT[(c * 4 + 1) * TST + row] = vx_r.y;
      xtT[(c * 4 + 2) * TST + row] = vx_r.z;
      xtT[(c * 4 + 3) * TST + row] = vx_r.w;
    }
    if (t < 64) { dtvL[t] = dv_r.x; dtaL[t] = dv_r.y; }
    __syncthreads();   // S1: staging visible

    // ---- issue next chunk's global loads (latency hides under compute) ----
    if (c0 + LCH < SEQ) {
#pragma unroll
      for (int it = 0; it < 2; ++it) {
        int id = t + 512 * it;
        int row = id >> 4, cc = id & 15;
        size_t g = (row0 + c0 + LCH + row) * CONV_DIM + INTER;
        vb_r[it] = *(const short8*)&convo[g + cc * 8];
        vc_r[it] = *(const short8*)&convo[g + STATE + cc * 8];
      }
      int row = t >> 3, c = t & 7;
      vx_r = *(const ushort4*)&convo[(row0 + c0 + LCH + row) * CONV_DIM + xcol + c * 4];
      if (t < 64) dv_r = dts[((row0 + c0 + LCH + t) << 6) + h];
    }

    // ---- per-wave cumulative log-decay scan (lane l holds cum[l]) ----
    float v = dtaL[lane];
#pragma unroll
    for (int off = 1; off < 64; off <<= 1) {
      float u = __shfl_up(v, off);
      if (lane >= off) v += u;
    }
    float tot = __shfl(v, 63);

    if (wv < 4) {
      // ================= Y-path =================
      short8 afC[4];
#pragma unroll
      for (int kt = 0; kt < 4; kt++)
        afC[kt] = *(const short8*)&Cst[(16 * wv + tq) * CST + kt * 32 + quad * 8];
      f32x4 g_acc[4];
#pragma unroll
      for (int nj = 0; nj < 4; nj++) g_acc[nj] = (f32x4){0.f, 0.f, 0.f, 0.f};
#pragma unroll
      for (int kt = 0; kt < 4; kt++) {
#pragma unroll
        for (int nj = 0; nj < 4; nj++) {
          short8 bfr = *(const short8*)&Bst[(16 * nj + tq) * CST + kt * 32 + quad * 8];
          g_acc[nj] = __builtin_amdgcn_mfma_f32_16x16x32_bf16(afC[kt], bfr, g_acc[nj], 0, 0, 0);
        }
      }
      float ci[4], pex[4];
#pragma unroll
      for (int r = 0; r < 4; r++) {
        ci[r] = __shfl(v, 16 * wv + quad * 4 + r);
        pex[r] = expf(ci[r]);
      }
#pragma unroll
      for (int nj = 0; nj < 4; nj++) {
        int j = 16 * nj + tq;
        float cj = __shfl(v, j);
        float dj = dtvL[j];
#pragma unroll
        for (int r = 0; r < 4; r++) {
          int i = 16 * wv + quad * 4 + r;
          float val = (j <= i) ? g_acc[nj][r] * expf(ci[r] - cj) * dj : 0.f;
          Msh[i * TST + j] = f2bf(val);
        }
      }
      // Y = Pex*(C*Sb^T) + Ms*x^T
      f32x4 yac[2];
      yac[0] = (f32x4){0.f, 0.f, 0.f, 0.f};
      yac[1] = (f32x4){0.f, 0.f, 0.f, 0.f};
#pragma unroll
      for (int kt = 0; kt < 4; kt++) {
#pragma unroll
        for (int np = 0; np < 2; np++) {
          short8 bs = *(const short8*)&Sb[pp][(16 * np + tq) * CST + kt * 32 + quad * 8];
          yac[np] = __builtin_amdgcn_mfma_f32_16x16x32_bf16(afC[kt], bs, yac[np], 0, 0, 0);
        }
      }
#pragma unroll
      for (int np = 0; np < 2; np++)
#pragma unroll
        for (int r = 0; r < 4; r++) yac[np][r] *= pex[r];
#pragma unroll
      for (int kt2 = 0; kt2 < 2; kt2++) {
        short8 am = *(const short8*)&Msh[(16 * wv + tq) * TST + kt2 * 32 + quad * 8];
#pragma unroll
        for (int np = 0; np < 2; np++) {
          short8 bx = *(const short8*)&xtT[(16 * np + tq) * TST + kt2 * 32 + quad * 8];
          yac[np] = __builtin_amdgcn_mfma_f32_16x16x32_bf16(am, bx, yac[np], 0, 0, 0);
        }
      }
#pragma unroll
      for (int np = 0; np < 2; np++) {
#pragma unroll
        for (int r = 0; r < 4; r++) {
          int i = 16 * wv + quad * 4 + r;
          int p = ph * 32 + 16 * np + tq;
          yp[(row0 + c0 + i) * INTER + h * 64 + p] = f2bf(yac[np][r]);
        }
      }
    } else {
      // ================= S-path =================
      float ptot = expf(tot);
      short8 ax[2];
#pragma unroll
      for (int kt2 = 0; kt2 < 2; kt2++) {
        short8 xv = *(const short8*)&xtT[(16 * pt + tq) * TST + kt2 * 32 + quad * 8];
#pragma unroll
        for (int e = 0; e < 8; e++) {
          int j = kt2 * 32 + quad * 8 + e;
          float cj = __shfl(v, j);
          float wj = expf(tot - cj) * dtvL[j];
          ax[kt2][e] = (short)f2bf(bf2f((unsigned short)xv[e]) * wj);
        }
      }
#pragma unroll
      for (int c = 0; c < 4; c++)
#pragma unroll
        for (int r = 0; r < 4; r++) s_acc[c][r] *= ptot;
#pragma unroll
      for (int kt2 = 0; kt2 < 2; kt2++) {
#pragma unroll
        for (int c = 0; c < 4; c++) {
          short8 bb = *(const short8*)&Btt[(16 * (ntb + c) + tq) * TST + kt2 * 32 + quad * 8];
          s_acc[c] = __builtin_amdgcn_mfma_f32_16x16x32_bf16(ax[kt2], bb, s_acc[c], 0, 0, 0);
        }
      }
#pragma unroll
      for (int c = 0; c < 4; c++)
#pragma unroll
        for (int r = 0; r < 4; r++) {
          int p = 16 * pt + quad * 4 + r;
          int n = 16 * (ntb + c) + tq;
          Sb[pp ^ 1][p * CST + n] = f2bf(s_acc[c][r]);
        }
    }
    // next chunk's B0 protects Sb[pp^1] writes before Y reads them
  }
}

// ---------------- y = yp + D*x; gated RMSNorm -> bf16 (registers, no LDS buf) ----------------
__global__ __launch_bounds__(256)
void gated_norm_kernel(const unsigned short* __restrict__ yp,
                       const unsigned short* __restrict__ convo, const unsigned short* __restrict__ proj,
                       const float* __restrict__ Dv, const float* __restrict__ gnw,
                       unsigned short* __restrict__ yn) {
  int row = blockIdx.x;
  int t = threadIdx.x;
  __shared__ float red[4];
  __shared__ float scl;
  size_t yo = (size_t)row * INTER;
  size_t co = (size_t)row * CONV_DIM;
  size_t po = (size_t)row * PROJ;
  float vv[16];
  float ss = 0.f;
#pragma unroll
  for (int c = 0; c < 4; c++) {
    int i = t * 4 + c * 1024;
    ushort4 y0 = *(const ushort4*)&yp[yo + i];
    ushort4 xs = *(const ushort4*)&convo[co + i];
    ushort4 g  = *(const ushort4*)&proj[po + i];
    float Dh = Dv[i >> 6];
    float yv[4] = { bf2f(y0.x) + Dh * bf2f(xs.x),
                    bf2f(y0.y) + Dh * bf2f(xs.y),
                    bf2f(y0.z) + Dh * bf2f(xs.z),
                    bf2f(y0.w) + Dh * bf2f(xs.w) };
    float gv[4] = { bf2f(g.x), bf2f(g.y), bf2f(g.z), bf2f(g.w) };
#pragma unroll
    for (int k = 0; k < 4; k++) {
      float val = yv[k] * (gv[k] / (1.f + expf(-gv[k])));
      vv[c * 4 + k] = val;
      ss += val * val;
    }
  }
  for (int o = 32; o > 0; o >>= 1) ss += __shfl_down(ss, o);
  if ((t & 63) == 0) red[t >> 6] = ss;
  __syncthreads();
  if (t == 0) scl = rsqrtf((red[0]+red[1]+red[2]+red[3]) / (float)INTER + EPS);
  __syncthreads();
  float s = scl;
#pragma unroll
  for (int c = 0; c < 4; c++) {
    int i = t * 4 + c * 1024;
    ushort4 o;
    o.x = f2bf(vv[c*4+0] * s * gnw[i + 0]);
    o.y = f2bf(vv[c*4+1] * s * gnw[i + 1]);
    o.z = f2bf(vv[c*4+2] * s * gnw[i + 2]);
    o.w = f2bf(vv[c*4+3] * s * gnw[i + 3]);
    *(ushort4*)&yn[po + i] = o;
  }
}

// ---------------- launch ----------------
extern "C" void kernel_launch(void* const* d_in, const int* in_sizes, int n_in,
                              void* d_out, int out_size, void* d_ws, size_t ws_size,
                              hipStream_t stream) {
  const float* hidden  = (const float*)d_in[0];
  const float* norm_w  = (const float*)d_in[1];
  const float* w1      = (const float*)d_in[2];
  const float* convw   = (const float*)d_in[3];
  const float* convb   = (const float*)d_in[4];
  const float* dt_bias = (const float*)d_in[5];
  const float* A_log   = (const float*)d_in[6];
  const float* Dv      = (const float*)d_in[7];
  const float* gnw     = (const float*)d_in[8];
  const float* w2      = (const float*)d_in[9];
  float* out = (float*)d_out;

  char* ws = (char*)d_ws;
  size_t off = 0;
  auto alloc = [&](size_t bytes) {
    void* p = ws + off;
    off += (bytes + 255) & ~(size_t)255;
    return p;
  };
  unsigned short* XN  = (unsigned short*)alloc((size_t)BS * HID * 2);      // 16.8 MB
  unsigned short* W1B = (unsigned short*)alloc((size_t)PROJ * HID * 2);    // 34.9 MB
  unsigned short* W2B = (unsigned short*)alloc((size_t)HID * INTER * 2);   // 16.8 MB
  unsigned short* PRJ = (unsigned short*)alloc((size_t)BS * PROJ * 2);     // 69.7 MB
  unsigned short* CVO = (unsigned short*)alloc((size_t)BS * CONV_DIM * 2); // 35.7 MB
  float2*         DTS = (float2*)alloc((size_t)BS * HEADS * 8);            //  2.1 MB
  unsigned short* YP  = XN;                    // overlay: XN+W1B dead after GEMM1
  unsigned short* YN  = PRJ + YN_COL;          // in-row overlay, stride PROJ
  if (off > ws_size) return;
  (void)in_sizes; (void)n_in; (void)out_size;

  int n1 = PROJ * HID / 4;
  cast_bf16_kernel<<<(n1 + 255) / 256, 256, 0, stream>>>((const float4*)w1, (ushort4*)W1B, n1);
  int n2 = HID * INTER / 4;
  cast_bf16_kernel<<<(n2 + 255) / 256, 256, 0, stream>>>((const float4*)w2, (ushort4*)W2B, n2);

  rmsnorm_in_kernel<<<BS, 256, 0, stream>>>(hidden, norm_w, XN);

  // GEMM1: [4096 x 8512] = XN[4096 x 2048] * W1B^T ; 16 x 67 = 1072 blocks
  gemm128n_kernel<<<dim3((BS / 256) * ((PROJ + 127) / 128)), 512, 0, stream>>>(
      XN, HID, W1B, nullptr, PRJ, PROJ, BS, PROJ, HID, nullptr);

  // conv: 34*64 = 2176 blocks + dt: 1024 blocks
  conv_dt_kernel<<<(CONV_DIM / CONV_BC) * (BS / CONV_BS) + (BS * HEADS) / 256, 256, 0, stream>>>(
      PRJ, convw, convb, dt_bias, A_log, CVO, DTS);

  ssd_scan_kernel<<<256, 512, 0, stream>>>(CVO, DTS, YP);

  gated_norm_kernel<<<BS, 256, 0, stream>>>(YP, CVO, PRJ, Dv, gnw, YN);

  // GEMM2: [4096 x 2048] = YN[4096 x 4096] * W2B^T + residual ; 16 x 16 = 256 blocks (1 round)
  gemm128n_kernel<<<dim3((BS / 256) * (HID / 128)), 512, 0, stream>>>(
      YN, PROJ, W2B, out, nullptr, HID, BS, HID, INTER, hidden);
}

// Round 4
// 587.847 us; speedup vs baseline: 1.2783x; 1.0197x over previous
//
#include <hip/hip_runtime.h>
#include <math.h>

#define HID      2048
#define STATE    128
#define HEADS    64
#define HEADDIM  64
#define INTER    4096
#define CONV_DIM 4352
#define PROJ     8512
#define NBATCH   2
#define SEQ      2048
#define BS       (NBATCH*SEQ)   /* 4096 token rows */
#define EPS      1e-5f
#define YN_COL   4160           /* YN lives in PRJ cols [4160, 8256) after conv/dt are dead */

typedef __attribute__((ext_vector_type(8))) short short8;
typedef __attribute__((ext_vector_type(4))) float f32x4;

__device__ inline unsigned short f2bf(float f) {
  union { float f; unsigned int u; } v; v.f = f;
  unsigned int r = v.u + 0x7fffu + ((v.u >> 16) & 1u);   // RNE
  return (unsigned short)(r >> 16);
}
__device__ inline float bf2f(unsigned short b) {
  union { unsigned int u; float f; } v; v.u = ((unsigned int)b) << 16;
  return v.f;
}

// ---------------- f32 -> bf16 cast (weights) ----------------
__global__ __launch_bounds__(256)
void cast_bf16_kernel(const float4* __restrict__ src, ushort4* __restrict__ dst, int n4) {
  int i = blockIdx.x * 256 + threadIdx.x;
  if (i >= n4) return;
  float4 v = src[i];
  ushort4 o;
  o.x = f2bf(v.x); o.y = f2bf(v.y); o.z = f2bf(v.z); o.w = f2bf(v.w);
  dst[i] = o;
}

// ---------------- input RMSNorm -> bf16 ----------------
__global__ __launch_bounds__(256)
void rmsnorm_in_kernel(const float* __restrict__ x, const float* __restrict__ w,
                       unsigned short* __restrict__ xn) {
  int row = blockIdx.x;
  int t = threadIdx.x;
  const float* xr = x + (size_t)row * HID;
  float4 a = ((const float4*)xr)[t];
  float4 b = ((const float4*)xr)[t + 256];
  float ss = a.x*a.x + a.y*a.y + a.z*a.z + a.w*a.w
           + b.x*b.x + b.y*b.y + b.z*b.z + b.w*b.w;
  for (int o = 32; o > 0; o >>= 1) ss += __shfl_down(ss, o);
  __shared__ float red[4];
  __shared__ float scl;
  if ((t & 63) == 0) red[t >> 6] = ss;
  __syncthreads();
  if (t == 0) scl = rsqrtf((red[0]+red[1]+red[2]+red[3]) / (float)HID + EPS);
  __syncthreads();
  float s = scl;
  float4 w0 = ((const float4*)w)[t];
  float4 w1 = ((const float4*)w)[t + 256];
  ushort4 o0, o1;
  o0.x = f2bf(a.x*s*w0.x); o0.y = f2bf(a.y*s*w0.y); o0.z = f2bf(a.z*s*w0.z); o0.w = f2bf(a.w*s*w0.w);
  o1.x = f2bf(b.x*s*w1.x); o1.y = f2bf(b.y*s*w1.y); o1.z = f2bf(b.z*s*w1.z); o1.w = f2bf(b.w*s*w1.w);
  ushort4* dst = (ushort4*)(xn + (size_t)row * HID);
  dst[t] = o0;
  dst[t + 256] = o1;
}

// ---------------- 128x128 / BK=64 / 4-wave / 8-phase / 2-blocks-per-CU bf16 BT-GEMM ----
// C[M,N] = A[M,K] * B[N,K]^T.  Same T2 swizzle + counted-vmcnt phase skeleton, shrunk to
// 64 KiB LDS so TWO independent blocks co-reside per CU: block A's barrier/lgkm drain is
// covered by block B's MFMAs (attacks the ~35% lockstep ceiling seen at 1 block/CU).
// 4 waves (2Mx2N), per-wave C = 64x64. One 8KB half-tile stage per phase; vmcnt(4) at
// p3/p7 (12 in flight, oldest 8 = the tile needed next must land). Stage targets only
// regions whose last ds_read was >=1 phase earlier (verified per quadrant).

__device__ __forceinline__ void stage_half64(const unsigned short* __restrict__ G, int ld,
                                             int row0, int rmax, int kt,
                                             unsigned short* lbase, int half, int t) {
  // half-tile = 64 rows x 64 cols bf16 = 8 KB = 512 x 16B chunks; 2 loads/thread (256 thr).
  // LDS linear; global source column pre-swizzled: chunk (rl, sl) <- col (sl ^ (rl&7)).
  const int w = t >> 6;
#pragma unroll
  for (int it = 0; it < 2; ++it) {
    int id = it * 256 + t;          // chunk id 0..511
    int rl = id >> 3;               // local row 0..63
    int sl = id & 7;                // 16B slot 0..7
    int grow = row0 + half * 64 + rl;
    if (grow > rmax) grow = rmax;
    const unsigned short* g = G + (size_t)grow * ld + kt * 64 + ((sl ^ (rl & 7)) << 3);
    unsigned short* l = lbase + half * (64 * 64) + (it * 256 + w * 64) * 8;  // wave-uniform
    __builtin_amdgcn_global_load_lds((const __attribute__((address_space(1))) void*)g,
                                     (__attribute__((address_space(3))) void*)l, 16, 0, 0);
  }
}

#define VMW4 asm volatile("s_waitcnt vmcnt(4)" ::: "memory")

#define PHASE(BUF, MH, NH, RA, RB, STG, VMW_)                                        \
  {                                                                                  \
    const unsigned short* bufA = lds + (BUF)*16384;                                  \
    const unsigned short* bufB = lds + (BUF)*16384 + 8192;                           \
    if (RA) {                                                                        \
      _Pragma("unroll")                                                              \
      for (int ml = 0; ml < 2; ++ml) {                                               \
        _Pragma("unroll")                                                            \
        for (int kk = 0; kk < 2; ++kk) {                                             \
          const int r = wr*64 + (MH)*32 + ml*16 + tq;                                \
          aR[ml][kk] = *(const short8*)(bufA + r*64 + (((kk<<2)|quad)^(r&7))*8);     \
        }                                                                            \
      }                                                                              \
    }                                                                                \
    if (RB) {                                                                        \
      _Pragma("unroll")                                                              \
      for (int nl = 0; nl < 2; ++nl) {                                               \
        _Pragma("unroll")                                                            \
        for (int kk = 0; kk < 2; ++kk) {                                             \
          const int r = wc*64 + (NH)*32 + nl*16 + tq;                                \
          bR[NH][nl][kk] = *(const short8*)(bufB + r*64 + (((kk<<2)|quad)^(r&7))*8); \
        }                                                                            \
      }                                                                              \
    }                                                                                \
    STG;                                                                             \
    __builtin_amdgcn_s_barrier();                                                    \
    asm volatile("s_waitcnt lgkmcnt(0)" ::: "memory");                               \
    __builtin_amdgcn_sched_barrier(0);                                               \
    __builtin_amdgcn_s_setprio(1);                                                   \
    _Pragma("unroll")                                                                \
    for (int ml = 0; ml < 2; ++ml) {                                                 \
      _Pragma("unroll")                                                              \
      for (int nl = 0; nl < 2; ++nl) {                                               \
        _Pragma("unroll")                                                            \
        for (int kk = 0; kk < 2; ++kk) {                                             \
          acc[(MH)*2+ml][(NH)*2+nl] = __builtin_amdgcn_mfma_f32_16x16x32_bf16(       \
              aR[ml][kk], bR[NH][nl][kk], acc[(MH)*2+ml][(NH)*2+nl], 0, 0, 0);       \
        }                                                                            \
      }                                                                              \
    }                                                                                \
    __builtin_amdgcn_s_setprio(0);                                                   \
    VMW_;                                                                            \
    __builtin_amdgcn_s_barrier();                                                    \
  }

__global__ __launch_bounds__(256, 2)
void gemm128_kernel(const unsigned short* __restrict__ A, int lda,
                    const unsigned short* __restrict__ B,
                    float* __restrict__ Cf, unsigned short* __restrict__ Cb, int ldc,
                    int M, int N, int Kd, const float* __restrict__ residual) {
  __shared__ unsigned short lds[32768];   // 64 KiB: [buf][A(128x64)|B(128x64)] x2
  const int t = threadIdx.x;
  const int lane = t & 63;
  const int quad = lane >> 4;
  const int tq = lane & 15;
  const int w = t >> 6;
  const int wr = w >> 1;    // 2 M-waves x 2 N-waves; per-wave C = 64x64
  const int wc = w & 1;

  // T1: bijective XCD swizzle + 8Mx8N brick map (64 tiles = per-XCD concurrency @2/CU)
  const int Mtiles = M >> 7;           // 32 for both call sites
  const int Ntiles = (N + 127) >> 7;
  const int nwg = (int)gridDim.x;
  const int cpx = nwg >> 3;            // nwg % 8 == 0 for both call sites
  const int bid = (int)blockIdx.x;
  const int sw = (bid & 7) * cpx + (bid >> 3);
  const int NBfull = Ntiles & ~7;
  int m0, n0;
  if (sw < Mtiles * NBfull) {
    int brick = sw >> 6;               // 64 tiles per 8x8 brick
    int inner = sw & 63;               // m-fastest within brick
    int bm = brick % (Mtiles >> 3);
    int bn = brick / (Mtiles >> 3);
    m0 = (bm * 8 + (inner & 7)) << 7;
    n0 = (bn * 8 + (inner >> 3)) << 7;
  } else {                             // ragged n-tail: m-major
    int r = sw - Mtiles * NBfull;
    m0 = (r % Mtiles) << 7;
    n0 = (NBfull + r / Mtiles) << 7;
  }

  f32x4 acc[4][4];
#pragma unroll
  for (int i = 0; i < 4; ++i)
#pragma unroll
    for (int j = 0; j < 4; ++j) acc[i][j] = (f32x4){0.f, 0.f, 0.f, 0.f};

  short8 aR[2][2];      // current MH half: 2 m-frags x 2 k-steps
  short8 bR[2][2][2];   // both NH halves kept live: [NH][nl][kk]

  unsigned short* A0 = lds;
  unsigned short* B0 = lds + 8192;
  unsigned short* A1 = lds + 16384;
  unsigned short* B1 = lds + 24576;

  const int kIters = Kd >> 6;      // K-tiles of 64 (even for K=2048/4096)
  const int nIter  = kIters >> 1;

  // prologue: tile 0 (A0,B0) fully + B(1) both halves pre-issued (steady-state p6/p7 image)
  stage_half64(A, lda, m0, M - 1, 0, A0, 0, t);
  stage_half64(A, lda, m0, M - 1, 0, A0, 1, t);
  stage_half64(B, Kd,  n0, N - 1, 0, B0, 0, t);
  stage_half64(B, Kd,  n0, N - 1, 0, B0, 1, t);
  stage_half64(B, Kd,  n0, N - 1, 1, B1, 0, t);
  stage_half64(B, Kd,  n0, N - 1, 1, B1, 1, t);
  VMW4;                              // tile0's 8 loads done; B(1)'s 4 may stay in flight
  __builtin_amdgcn_s_barrier();

  for (int i = 0; i < nIter; ++i) {
    const int k1 = 2 * i + 1;
    int k2 = 2 * i + 2; if (k2 > kIters - 1) k2 = kIters - 1;   // tail: harmless re-stage
    int k3 = 2 * i + 3; if (k3 > kIters - 1) k3 = kIters - 1;
    // phases 0-3: compute K-tile 2i (buf0); stage A(k1)->A1, B(k2)->B0
    PHASE(0, 0, 0, 1, 1, stage_half64(A, lda, m0, M - 1, k1, A1, 0, t), ((void)0))
    PHASE(0, 0, 1, 0, 1, stage_half64(A, lda, m0, M - 1, k1, A1, 1, t), ((void)0))
    PHASE(0, 1, 1, 1, 0, stage_half64(B, Kd,  n0, N - 1, k2, B0, 0, t), ((void)0))
    PHASE(0, 1, 0, 0, 0, stage_half64(B, Kd,  n0, N - 1, k2, B0, 1, t), VMW4)
    // phases 4-7: compute K-tile 2i+1 (buf1); stage A(k2)->A0, B(k3)->B1
    PHASE(1, 0, 0, 1, 1, stage_half64(A, lda, m0, M - 1, k2, A0, 0, t), ((void)0))
    PHASE(1, 0, 1, 0, 1, stage_half64(A, lda, m0, M - 1, k2, A0, 1, t), ((void)0))
    PHASE(1, 1, 1, 1, 0, stage_half64(B, Kd,  n0, N - 1, k3, B1, 0, t), ((void)0))
    PHASE(1, 1, 0, 0, 0, stage_half64(B, Kd,  n0, N - 1, k3, B1, 1, t), VMW4)
  }
  asm volatile("s_waitcnt vmcnt(0)" ::: "memory");   // drain LDS-DMA before exit

#pragma unroll
  for (int mf = 0; mf < 4; ++mf) {
    const int rowb = m0 + wr * 64 + mf * 16 + quad * 4;
#pragma unroll
    for (int nf = 0; nf < 4; ++nf) {
      const int col = n0 + wc * 64 + nf * 16 + tq;
      if (col < N) {
        if (Cb) {
#pragma unroll
          for (int r = 0; r < 4; ++r)
            Cb[(size_t)(rowb + r) * ldc + col] = f2bf(acc[mf][nf][r]);
        } else {
#pragma unroll
          for (int r = 0; r < 4; ++r) {
            size_t idx = (size_t)(rowb + r) * N + col;
            float v = acc[mf][nf][r];
            if (residual) v += residual[idx];
            Cf[idx] = v;
          }
        }
      }
    }
  }
}

// ---------------- fused causal conv(K=4)+SiLU (LDS row-tiled) and dt=softplus ----------------
// Block covers 64 s-rows x 128 channels; stages 67 input rows once into LDS
// (read amplification 4x -> 1.05x). c8 is constant per thread -> conv weights in regs.
#define CONV_BC 128
#define CONV_BS 64
#define CXS 136   /* padded LDS row stride (shorts): +4 banks per row */

__global__ __launch_bounds__(256)
void conv_dt_kernel(const unsigned short* __restrict__ proj, const float* __restrict__ cw,
                    const float* __restrict__ cb, const float* __restrict__ dtb,
                    const float* __restrict__ A_log,
                    unsigned short* __restrict__ convo, float2* __restrict__ dts) {
  const int NCB = CONV_DIM / CONV_BC;            // 34 channel-blocks
  const int NCONVB = NCB * (BS / CONV_BS);       // 34*64 = 2176 conv blocks
  int blk = blockIdx.x;
  int t = threadIdx.x;
  if (blk < NCONVB) {
    __shared__ unsigned short xs[67 * CXS];
    int cblk = blk % NCB;
    int rblk = blk / NCB;
    int ch0 = cblk * CONV_BC;
    int rs0 = rblk * CONV_BS;                    // global token row (b*SEQ+s)
    int s0 = rs0 & (SEQ - 1);
    // per-thread fixed channel group
    const int c8 = t & 15;                       // tasks stride 256 => c8 const
    const int co = c8 * 8;
    float cwr[4][8], cbr[8];
#pragma unroll
    for (int e = 0; e < 8; e++) {
      cbr[e] = cb[ch0 + co + e];
#pragma unroll
      for (int k = 0; k < 4; k++) cwr[k][e] = cw[(ch0 + co + e) * 4 + k];
    }
    // stage rows s0-3 .. s0+63 (67 rows x 128 ch)
    for (int i = t; i < 67 * 16; i += 256) {
      int row = i >> 4, sl = i & 15;
      short8 v;
      if (s0 == 0 && row < 3) v = (short8){0,0,0,0,0,0,0,0};
      else v = *(const short8*)&proj[(size_t)(rs0 - 3 + row) * PROJ + INTER + ch0 + sl * 8];
      *(short8*)&xs[row * CXS + sl * 8] = v;
    }
    __syncthreads();
    // compute: row r needs LDS rows r..r+3 (tap k at row r+k)
#pragma unroll
    for (int it = 0; it < 4; ++it) {
      int r = (t >> 4) + it * 16;
      float acc[8];
#pragma unroll
      for (int e = 0; e < 8; e++) acc[e] = cbr[e];
#pragma unroll
      for (int k = 0; k < 4; k++) {
        short8 v = *(const short8*)&xs[(r + k) * CXS + co];
#pragma unroll
        for (int e = 0; e < 8; e++) acc[e] += bf2f((unsigned short)v[e]) * cwr[k][e];
      }
      short8 o;
#pragma unroll
      for (int e = 0; e < 8; e++) {
        float a = acc[e];
        o[e] = (short)f2bf(a / (1.f + expf(-a)));   // SiLU
      }
      *(short8*)&convo[(size_t)(rs0 + r) * CONV_DIM + ch0 + co] = o;
    }
  } else {
    int k = (blk - NCONVB) * 256 + t;
    if (k < BS * HEADS) {
      int h  = k & 63;
      int rs = k >> 6;
      float x = bf2f(proj[(size_t)rs * PROJ + INTER + CONV_DIM + h]) + dtb[h];
      float dt = (x > 20.f) ? x : log1pf(expf(x));
      float Ah = -expf(A_log[h]);
      dts[k] = make_float2(dt, dt * Ah);   // {dt, log-decay increment}
    }
  }
}

// ---------------- SSD chunked scan (MFMA), 8 waves: Y-path || S-path ----------------
// T14 async-stage: next chunk's global reads issued right after S1 (held in regs),
// written to LDS after the following B0 -> HBM latency hides under compute.
#define LCH 64
#define CST 136   /* row stride (shorts) for Cst/Bst/Sb */
#define TST 72    /* row stride (shorts) for Btt/xtT/Msh */

__global__ __launch_bounds__(512)
void ssd_scan_kernel(const unsigned short* __restrict__ convo, const float2* __restrict__ dts,
                     unsigned short* __restrict__ yp) {
  __shared__ unsigned short Cst[64 * CST];
  __shared__ unsigned short Bst[64 * CST];
  __shared__ unsigned short Btt[128 * TST];   // B transposed [n][j]
  __shared__ unsigned short xtT[32 * TST];    // x transposed [p_local][j]
  __shared__ unsigned short Msh[64 * TST];    // masked decay-weighted G [i][j]
  __shared__ unsigned short Sb[2][32 * CST];  // state bf16 [p_local][n], double-buffered
  __shared__ float dtaL[64], dtvL[64];

  const int ph = blockIdx.x & 1;
  const int h  = (blockIdx.x >> 1) & 63;
  const int b  = blockIdx.x >> 7;
  const int t  = threadIdx.x;
  const int wv = t >> 6;
  const int lane = t & 63;
  const int quad = lane >> 4;
  const int tq   = lane & 15;
  const size_t row0 = (size_t)b * SEQ;
  const int xcol = h * 64 + ph * 32;

  for (int i = t; i < 32 * CST; i += 512) Sb[0][i] = 0;

  // S-wave (wv>=4) persistent state accumulators
  f32x4 s_acc[4];
#pragma unroll
  for (int c = 0; c < 4; c++) s_acc[c] = (f32x4){0.f, 0.f, 0.f, 0.f};
  const int pt  = wv & 1;               // S-wave p-tile (0/1)
  const int ntb = ((wv >> 1) & 1) * 4;  // S-wave n-tile base (x16)

  // ---- prefetch chunk 0 into registers ----
  short8 vb_r[2], vc_r[2]; ushort4 vx_r; float2 dv_r = make_float2(0.f, 0.f);
  {
#pragma unroll
    for (int it = 0; it < 2; ++it) {
      int id = t + 512 * it;
      int row = id >> 4, cc = id & 15;
      size_t g = (row0 + row) * CONV_DIM + INTER;
      vb_r[it] = *(const short8*)&convo[g + cc * 8];
      vc_r[it] = *(const short8*)&convo[g + STATE + cc * 8];
    }
    int row = t >> 3, c = t & 7;
    vx_r = *(const ushort4*)&convo[(row0 + row) * CONV_DIM + xcol + c * 4];
    if (t < 64) dv_r = dts[((row0 + t) << 6) + h];
  }

  int pp = 0;
  for (int c0 = 0; c0 < SEQ; c0 += LCH, pp ^= 1) {
    __syncthreads();   // B0: prior chunk's compute reads done before restaging
    // ---- write register-staged B, C, B^T, x^T, dt into LDS ----
#pragma unroll
    for (int it = 0; it < 2; ++it) {
      int id = t + 512 * it;
      int row = id >> 4, cc = id & 15;
      *(short8*)&Bst[row * CST + cc * 8] = vb_r[it];
      *(short8*)&Cst[row * CST + cc * 8] = vc_r[it];
#pragma unroll
      for (int e = 0; e < 8; e++)
        Btt[(cc * 8 + e) * TST + row] = (unsigned short)vb_r[it][e];
    }
    {
      int row = t >> 3, c = t & 7;
      xtT[(c * 4 + 0) * TST + row] = vx_r.x;
      xtT[(c * 4 + 1) * TST + row] = vx_r.y;
      xtT[(c * 4 + 2) * TST + row] = vx_r.z;
      xtT[(c * 4 + 3) * TST + row] = vx_r.w;
    }
    if (t < 64) { dtvL[t] = dv_r.x; dtaL[t] = dv_r.y; }
    __syncthreads();   // S1: staging visible

    // ---- issue next chunk's global loads (latency hides under compute) ----
    if (c0 + LCH < SEQ) {
#pragma unroll
      for (int it = 0; it < 2; ++it) {
        int id = t + 512 * it;
        int row = id >> 4, cc = id & 15;
        size_t g = (row0 + c0 + LCH + row) * CONV_DIM + INTER;
        vb_r[it] = *(const short8*)&convo[g + cc * 8];
        vc_r[it] = *(const short8*)&convo[g + STATE + cc * 8];
      }
      int row = t >> 3, c = t & 7;
      vx_r = *(const ushort4*)&convo[(row0 + c0 + LCH + row) * CONV_DIM + xcol + c * 4];
      if (t < 64) dv_r = dts[((row0 + c0 + LCH + t) << 6) + h];
    }

    // ---- per-wave cumulative log-decay scan (lane l holds cum[l]) ----
    float v = dtaL[lane];
#pragma unroll
    for (int off = 1; off < 64; off <<= 1) {
      float u = __shfl_up(v, off);
      if (lane >= off) v += u;
    }
    float tot = __shfl(v, 63);

    if (wv < 4) {
      // ================= Y-path =================
      short8 afC[4];
#pragma unroll
      for (int kt = 0; kt < 4; kt++)
        afC[kt] = *(const short8*)&Cst[(16 * wv + tq) * CST + kt * 32 + quad * 8];
      f32x4 g_acc[4];
#pragma unroll
      for (int nj = 0; nj < 4; nj++) g_acc[nj] = (f32x4){0.f, 0.f, 0.f, 0.f};
#pragma unroll
      for (int kt = 0; kt < 4; kt++) {
#pragma unroll
        for (int nj = 0; nj < 4; nj++) {
          short8 bfr = *(const short8*)&Bst[(16 * nj + tq) * CST + kt * 32 + quad * 8];
          g_acc[nj] = __builtin_amdgcn_mfma_f32_16x16x32_bf16(afC[kt], bfr, g_acc[nj], 0, 0, 0);
        }
      }
      float ci[4], pex[4];
#pragma unroll
      for (int r = 0; r < 4; r++) {
        ci[r] = __shfl(v, 16 * wv + quad * 4 + r);
        pex[r] = expf(ci[r]);
      }
#pragma unroll
      for (int nj = 0; nj < 4; nj++) {
        int j = 16 * nj + tq;
        float cj = __shfl(v, j);
        float dj = dtvL[j];
#pragma unroll
        for (int r = 0; r < 4; r++) {
          int i = 16 * wv + quad * 4 + r;
          float val = (j <= i) ? g_acc[nj][r] * expf(ci[r] - cj) * dj : 0.f;
          Msh[i * TST + j] = f2bf(val);
        }
      }
      // Y = Pex*(C*Sb^T) + Ms*x^T
      f32x4 yac[2];
      yac[0] = (f32x4){0.f, 0.f, 0.f, 0.f};
      yac[1] = (f32x4){0.f, 0.f, 0.f, 0.f};
#pragma unroll
      for (int kt = 0; kt < 4; kt++) {
#pragma unroll
        for (int np = 0; np < 2; np++) {
          short8 bs = *(const short8*)&Sb[pp][(16 * np + tq) * CST + kt * 32 + quad * 8];
          yac[np] = __builtin_amdgcn_mfma_f32_16x16x32_bf16(afC[kt], bs, yac[np], 0, 0, 0);
        }
      }
#pragma unroll
      for (int np = 0; np < 2; np++)
#pragma unroll
        for (int r = 0; r < 4; r++) yac[np][r] *= pex[r];
#pragma unroll
      for (int kt2 = 0; kt2 < 2; kt2++) {
        short8 am = *(const short8*)&Msh[(16 * wv + tq) * TST + kt2 * 32 + quad * 8];
#pragma unroll
        for (int np = 0; np < 2; np++) {
          short8 bx = *(const short8*)&xtT[(16 * np + tq) * TST + kt2 * 32 + quad * 8];
          yac[np] = __builtin_amdgcn_mfma_f32_16x16x32_bf16(am, bx, yac[np], 0, 0, 0);
        }
      }
#pragma unroll
      for (int np = 0; np < 2; np++) {
#pragma unroll
        for (int r = 0; r < 4; r++) {
          int i = 16 * wv + quad * 4 + r;
          int p = ph * 32 + 16 * np + tq;
          yp[(row0 + c0 + i) * INTER + h * 64 + p] = f2bf(yac[np][r]);
        }
      }
    } else {
      // ================= S-path =================
      float ptot = expf(tot);
      short8 ax[2];
#pragma unroll
      for (int kt2 = 0; kt2 < 2; kt2++) {
        short8 xv = *(const short8*)&xtT[(16 * pt + tq) * TST + kt2 * 32 + quad * 8];
#pragma unroll
        for (int e = 0; e < 8; e++) {
          int j = kt2 * 32 + quad * 8 + e;
          float cj = __shfl(v, j);
          float wj = expf(tot - cj) * dtvL[j];
          ax[kt2][e] = (short)f2bf(bf2f((unsigned short)xv[e]) * wj);
        }
      }
#pragma unroll
      for (int c = 0; c < 4; c++)
#pragma unroll
        for (int r = 0; r < 4; r++) s_acc[c][r] *= ptot;
#pragma unroll
      for (int kt2 = 0; kt2 < 2; kt2++) {
#pragma unroll
        for (int c = 0; c < 4; c++) {
          short8 bb = *(const short8*)&Btt[(16 * (ntb + c) + tq) * TST + kt2 * 32 + quad * 8];
          s_acc[c] = __builtin_amdgcn_mfma_f32_16x16x32_bf16(ax[kt2], bb, s_acc[c], 0, 0, 0);
        }
      }
#pragma unroll
      for (int c = 0; c < 4; c++)
#pragma unroll
        for (int r = 0; r < 4; r++) {
          int p = 16 * pt + quad * 4 + r;
          int n = 16 * (ntb + c) + tq;
          Sb[pp ^ 1][p * CST + n] = f2bf(s_acc[c][r]);
        }
    }
    // next chunk's B0 protects Sb[pp^1] writes before Y reads them
  }
}

// ---------------- y = yp + D*x; gated RMSNorm -> bf16 (registers, no LDS buf) ----------------
__global__ __launch_bounds__(256)
void gated_norm_kernel(const unsigned short* __restrict__ yp,
                       const unsigned short* __restrict__ convo, const unsigned short* __restrict__ proj,
                       const float* __restrict__ Dv, const float* __restrict__ gnw,
                       unsigned short* __restrict__ yn) {
  int row = blockIdx.x;
  int t = threadIdx.x;
  __shared__ float red[4];
  __shared__ float scl;
  size_t yo = (size_t)row * INTER;
  size_t co = (size_t)row * CONV_DIM;
  size_t po = (size_t)row * PROJ;
  float vv[16];
  float ss = 0.f;
#pragma unroll
  for (int c = 0; c < 4; c++) {
    int i = t * 4 + c * 1024;
    ushort4 y0 = *(const ushort4*)&yp[yo + i];
    ushort4 xs = *(const ushort4*)&convo[co + i];
    ushort4 g  = *(const ushort4*)&proj[po + i];
    float Dh = Dv[i >> 6];
    float yv[4] = { bf2f(y0.x) + Dh * bf2f(xs.x),
                    bf2f(y0.y) + Dh * bf2f(xs.y),
                    bf2f(y0.z) + Dh * bf2f(xs.z),
                    bf2f(y0.w) + Dh * bf2f(xs.w) };
    float gv[4] = { bf2f(g.x), bf2f(g.y), bf2f(g.z), bf2f(g.w) };
#pragma unroll
    for (int k = 0; k < 4; k++) {
      float val = yv[k] * (gv[k] / (1.f + expf(-gv[k])));
      vv[c * 4 + k] = val;
      ss += val * val;
    }
  }
  for (int o = 32; o > 0; o >>= 1) ss += __shfl_down(ss, o);
  if ((t & 63) == 0) red[t >> 6] = ss;
  __syncthreads();
  if (t == 0) scl = rsqrtf((red[0]+red[1]+red[2]+red[3]) / (float)INTER + EPS);
  __syncthreads();
  float s = scl;
#pragma unroll
  for (int c = 0; c < 4; c++) {
    int i = t * 4 + c * 1024;
    ushort4 o;
    o.x = f2bf(vv[c*4+0] * s * gnw[i + 0]);
    o.y = f2bf(vv[c*4+1] * s * gnw[i + 1]);
    o.z = f2bf(vv[c*4+2] * s * gnw[i + 2]);
    o.w = f2bf(vv[c*4+3] * s * gnw[i + 3]);
    *(ushort4*)&yn[po + i] = o;
  }
}

// ---------------- launch ----------------
extern "C" void kernel_launch(void* const* d_in, const int* in_sizes, int n_in,
                              void* d_out, int out_size, void* d_ws, size_t ws_size,
                              hipStream_t stream) {
  const float* hidden  = (const float*)d_in[0];
  const float* norm_w  = (const float*)d_in[1];
  const float* w1      = (const float*)d_in[2];
  const float* convw   = (const float*)d_in[3];
  const float* convb   = (const float*)d_in[4];
  const float* dt_bias = (const float*)d_in[5];
  const float* A_log   = (const float*)d_in[6];
  const float* Dv      = (const float*)d_in[7];
  const float* gnw     = (const float*)d_in[8];
  const float* w2      = (const float*)d_in[9];
  float* out = (float*)d_out;

  char* ws = (char*)d_ws;
  size_t off = 0;
  auto alloc = [&](size_t bytes) {
    void* p = ws + off;
    off += (bytes + 255) & ~(size_t)255;
    return p;
  };
  unsigned short* XN  = (unsigned short*)alloc((size_t)BS * HID * 2);      // 16.8 MB
  unsigned short* W1B = (unsigned short*)alloc((size_t)PROJ * HID * 2);    // 34.9 MB
  unsigned short* W2B = (unsigned short*)alloc((size_t)HID * INTER * 2);   // 16.8 MB
  unsigned short* PRJ = (unsigned short*)alloc((size_t)BS * PROJ * 2);     // 69.7 MB
  unsigned short* CVO = (unsigned short*)alloc((size_t)BS * CONV_DIM * 2); // 35.7 MB
  float2*         DTS = (float2*)alloc((size_t)BS * HEADS * 8);            //  2.1 MB
  unsigned short* YP  = XN;                    // overlay: XN+W1B dead after GEMM1
  unsigned short* YN  = PRJ + YN_COL;          // in-row overlay, stride PROJ
  if (off > ws_size) return;
  (void)in_sizes; (void)n_in; (void)out_size;

  int n1 = PROJ * HID / 4;
  cast_bf16_kernel<<<(n1 + 255) / 256, 256, 0, stream>>>((const float4*)w1, (ushort4*)W1B, n1);
  int n2 = HID * INTER / 4;
  cast_bf16_kernel<<<(n2 + 255) / 256, 256, 0, stream>>>((const float4*)w2, (ushort4*)W2B, n2);

  rmsnorm_in_kernel<<<BS, 256, 0, stream>>>(hidden, norm_w, XN);

  // GEMM1: [4096 x 8512] = XN[4096 x 2048] * W1B^T ; 32 x 67 = 2144 blocks (2144 % 8 == 0)
  gemm128_kernel<<<dim3((BS / 128) * ((PROJ + 127) / 128)), 256, 0, stream>>>(
      XN, HID, W1B, nullptr, PRJ, PROJ, BS, PROJ, HID, nullptr);

  // conv: 34*64 = 2176 blocks + dt: 1024 blocks
  conv_dt_kernel<<<(CONV_DIM / CONV_BC) * (BS / CONV_BS) + (BS * HEADS) / 256, 256, 0, stream>>>(
      PRJ, convw, convb, dt_bias, A_log, CVO, DTS);

  ssd_scan_kernel<<<256, 512, 0, stream>>>(CVO, DTS, YP);

  gated_norm_kernel<<<BS, 256, 0, stream>>>(YP, CVO, PRJ, Dv, gnw, YN);

  // GEMM2: [4096 x 2048] = YN[4096 x 4096] * W2B^T + residual ; 32 x 16 = 512 blocks (1 round @2/CU)
  gemm128_kernel<<<dim3((BS / 128) * (HID / 128)), 256, 0, stream>>>(
      YN, PROJ, W2B, out, nullptr, HID, BS, HID, INTER, hidden);
}

// Round 5
// 558.273 us; speedup vs baseline: 1.3460x; 1.0530x over previous
//
#include <hip/hip_runtime.h>
#include <math.h>

#define HID      2048
#define STATE    128
#define HEADS    64
#define HEADDIM  64
#define INTER    4096
#define CONV_DIM 4352
#define PROJ     8512
#define NBATCH   2
#define SEQ      2048
#define BS       (NBATCH*SEQ)   /* 4096 token rows */
#define EPS      1e-5f
#define YN_COL   4160           /* YN lives in PRJ cols [4160, 8256) after conv/dt are dead */

typedef __attribute__((ext_vector_type(8))) short short8;
typedef __attribute__((ext_vector_type(4))) float f32x4;

__device__ inline unsigned short f2bf(float f) {
  union { float f; unsigned int u; } v; v.f = f;
  unsigned int r = v.u + 0x7fffu + ((v.u >> 16) & 1u);   // RNE
  return (unsigned short)(r >> 16);
}
__device__ inline float bf2f(unsigned short b) {
  union { unsigned int u; float f; } v; v.u = ((unsigned int)b) << 16;
  return v.f;
}

// ---------------- f32 -> bf16 cast (weights) ----------------
__global__ __launch_bounds__(256)
void cast_bf16_kernel(const float4* __restrict__ src, ushort4* __restrict__ dst, int n4) {
  int i = blockIdx.x * 256 + threadIdx.x;
  if (i >= n4) return;
  float4 v = src[i];
  ushort4 o;
  o.x = f2bf(v.x); o.y = f2bf(v.y); o.z = f2bf(v.z); o.w = f2bf(v.w);
  dst[i] = o;
}

// ---------------- input RMSNorm -> bf16 ----------------
__global__ __launch_bounds__(256)
void rmsnorm_in_kernel(const float* __restrict__ x, const float* __restrict__ w,
                       unsigned short* __restrict__ xn) {
  int row = blockIdx.x;
  int t = threadIdx.x;
  const float* xr = x + (size_t)row * HID;
  float4 a = ((const float4*)xr)[t];
  float4 b = ((const float4*)xr)[t + 256];
  float ss = a.x*a.x + a.y*a.y + a.z*a.z + a.w*a.w
           + b.x*b.x + b.y*b.y + b.z*b.z + b.w*b.w;
  for (int o = 32; o > 0; o >>= 1) ss += __shfl_down(ss, o);
  __shared__ float red[4];
  __shared__ float scl;
  if ((t & 63) == 0) red[t >> 6] = ss;
  __syncthreads();
  if (t == 0) scl = rsqrtf((red[0]+red[1]+red[2]+red[3]) / (float)HID + EPS);
  __syncthreads();
  float s = scl;
  float4 w0 = ((const float4*)w)[t];
  float4 w1 = ((const float4*)w)[t + 256];
  ushort4 o0, o1;
  o0.x = f2bf(a.x*s*w0.x); o0.y = f2bf(a.y*s*w0.y); o0.z = f2bf(a.z*s*w0.z); o0.w = f2bf(a.w*s*w0.w);
  o1.x = f2bf(b.x*s*w1.x); o1.y = f2bf(b.y*s*w1.y); o1.z = f2bf(b.z*s*w1.z); o1.w = f2bf(b.w*s*w1.w);
  ushort4* dst = (ushort4*)(xn + (size_t)row * HID);
  dst[t] = o0;
  dst[t + 256] = o1;
}

// ---------------- 128x128 / BK=64 / 4-wave / 8-phase / 2-blocks-per-CU bf16 BT-GEMM ----
// (unchanged from round 4 — verified: removed GEMM from the top-5)

__device__ __forceinline__ void stage_half64(const unsigned short* __restrict__ G, int ld,
                                             int row0, int rmax, int kt,
                                             unsigned short* lbase, int half, int t) {
  const int w = t >> 6;
#pragma unroll
  for (int it = 0; it < 2; ++it) {
    int id = it * 256 + t;          // chunk id 0..511
    int rl = id >> 3;               // local row 0..63
    int sl = id & 7;                // 16B slot 0..7
    int grow = row0 + half * 64 + rl;
    if (grow > rmax) grow = rmax;
    const unsigned short* g = G + (size_t)grow * ld + kt * 64 + ((sl ^ (rl & 7)) << 3);
    unsigned short* l = lbase + half * (64 * 64) + (it * 256 + w * 64) * 8;  // wave-uniform
    __builtin_amdgcn_global_load_lds((const __attribute__((address_space(1))) void*)g,
                                     (__attribute__((address_space(3))) void*)l, 16, 0, 0);
  }
}

#define VMW4 asm volatile("s_waitcnt vmcnt(4)" ::: "memory")

#define PHASE(BUF, MH, NH, RA, RB, STG, VMW_)                                        \
  {                                                                                  \
    const unsigned short* bufA = lds + (BUF)*16384;                                  \
    const unsigned short* bufB = lds + (BUF)*16384 + 8192;                           \
    if (RA) {                                                                        \
      _Pragma("unroll")                                                              \
      for (int ml = 0; ml < 2; ++ml) {                                               \
        _Pragma("unroll")                                                            \
        for (int kk = 0; kk < 2; ++kk) {                                             \
          const int r = wr*64 + (MH)*32 + ml*16 + tq;                                \
          aR[ml][kk] = *(const short8*)(bufA + r*64 + (((kk<<2)|quad)^(r&7))*8);     \
        }                                                                            \
      }                                                                              \
    }                                                                                \
    if (RB) {                                                                        \
      _Pragma("unroll")                                                              \
      for (int nl = 0; nl < 2; ++nl) {                                               \
        _Pragma("unroll")                                                            \
        for (int kk = 0; kk < 2; ++kk) {                                             \
          const int r = wc*64 + (NH)*32 + nl*16 + tq;                                \
          bR[NH][nl][kk] = *(const short8*)(bufB + r*64 + (((kk<<2)|quad)^(r&7))*8); \
        }                                                                            \
      }                                                                              \
    }                                                                                \
    STG;                                                                             \
    __builtin_amdgcn_s_barrier();                                                    \
    asm volatile("s_waitcnt lgkmcnt(0)" ::: "memory");                               \
    __builtin_amdgcn_sched_barrier(0);                                               \
    __builtin_amdgcn_s_setprio(1);                                                   \
    _Pragma("unroll")                                                                \
    for (int ml = 0; ml < 2; ++ml) {                                                 \
      _Pragma("unroll")                                                              \
      for (int nl = 0; nl < 2; ++nl) {                                               \
        _Pragma("unroll")                                                            \
        for (int kk = 0; kk < 2; ++kk) {                                             \
          acc[(MH)*2+ml][(NH)*2+nl] = __builtin_amdgcn_mfma_f32_16x16x32_bf16(       \
              aR[ml][kk], bR[NH][nl][kk], acc[(MH)*2+ml][(NH)*2+nl], 0, 0, 0);       \
        }                                                                            \
      }                                                                              \
    }                                                                                \
    __builtin_amdgcn_s_setprio(0);                                                   \
    VMW_;                                                                            \
    __builtin_amdgcn_s_barrier();                                                    \
  }

__global__ __launch_bounds__(256, 2)
void gemm128_kernel(const unsigned short* __restrict__ A, int lda,
                    const unsigned short* __restrict__ B,
                    float* __restrict__ Cf, unsigned short* __restrict__ Cb, int ldc,
                    int M, int N, int Kd, const float* __restrict__ residual) {
  __shared__ unsigned short lds[32768];   // 64 KiB: [buf][A(128x64)|B(128x64)] x2
  const int t = threadIdx.x;
  const int lane = t & 63;
  const int quad = lane >> 4;
  const int tq = lane & 15;
  const int w = t >> 6;
  const int wr = w >> 1;    // 2 M-waves x 2 N-waves; per-wave C = 64x64
  const int wc = w & 1;

  const int Mtiles = M >> 7;
  const int Ntiles = (N + 127) >> 7;
  const int nwg = (int)gridDim.x;
  const int cpx = nwg >> 3;
  const int bid = (int)blockIdx.x;
  const int sw = (bid & 7) * cpx + (bid >> 3);
  const int NBfull = Ntiles & ~7;
  int m0, n0;
  if (sw < Mtiles * NBfull) {
    int brick = sw >> 6;               // 64 tiles per 8x8 brick
    int inner = sw & 63;
    int bm = brick % (Mtiles >> 3);
    int bn = brick / (Mtiles >> 3);
    m0 = (bm * 8 + (inner & 7)) << 7;
    n0 = (bn * 8 + (inner >> 3)) << 7;
  } else {
    int r = sw - Mtiles * NBfull;
    m0 = (r % Mtiles) << 7;
    n0 = (NBfull + r / Mtiles) << 7;
  }

  f32x4 acc[4][4];
#pragma unroll
  for (int i = 0; i < 4; ++i)
#pragma unroll
    for (int j = 0; j < 4; ++j) acc[i][j] = (f32x4){0.f, 0.f, 0.f, 0.f};

  short8 aR[2][2];
  short8 bR[2][2][2];

  unsigned short* A0 = lds;
  unsigned short* B0 = lds + 8192;
  unsigned short* A1 = lds + 16384;
  unsigned short* B1 = lds + 24576;

  const int kIters = Kd >> 6;
  const int nIter  = kIters >> 1;

  stage_half64(A, lda, m0, M - 1, 0, A0, 0, t);
  stage_half64(A, lda, m0, M - 1, 0, A0, 1, t);
  stage_half64(B, Kd,  n0, N - 1, 0, B0, 0, t);
  stage_half64(B, Kd,  n0, N - 1, 0, B0, 1, t);
  stage_half64(B, Kd,  n0, N - 1, 1, B1, 0, t);
  stage_half64(B, Kd,  n0, N - 1, 1, B1, 1, t);
  VMW4;
  __builtin_amdgcn_s_barrier();

  for (int i = 0; i < nIter; ++i) {
    const int k1 = 2 * i + 1;
    int k2 = 2 * i + 2; if (k2 > kIters - 1) k2 = kIters - 1;
    int k3 = 2 * i + 3; if (k3 > kIters - 1) k3 = kIters - 1;
    PHASE(0, 0, 0, 1, 1, stage_half64(A, lda, m0, M - 1, k1, A1, 0, t), ((void)0))
    PHASE(0, 0, 1, 0, 1, stage_half64(A, lda, m0, M - 1, k1, A1, 1, t), ((void)0))
    PHASE(0, 1, 1, 1, 0, stage_half64(B, Kd,  n0, N - 1, k2, B0, 0, t), ((void)0))
    PHASE(0, 1, 0, 0, 0, stage_half64(B, Kd,  n0, N - 1, k2, B0, 1, t), VMW4)
    PHASE(1, 0, 0, 1, 1, stage_half64(A, lda, m0, M - 1, k2, A0, 0, t), ((void)0))
    PHASE(1, 0, 1, 0, 1, stage_half64(A, lda, m0, M - 1, k2, A0, 1, t), ((void)0))
    PHASE(1, 1, 1, 1, 0, stage_half64(B, Kd,  n0, N - 1, k3, B1, 0, t), ((void)0))
    PHASE(1, 1, 0, 0, 0, stage_half64(B, Kd,  n0, N - 1, k3, B1, 1, t), VMW4)
  }
  asm volatile("s_waitcnt vmcnt(0)" ::: "memory");

#pragma unroll
  for (int mf = 0; mf < 4; ++mf) {
    const int rowb = m0 + wr * 64 + mf * 16 + quad * 4;
#pragma unroll
    for (int nf = 0; nf < 4; ++nf) {
      const int col = n0 + wc * 64 + nf * 16 + tq;
      if (col < N) {
        if (Cb) {
#pragma unroll
          for (int r = 0; r < 4; ++r)
            Cb[(size_t)(rowb + r) * ldc + col] = f2bf(acc[mf][nf][r]);
        } else {
#pragma unroll
          for (int r = 0; r < 4; ++r) {
            size_t idx = (size_t)(rowb + r) * N + col;
            float v = acc[mf][nf][r];
            if (residual) v += residual[idx];
            Cf[idx] = v;
          }
        }
      }
    }
  }
}

// ---------------- fused causal conv(K=4)+SiLU (LDS row-tiled) and dt=softplus ----------------
#define CONV_BC 128
#define CONV_BS 64
#define CXS 136   /* padded LDS row stride (shorts) */

__global__ __launch_bounds__(256)
void conv_dt_kernel(const unsigned short* __restrict__ proj, const float* __restrict__ cw,
                    const float* __restrict__ cb, const float* __restrict__ dtb,
                    const float* __restrict__ A_log,
                    unsigned short* __restrict__ convo, float2* __restrict__ dts) {
  const int NCB = CONV_DIM / CONV_BC;            // 34 channel-blocks
  const int NCONVB = NCB * (BS / CONV_BS);       // 2176 conv blocks
  int blk = blockIdx.x;
  int t = threadIdx.x;
  if (blk < NCONVB) {
    __shared__ unsigned short xs[67 * CXS];
    int cblk = blk % NCB;
    int rblk = blk / NCB;
    int ch0 = cblk * CONV_BC;
    int rs0 = rblk * CONV_BS;
    int s0 = rs0 & (SEQ - 1);
    const int c8 = t & 15;
    const int co = c8 * 8;
    float cwr[4][8], cbr[8];
#pragma unroll
    for (int e = 0; e < 8; e++) {
      cbr[e] = cb[ch0 + co + e];
#pragma unroll
      for (int k = 0; k < 4; k++) cwr[k][e] = cw[(ch0 + co + e) * 4 + k];
    }
    for (int i = t; i < 67 * 16; i += 256) {
      int row = i >> 4, sl = i & 15;
      short8 v;
      if (s0 == 0 && row < 3) v = (short8){0,0,0,0,0,0,0,0};
      else v = *(const short8*)&proj[(size_t)(rs0 - 3 + row) * PROJ + INTER + ch0 + sl * 8];
      *(short8*)&xs[row * CXS + sl * 8] = v;
    }
    __syncthreads();
#pragma unroll
    for (int it = 0; it < 4; ++it) {
      int r = (t >> 4) + it * 16;
      float acc[8];
#pragma unroll
      for (int e = 0; e < 8; e++) acc[e] = cbr[e];
#pragma unroll
      for (int k = 0; k < 4; k++) {
        short8 v = *(const short8*)&xs[(r + k) * CXS + co];
#pragma unroll
        for (int e = 0; e < 8; e++) acc[e] += bf2f((unsigned short)v[e]) * cwr[k][e];
      }
      short8 o;
#pragma unroll
      for (int e = 0; e < 8; e++) {
        float a = acc[e];
        o[e] = (short)f2bf(a / (1.f + expf(-a)));   // SiLU
      }
      *(short8*)&convo[(size_t)(rs0 + r) * CONV_DIM + ch0 + co] = o;
    }
  } else {
    int k = (blk - NCONVB) * 256 + t;
    if (k < BS * HEADS) {
      int h  = k & 63;
      int rs = k >> 6;
      float x = bf2f(proj[(size_t)rs * PROJ + INTER + CONV_DIM + h]) + dtb[h];
      float dt = (x > 20.f) ? x : log1pf(expf(x));
      float Ah = -expf(A_log[h]);
      dts[k] = make_float2(dt, dt * Ah);   // {dt, log-decay increment}
    }
  }
}

// ---------------- SSD chunked scan (MFMA), 8 waves: Y-path || S-path ----------------
// Layout fix vs round 4: Bst/Cst/Sb use power-of-2 row stride (128 sh) + chunk-XOR
// swizzle (T2) -> all b128 reads & short8 staging writes at bank floor. The 32-way-
// conflicted Btt scalar scatter is replaced by a cooperative post-S1 transpose pass
// (conflict-free scalar reads from swizzled Bst + swizzled short8 writes) + S2 barrier.
// 3 barriers/chunk. Arithmetic identical to round 4.
#define LCH 64
#define SR  128   /* row stride (shorts) for Cst/Bst/Sb (chunk-XOR swizzled) */
#define BR  64    /* row stride (shorts) for Btt (chunk-XOR swizzled) */
#define TST 72    /* row stride (shorts) for xtT/Msh (unchanged) */
#define SWZ(r,c) ((((c) ^ ((r) & 7)) << 3))

__global__ __launch_bounds__(512)
void ssd_scan_kernel(const unsigned short* __restrict__ convo, const float2* __restrict__ dts,
                     unsigned short* __restrict__ yp) {
  __shared__ unsigned short Cst[64 * SR];
  __shared__ unsigned short Bst[64 * SR];
  __shared__ unsigned short Btt[128 * BR];    // B transposed [n][j], built post-S1
  __shared__ unsigned short xtT[32 * TST];    // x transposed [p_local][j]
  __shared__ unsigned short Msh[64 * TST];    // masked decay-weighted G [i][j]
  __shared__ unsigned short Sb[2][32 * SR];   // state bf16 [p_local][n], double-buffered
  __shared__ float dtaL[64], dtvL[64];

  const int ph = blockIdx.x & 1;
  const int h  = (blockIdx.x >> 1) & 63;
  const int b  = blockIdx.x >> 7;
  const int t  = threadIdx.x;
  const int wv = t >> 6;
  const int lane = t & 63;
  const int quad = lane >> 4;
  const int tq   = lane & 15;
  const size_t row0 = (size_t)b * SEQ;
  const int xcol = h * 64 + ph * 32;

  for (int i = t; i < 32 * SR; i += 512) Sb[0][i] = 0;

  f32x4 s_acc[4];
#pragma unroll
  for (int c = 0; c < 4; c++) s_acc[c] = (f32x4){0.f, 0.f, 0.f, 0.f};
  const int pt  = wv & 1;
  const int ntb = ((wv >> 1) & 1) * 4;

  // ---- prefetch chunk 0 into registers (T14) ----
  short8 vb_r[2], vc_r[2]; ushort4 vx_r; float2 dv_r = make_float2(0.f, 0.f);
  {
#pragma unroll
    for (int it = 0; it < 2; ++it) {
      int id = t + 512 * it;
      int row = id >> 4, cc = id & 15;
      size_t g = (row0 + row) * CONV_DIM + INTER;
      vb_r[it] = *(const short8*)&convo[g + cc * 8];
      vc_r[it] = *(const short8*)&convo[g + STATE + cc * 8];
    }
    int row = t >> 3, c = t & 7;
    vx_r = *(const ushort4*)&convo[(row0 + row) * CONV_DIM + xcol + c * 4];
    if (t < 64) dv_r = dts[((row0 + t) << 6) + h];
  }

  int pp = 0;
  for (int c0 = 0; c0 < SEQ; c0 += LCH, pp ^= 1) {
    __syncthreads();   // B0: prior chunk's compute reads done before restaging
    // ---- write register-staged B, C (swizzled), x^T, dt into LDS ----
#pragma unroll
    for (int it = 0; it < 2; ++it) {
      int id = t + 512 * it;
      int row = id >> 4, cc = id & 15;
      *(short8*)&Bst[row * SR + SWZ(row, cc)] = vb_r[it];
      *(short8*)&Cst[row * SR + SWZ(row, cc)] = vc_r[it];
    }
    {
      int row = t >> 3, c = t & 7;
      xtT[(c * 4 + 0) * TST + row] = vx_r.x;
      xtT[(c * 4 + 1) * TST + row] = vx_r.y;
      xtT[(c * 4 + 2) * TST + row] = vx_r.z;
      xtT[(c * 4 + 3) * TST + row] = vx_r.w;
    }
    if (t < 64) { dtvL[t] = dv_r.x; dtaL[t] = dv_r.y; }
    __syncthreads();   // S1: staging visible

    // ---- cooperative Btt build from Bst (conflict-free under SWZ) ----
#pragma unroll
    for (int bi = 0; bi < 2; ++bi) {
      int q = t + 512 * bi;
      int n = q & 127, jc = q >> 7;          // 128 n-rows x 8 j-chunks
      short8 o;
#pragma unroll
      for (int s = 0; s < 8; ++s)
        o[s] = (short)Bst[(jc * 8 + s) * SR + SWZ(jc * 8 + s, n >> 3) + (n & 7)];
      *(short8*)&Btt[n * BR + SWZ(n, jc)] = o;
    }

    // ---- issue next chunk's global loads (latency hides under compute) ----
    if (c0 + LCH < SEQ) {
#pragma unroll
      for (int it = 0; it < 2; ++it) {
        int id = t + 512 * it;
        int row = id >> 4, cc = id & 15;
        size_t g = (row0 + c0 + LCH + row) * CONV_DIM + INTER;
        vb_r[it] = *(const short8*)&convo[g + cc * 8];
        vc_r[it] = *(const short8*)&convo[g + STATE + cc * 8];
      }
      int row = t >> 3, c = t & 7;
      vx_r = *(const ushort4*)&convo[(row0 + c0 + LCH + row) * CONV_DIM + xcol + c * 4];
      if (t < 64) dv_r = dts[((row0 + c0 + LCH + t) << 6) + h];
    }

    // ---- per-wave cumulative log-decay scan ----
    float v = dtaL[lane];
#pragma unroll
    for (int off = 1; off < 64; off <<= 1) {
      float u = __shfl_up(v, off);
      if (lane >= off) v += u;
    }
    float tot = __shfl(v, 63);

    __syncthreads();   // S2: Btt visible

    if (wv < 4) {
      // ================= Y-path =================
      short8 afC[4];
#pragma unroll
      for (int kt = 0; kt < 4; kt++)
        afC[kt] = *(const short8*)&Cst[(16 * wv + tq) * SR + SWZ(16 * wv + tq, kt * 4 + quad)];
      f32x4 g_acc[4];
#pragma unroll
      for (int nj = 0; nj < 4; nj++) g_acc[nj] = (f32x4){0.f, 0.f, 0.f, 0.f};
#pragma unroll
      for (int kt = 0; kt < 4; kt++) {
#pragma unroll
        for (int nj = 0; nj < 4; nj++) {
          short8 bfr = *(const short8*)&Bst[(16 * nj + tq) * SR + SWZ(16 * nj + tq, kt * 4 + quad)];
          g_acc[nj] = __builtin_amdgcn_mfma_f32_16x16x32_bf16(afC[kt], bfr, g_acc[nj], 0, 0, 0);
        }
      }
      float ci[4], pex[4];
#pragma unroll
      for (int r = 0; r < 4; r++) {
        ci[r] = __shfl(v, 16 * wv + quad * 4 + r);
        pex[r] = expf(ci[r]);
      }
#pragma unroll
      for (int nj = 0; nj < 4; nj++) {
        int j = 16 * nj + tq;
        float cj = __shfl(v, j);
        float dj = dtvL[j];
#pragma unroll
        for (int r = 0; r < 4; r++) {
          int i = 16 * wv + quad * 4 + r;
          float val = (j <= i) ? g_acc[nj][r] * expf(ci[r] - cj) * dj : 0.f;
          Msh[i * TST + j] = f2bf(val);
        }
      }
      // Y = Pex*(C*Sb^T) + Ms*x^T
      f32x4 yac[2];
      yac[0] = (f32x4){0.f, 0.f, 0.f, 0.f};
      yac[1] = (f32x4){0.f, 0.f, 0.f, 0.f};
#pragma unroll
      for (int kt = 0; kt < 4; kt++) {
#pragma unroll
        for (int np = 0; np < 2; np++) {
          short8 bs = *(const short8*)&Sb[pp][(16 * np + tq) * SR + SWZ(16 * np + tq, kt * 4 + quad)];
          yac[np] = __builtin_amdgcn_mfma_f32_16x16x32_bf16(afC[kt], bs, yac[np], 0, 0, 0);
        }
      }
#pragma unroll
      for (int np = 0; np < 2; np++)
#pragma unroll
        for (int r = 0; r < 4; r++) yac[np][r] *= pex[r];
#pragma unroll
      for (int kt2 = 0; kt2 < 2; kt2++) {
        short8 am = *(const short8*)&Msh[(16 * wv + tq) * TST + kt2 * 32 + quad * 8];
#pragma unroll
        for (int np = 0; np < 2; np++) {
          short8 bx = *(const short8*)&xtT[(16 * np + tq) * TST + kt2 * 32 + quad * 8];
          yac[np] = __builtin_amdgcn_mfma_f32_16x16x32_bf16(am, bx, yac[np], 0, 0, 0);
        }
      }
#pragma unroll
      for (int np = 0; np < 2; np++) {
#pragma unroll
        for (int r = 0; r < 4; r++) {
          int i = 16 * wv + quad * 4 + r;
          int p = ph * 32 + 16 * np + tq;
          yp[(row0 + c0 + i) * INTER + h * 64 + p] = f2bf(yac[np][r]);
        }
      }
    } else {
      // ================= S-path =================
      float ptot = expf(tot);
      short8 ax[2];
#pragma unroll
      for (int kt2 = 0; kt2 < 2; kt2++) {
        short8 xv = *(const short8*)&xtT[(16 * pt + tq) * TST + kt2 * 32 + quad * 8];
#pragma unroll
        for (int e = 0; e < 8; e++) {
          int j = kt2 * 32 + quad * 8 + e;
          float cj = __shfl(v, j);
          float wj = expf(tot - cj) * dtvL[j];
          ax[kt2][e] = (short)f2bf(bf2f((unsigned short)xv[e]) * wj);
        }
      }
#pragma unroll
      for (int c = 0; c < 4; c++)
#pragma unroll
        for (int r = 0; r < 4; r++) s_acc[c][r] *= ptot;
#pragma unroll
      for (int kt2 = 0; kt2 < 2; kt2++) {
#pragma unroll
        for (int c = 0; c < 4; c++) {
          short8 bb = *(const short8*)&Btt[(16 * (ntb + c) + tq) * BR + SWZ(16 * (ntb + c) + tq, kt2 * 4 + quad)];
          s_acc[c] = __builtin_amdgcn_mfma_f32_16x16x32_bf16(ax[kt2], bb, s_acc[c], 0, 0, 0);
        }
      }
#pragma unroll
      for (int c = 0; c < 4; c++)
#pragma unroll
        for (int r = 0; r < 4; r++) {
          int p = 16 * pt + quad * 4 + r;
          int n = 16 * (ntb + c) + tq;
          Sb[pp ^ 1][p * SR + SWZ(p, n >> 3) + (n & 7)] = f2bf(s_acc[c][r]);
        }
    }
    // next chunk's B0 protects Sb[pp^1] writes before Y reads them
  }
}

// ---------------- y = yp + D*x; gated RMSNorm -> bf16 (registers, no LDS buf) ----------------
__global__ __launch_bounds__(256)
void gated_norm_kernel(const unsigned short* __restrict__ yp,
                       const unsigned short* __restrict__ convo, const unsigned short* __restrict__ proj,
                       const float* __restrict__ Dv, const float* __restrict__ gnw,
                       unsigned short* __restrict__ yn) {
  int row = blockIdx.x;
  int t = threadIdx.x;
  __shared__ float red[4];
  __shared__ float scl;
  size_t yo = (size_t)row * INTER;
  size_t co = (size_t)row * CONV_DIM;
  size_t po = (size_t)row * PROJ;
  float vv[16];
  float ss = 0.f;
#pragma unroll
  for (int c = 0; c < 4; c++) {
    int i = t * 4 + c * 1024;
    ushort4 y0 = *(const ushort4*)&yp[yo + i];
    ushort4 xs = *(const ushort4*)&convo[co + i];
    ushort4 g  = *(const ushort4*)&proj[po + i];
    float Dh = Dv[i >> 6];
    float yv[4] = { bf2f(y0.x) + Dh * bf2f(xs.x),
                    bf2f(y0.y) + Dh * bf2f(xs.y),
                    bf2f(y0.z) + Dh * bf2f(xs.z),
                    bf2f(y0.w) + Dh * bf2f(xs.w) };
    float gv[4] = { bf2f(g.x), bf2f(g.y), bf2f(g.z), bf2f(g.w) };
#pragma unroll
    for (int k = 0; k < 4; k++) {
      float val = yv[k] * (gv[k] / (1.f + expf(-gv[k])));
      vv[c * 4 + k] = val;
      ss += val * val;
    }
  }
  for (int o = 32; o > 0; o >>= 1) ss += __shfl_down(ss, o);
  if ((t & 63) == 0) red[t >> 6] = ss;
  __syncthreads();
  if (t == 0) scl = rsqrtf((red[0]+red[1]+red[2]+red[3]) / (float)INTER + EPS);
  __syncthreads();
  float s = scl;
#pragma unroll
  for (int c = 0; c < 4; c++) {
    int i = t * 4 + c * 1024;
    ushort4 o;
    o.x = f2bf(vv[c*4+0] * s * gnw[i + 0]);
    o.y = f2bf(vv[c*4+1] * s * gnw[i + 1]);
    o.z = f2bf(vv[c*4+2] * s * gnw[i + 2]);
    o.w = f2bf(vv[c*4+3] * s * gnw[i + 3]);
    *(ushort4*)&yn[po + i] = o;
  }
}

// ---------------- launch ----------------
extern "C" void kernel_launch(void* const* d_in, const int* in_sizes, int n_in,
                              void* d_out, int out_size, void* d_ws, size_t ws_size,
                              hipStream_t stream) {
  const float* hidden  = (const float*)d_in[0];
  const float* norm_w  = (const float*)d_in[1];
  const float* w1      = (const float*)d_in[2];
  const float* convw   = (const float*)d_in[3];
  const float* convb   = (const float*)d_in[4];
  const float* dt_bias = (const float*)d_in[5];
  const float* A_log   = (const float*)d_in[6];
  const float* Dv      = (const float*)d_in[7];
  const float* gnw     = (const float*)d_in[8];
  const float* w2      = (const float*)d_in[9];
  float* out = (float*)d_out;

  char* ws = (char*)d_ws;
  size_t off = 0;
  auto alloc = [&](size_t bytes) {
    void* p = ws + off;
    off += (bytes + 255) & ~(size_t)255;
    return p;
  };
  unsigned short* XN  = (unsigned short*)alloc((size_t)BS * HID * 2);      // 16.8 MB
  unsigned short* W1B = (unsigned short*)alloc((size_t)PROJ * HID * 2);    // 34.9 MB
  unsigned short* W2B = (unsigned short*)alloc((size_t)HID * INTER * 2);   // 16.8 MB
  unsigned short* PRJ = (unsigned short*)alloc((size_t)BS * PROJ * 2);     // 69.7 MB
  unsigned short* CVO = (unsigned short*)alloc((size_t)BS * CONV_DIM * 2); // 35.7 MB
  float2*         DTS = (float2*)alloc((size_t)BS * HEADS * 8);            //  2.1 MB
  unsigned short* YP  = XN;                    // overlay: XN+W1B dead after GEMM1
  unsigned short* YN  = PRJ + YN_COL;          // in-row overlay, stride PROJ
  if (off > ws_size) return;
  (void)in_sizes; (void)n_in; (void)out_size;

  int n1 = PROJ * HID / 4;
  cast_bf16_kernel<<<(n1 + 255) / 256, 256, 0, stream>>>((const float4*)w1, (ushort4*)W1B, n1);
  int n2 = HID * INTER / 4;
  cast_bf16_kernel<<<(n2 + 255) / 256, 256, 0, stream>>>((const float4*)w2, (ushort4*)W2B, n2);

  rmsnorm_in_kernel<<<BS, 256, 0, stream>>>(hidden, norm_w, XN);

  // GEMM1: [4096 x 8512] = XN[4096 x 2048] * W1B^T ; 32 x 67 = 2144 blocks
  gemm128_kernel<<<dim3((BS / 128) * ((PROJ + 127) / 128)), 256, 0, stream>>>(
      XN, HID, W1B, nullptr, PRJ, PROJ, BS, PROJ, HID, nullptr);

  conv_dt_kernel<<<(CONV_DIM / CONV_BC) * (BS / CONV_BS) + (BS * HEADS) / 256, 256, 0, stream>>>(
      PRJ, convw, convb, dt_bias, A_log, CVO, DTS);

  ssd_scan_kernel<<<256, 512, 0, stream>>>(CVO, DTS, YP);

  gated_norm_kernel<<<BS, 256, 0, stream>>>(YP, CVO, PRJ, Dv, gnw, YN);

  // GEMM2: [4096 x 2048] = YN[4096 x 4096] * W2B^T + residual ; 32 x 16 = 512 blocks
  gemm128_kernel<<<dim3((BS / 128) * (HID / 128)), 256, 0, stream>>>(
      YN, PROJ, W2B, out, nullptr, HID, BS, HID, INTER, hidden);
}

// Round 6
// 532.094 us; speedup vs baseline: 1.4122x; 1.0492x over previous
//
#include <hip/hip_runtime.h>
#include <math.h>

#define HID      2048
#define STATE    128
#define HEADS    64
#define HEADDIM  64
#define INTER    4096
#define CONV_DIM 4352
#define PROJ     8512
#define NBATCH   2
#define SEQ      2048
#define BS       (NBATCH*SEQ)   /* 4096 token rows */
#define EPS      1e-5f
#define YN_COL   4160           /* YN lives in PRJ cols [4160, 8256) after conv/dt are dead */

typedef __attribute__((ext_vector_type(8))) short short8;
typedef __attribute__((ext_vector_type(4))) float f32x4;

__device__ inline unsigned short f2bf(float f) {
  union { float f; unsigned int u; } v; v.f = f;
  unsigned int r = v.u + 0x7fffu + ((v.u >> 16) & 1u);   // RNE
  return (unsigned short)(r >> 16);
}
__device__ inline float bf2f(unsigned short b) {
  union { unsigned int u; float f; } v; v.u = ((unsigned int)b) << 16;
  return v.f;
}

// ---------------- f32 -> bf16 cast (weights) ----------------
__global__ __launch_bounds__(256)
void cast_bf16_kernel(const float4* __restrict__ src, ushort4* __restrict__ dst, int n4) {
  int i = blockIdx.x * 256 + threadIdx.x;
  if (i >= n4) return;
  float4 v = src[i];
  ushort4 o;
  o.x = f2bf(v.x); o.y = f2bf(v.y); o.z = f2bf(v.z); o.w = f2bf(v.w);
  dst[i] = o;
}

// ---------------- input RMSNorm -> bf16 ----------------
__global__ __launch_bounds__(256)
void rmsnorm_in_kernel(const float* __restrict__ x, const float* __restrict__ w,
                       unsigned short* __restrict__ xn) {
  int row = blockIdx.x;
  int t = threadIdx.x;
  const float* xr = x + (size_t)row * HID;
  float4 a = ((const float4*)xr)[t];
  float4 b = ((const float4*)xr)[t + 256];
  float ss = a.x*a.x + a.y*a.y + a.z*a.z + a.w*a.w
           + b.x*b.x + b.y*b.y + b.z*b.z + b.w*b.w;
  for (int o = 32; o > 0; o >>= 1) ss += __shfl_down(ss, o);
  __shared__ float red[4];
  __shared__ float scl;
  if ((t & 63) == 0) red[t >> 6] = ss;
  __syncthreads();
  if (t == 0) scl = rsqrtf((red[0]+red[1]+red[2]+red[3]) / (float)HID + EPS);
  __syncthreads();
  float s = scl;
  float4 w0 = ((const float4*)w)[t];
  float4 w1 = ((const float4*)w)[t + 256];
  ushort4 o0, o1;
  o0.x = f2bf(a.x*s*w0.x); o0.y = f2bf(a.y*s*w0.y); o0.z = f2bf(a.z*s*w0.z); o0.w = f2bf(a.w*s*w0.w);
  o1.x = f2bf(b.x*s*w1.x); o1.y = f2bf(b.y*s*w1.y); o1.z = f2bf(b.z*s*w1.z); o1.w = f2bf(b.w*s*w1.w);
  ushort4* dst = (ushort4*)(xn + (size_t)row * HID);
  dst[t] = o0;
  dst[t + 256] = o1;
}

// ---------------- 128x128 / BK=64 / 4-wave / 8-phase / 2-blocks-per-CU bf16 BT-GEMM ----
// (unchanged from round 5)

__device__ __forceinline__ void stage_half64(const unsigned short* __restrict__ G, int ld,
                                             int row0, int rmax, int kt,
                                             unsigned short* lbase, int half, int t) {
  const int w = t >> 6;
#pragma unroll
  for (int it = 0; it < 2; ++it) {
    int id = it * 256 + t;          // chunk id 0..511
    int rl = id >> 3;               // local row 0..63
    int sl = id & 7;                // 16B slot 0..7
    int grow = row0 + half * 64 + rl;
    if (grow > rmax) grow = rmax;
    const unsigned short* g = G + (size_t)grow * ld + kt * 64 + ((sl ^ (rl & 7)) << 3);
    unsigned short* l = lbase + half * (64 * 64) + (it * 256 + w * 64) * 8;  // wave-uniform
    __builtin_amdgcn_global_load_lds((const __attribute__((address_space(1))) void*)g,
                                     (__attribute__((address_space(3))) void*)l, 16, 0, 0);
  }
}

#define VMW4 asm volatile("s_waitcnt vmcnt(4)" ::: "memory")

#define PHASE(BUF, MH, NH, RA, RB, STG, VMW_)                                        \
  {                                                                                  \
    const unsigned short* bufA = lds + (BUF)*16384;                                  \
    const unsigned short* bufB = lds + (BUF)*16384 + 8192;                           \
    if (RA) {                                                                        \
      _Pragma("unroll")                                                              \
      for (int ml = 0; ml < 2; ++ml) {                                               \
        _Pragma("unroll")                                                            \
        for (int kk = 0; kk < 2; ++kk) {                                             \
          const int r = wr*64 + (MH)*32 + ml*16 + tq;                                \
          aR[ml][kk] = *(const short8*)(bufA + r*64 + (((kk<<2)|quad)^(r&7))*8);     \
        }                                                                            \
      }                                                                              \
    }                                                                                \
    if (RB) {                                                                        \
      _Pragma("unroll")                                                              \
      for (int nl = 0; nl < 2; ++nl) {                                               \
        _Pragma("unroll")                                                            \
        for (int kk = 0; kk < 2; ++kk) {                                             \
          const int r = wc*64 + (NH)*32 + nl*16 + tq;                                \
          bR[NH][nl][kk] = *(const short8*)(bufB + r*64 + (((kk<<2)|quad)^(r&7))*8); \
        }                                                                            \
      }                                                                              \
    }                                                                                \
    STG;                                                                             \
    __builtin_amdgcn_s_barrier();                                                    \
    asm volatile("s_waitcnt lgkmcnt(0)" ::: "memory");                               \
    __builtin_amdgcn_sched_barrier(0);                                               \
    __builtin_amdgcn_s_setprio(1);                                                   \
    _Pragma("unroll")                                                                \
    for (int ml = 0; ml < 2; ++ml) {                                                 \
      _Pragma("unroll")                                                              \
      for (int nl = 0; nl < 2; ++nl) {                                               \
        _Pragma("unroll")                                                            \
        for (int kk = 0; kk < 2; ++kk) {                                             \
          acc[(MH)*2+ml][(NH)*2+nl] = __builtin_amdgcn_mfma_f32_16x16x32_bf16(       \
              aR[ml][kk], bR[NH][nl][kk], acc[(MH)*2+ml][(NH)*2+nl], 0, 0, 0);       \
        }                                                                            \
      }                                                                              \
    }                                                                                \
    __builtin_amdgcn_s_setprio(0);                                                   \
    VMW_;                                                                            \
    __builtin_amdgcn_s_barrier();                                                    \
  }

__global__ __launch_bounds__(256, 2)
void gemm128_kernel(const unsigned short* __restrict__ A, int lda,
                    const unsigned short* __restrict__ B,
                    float* __restrict__ Cf, unsigned short* __restrict__ Cb, int ldc,
                    int M, int N, int Kd, const float* __restrict__ residual) {
  __shared__ unsigned short lds[32768];   // 64 KiB: [buf][A(128x64)|B(128x64)] x2
  const int t = threadIdx.x;
  const int lane = t & 63;
  const int quad = lane >> 4;
  const int tq = lane & 15;
  const int w = t >> 6;
  const int wr = w >> 1;    // 2 M-waves x 2 N-waves; per-wave C = 64x64
  const int wc = w & 1;

  const int Mtiles = M >> 7;
  const int Ntiles = (N + 127) >> 7;
  const int nwg = (int)gridDim.x;
  const int cpx = nwg >> 3;
  const int bid = (int)blockIdx.x;
  const int sw = (bid & 7) * cpx + (bid >> 3);
  const int NBfull = Ntiles & ~7;
  int m0, n0;
  if (sw < Mtiles * NBfull) {
    int brick = sw >> 6;               // 64 tiles per 8x8 brick
    int inner = sw & 63;
    int bm = brick % (Mtiles >> 3);
    int bn = brick / (Mtiles >> 3);
    m0 = (bm * 8 + (inner & 7)) << 7;
    n0 = (bn * 8 + (inner >> 3)) << 7;
  } else {
    int r = sw - Mtiles * NBfull;
    m0 = (r % Mtiles) << 7;
    n0 = (NBfull + r / Mtiles) << 7;
  }

  f32x4 acc[4][4];
#pragma unroll
  for (int i = 0; i < 4; ++i)
#pragma unroll
    for (int j = 0; j < 4; ++j) acc[i][j] = (f32x4){0.f, 0.f, 0.f, 0.f};

  short8 aR[2][2];
  short8 bR[2][2][2];

  unsigned short* A0 = lds;
  unsigned short* B0 = lds + 8192;
  unsigned short* A1 = lds + 16384;
  unsigned short* B1 = lds + 24576;

  const int kIters = Kd >> 6;
  const int nIter  = kIters >> 1;

  stage_half64(A, lda, m0, M - 1, 0, A0, 0, t);
  stage_half64(A, lda, m0, M - 1, 0, A0, 1, t);
  stage_half64(B, Kd,  n0, N - 1, 0, B0, 0, t);
  stage_half64(B, Kd,  n0, N - 1, 0, B0, 1, t);
  stage_half64(B, Kd,  n0, N - 1, 1, B1, 0, t);
  stage_half64(B, Kd,  n0, N - 1, 1, B1, 1, t);
  VMW4;
  __builtin_amdgcn_s_barrier();

  for (int i = 0; i < nIter; ++i) {
    const int k1 = 2 * i + 1;
    int k2 = 2 * i + 2; if (k2 > kIters - 1) k2 = kIters - 1;
    int k3 = 2 * i + 3; if (k3 > kIters - 1) k3 = kIters - 1;
    PHASE(0, 0, 0, 1, 1, stage_half64(A, lda, m0, M - 1, k1, A1, 0, t), ((void)0))
    PHASE(0, 0, 1, 0, 1, stage_half64(A, lda, m0, M - 1, k1, A1, 1, t), ((void)0))
    PHASE(0, 1, 1, 1, 0, stage_half64(B, Kd,  n0, N - 1, k2, B0, 0, t), ((void)0))
    PHASE(0, 1, 0, 0, 0, stage_half64(B, Kd,  n0, N - 1, k2, B0, 1, t), VMW4)
    PHASE(1, 0, 0, 1, 1, stage_half64(A, lda, m0, M - 1, k2, A0, 0, t), ((void)0))
    PHASE(1, 0, 1, 0, 1, stage_half64(A, lda, m0, M - 1, k2, A0, 1, t), ((void)0))
    PHASE(1, 1, 1, 1, 0, stage_half64(B, Kd,  n0, N - 1, k3, B1, 0, t), ((void)0))
    PHASE(1, 1, 0, 0, 0, stage_half64(B, Kd,  n0, N - 1, k3, B1, 1, t), VMW4)
  }
  asm volatile("s_waitcnt vmcnt(0)" ::: "memory");

#pragma unroll
  for (int mf = 0; mf < 4; ++mf) {
    const int rowb = m0 + wr * 64 + mf * 16 + quad * 4;
#pragma unroll
    for (int nf = 0; nf < 4; ++nf) {
      const int col = n0 + wc * 64 + nf * 16 + tq;
      if (col < N) {
        if (Cb) {
#pragma unroll
          for (int r = 0; r < 4; ++r)
            Cb[(size_t)(rowb + r) * ldc + col] = f2bf(acc[mf][nf][r]);
        } else {
#pragma unroll
          for (int r = 0; r < 4; ++r) {
            size_t idx = (size_t)(rowb + r) * N + col;
            float v = acc[mf][nf][r];
            if (residual) v += residual[idx];
            Cf[idx] = v;
          }
        }
      }
    }
  }
}

// ---------------- fused causal conv(K=4)+SiLU (LDS row-tiled) and dt=softplus ----------------
// Round 6: expf -> __expf (v_exp_f32 fast path), div -> rcp. bf16 outputs mask the ~1ulp err.
#define CONV_BC 128
#define CONV_BS 64
#define CXS 136   /* padded LDS row stride (shorts) */

__global__ __launch_bounds__(256)
void conv_dt_kernel(const unsigned short* __restrict__ proj, const float* __restrict__ cw,
                    const float* __restrict__ cb, const float* __restrict__ dtb,
                    const float* __restrict__ A_log,
                    unsigned short* __restrict__ convo, float2* __restrict__ dts) {
  const int NCB = CONV_DIM / CONV_BC;            // 34 channel-blocks
  const int NCONVB = NCB * (BS / CONV_BS);       // 2176 conv blocks
  int blk = blockIdx.x;
  int t = threadIdx.x;
  if (blk < NCONVB) {
    __shared__ unsigned short xs[67 * CXS];
    int cblk = blk % NCB;
    int rblk = blk / NCB;
    int ch0 = cblk * CONV_BC;
    int rs0 = rblk * CONV_BS;
    int s0 = rs0 & (SEQ - 1);
    const int c8 = t & 15;
    const int co = c8 * 8;
    float cwr[4][8], cbr[8];
#pragma unroll
    for (int e = 0; e < 8; e++) {
      cbr[e] = cb[ch0 + co + e];
#pragma unroll
      for (int k = 0; k < 4; k++) cwr[k][e] = cw[(ch0 + co + e) * 4 + k];
    }
    for (int i = t; i < 67 * 16; i += 256) {
      int row = i >> 4, sl = i & 15;
      short8 v;
      if (s0 == 0 && row < 3) v = (short8){0,0,0,0,0,0,0,0};
      else v = *(const short8*)&proj[(size_t)(rs0 - 3 + row) * PROJ + INTER + ch0 + sl * 8];
      *(short8*)&xs[row * CXS + sl * 8] = v;
    }
    __syncthreads();
#pragma unroll
    for (int it = 0; it < 4; ++it) {
      int r = (t >> 4) + it * 16;
      float acc[8];
#pragma unroll
      for (int e = 0; e < 8; e++) acc[e] = cbr[e];
#pragma unroll
      for (int k = 0; k < 4; k++) {
        short8 v = *(const short8*)&xs[(r + k) * CXS + co];
#pragma unroll
        for (int e = 0; e < 8; e++) acc[e] += bf2f((unsigned short)v[e]) * cwr[k][e];
      }
      short8 o;
#pragma unroll
      for (int e = 0; e < 8; e++) {
        float a = acc[e];
        o[e] = (short)f2bf(a * __builtin_amdgcn_rcpf(1.f + __expf(-a)));   // fast SiLU
      }
      *(short8*)&convo[(size_t)(rs0 + r) * CONV_DIM + ch0 + co] = o;
    }
  } else {
    int k = (blk - NCONVB) * 256 + t;
    if (k < BS * HEADS) {
      int h  = k & 63;
      int rs = k >> 6;
      float x = bf2f(proj[(size_t)rs * PROJ + INTER + CONV_DIM + h]) + dtb[h];
      float dt = (x > 20.f) ? x : log1pf(__expf(x));
      float Ah = -__expf(A_log[h]);
      dts[k] = make_float2(dt, dt * Ah);   // {dt, log-decay increment}
    }
  }
}

// ---------------- SSD chunked scan (MFMA), 8 waves: Y-path || S-path ----------------
// Round 6: all expf -> __expf. The chunk loop was libm-expf-bound (~20 precise expf
// calls/lane/chunk ~= 1000 VALU-cyc); v_exp_f32 path cuts that ~10x.
#define LCH 64
#define SR  128   /* row stride (shorts) for Cst/Bst/Sb (chunk-XOR swizzled) */
#define BR  64    /* row stride (shorts) for Btt (chunk-XOR swizzled) */
#define TST 72    /* row stride (shorts) for xtT/Msh */
#define SWZ(r,c) ((((c) ^ ((r) & 7)) << 3))

__global__ __launch_bounds__(512)
void ssd_scan_kernel(const unsigned short* __restrict__ convo, const float2* __restrict__ dts,
                     unsigned short* __restrict__ yp) {
  __shared__ unsigned short Cst[64 * SR];
  __shared__ unsigned short Bst[64 * SR];
  __shared__ unsigned short Btt[128 * BR];    // B transposed [n][j], built post-S1
  __shared__ unsigned short xtT[32 * TST];    // x transposed [p_local][j]
  __shared__ unsigned short Msh[64 * TST];    // masked decay-weighted G [i][j]
  __shared__ unsigned short Sb[2][32 * SR];   // state bf16 [p_local][n], double-buffered
  __shared__ float dtaL[64], dtvL[64];

  const int ph = blockIdx.x & 1;
  const int h  = (blockIdx.x >> 1) & 63;
  const int b  = blockIdx.x >> 7;
  const int t  = threadIdx.x;
  const int wv = t >> 6;
  const int lane = t & 63;
  const int quad = lane >> 4;
  const int tq   = lane & 15;
  const size_t row0 = (size_t)b * SEQ;
  const int xcol = h * 64 + ph * 32;

  for (int i = t; i < 32 * SR; i += 512) Sb[0][i] = 0;

  f32x4 s_acc[4];
#pragma unroll
  for (int c = 0; c < 4; c++) s_acc[c] = (f32x4){0.f, 0.f, 0.f, 0.f};
  const int pt  = wv & 1;
  const int ntb = ((wv >> 1) & 1) * 4;

  // ---- prefetch chunk 0 into registers (T14) ----
  short8 vb_r[2], vc_r[2]; ushort4 vx_r; float2 dv_r = make_float2(0.f, 0.f);
  {
#pragma unroll
    for (int it = 0; it < 2; ++it) {
      int id = t + 512 * it;
      int row = id >> 4, cc = id & 15;
      size_t g = (row0 + row) * CONV_DIM + INTER;
      vb_r[it] = *(const short8*)&convo[g + cc * 8];
      vc_r[it] = *(const short8*)&convo[g + STATE + cc * 8];
    }
    int row = t >> 3, c = t & 7;
    vx_r = *(const ushort4*)&convo[(row0 + row) * CONV_DIM + xcol + c * 4];
    if (t < 64) dv_r = dts[((row0 + t) << 6) + h];
  }

  int pp = 0;
  for (int c0 = 0; c0 < SEQ; c0 += LCH, pp ^= 1) {
    __syncthreads();   // B0: prior chunk's compute reads done before restaging
    // ---- write register-staged B, C (swizzled), x^T, dt into LDS ----
#pragma unroll
    for (int it = 0; it < 2; ++it) {
      int id = t + 512 * it;
      int row = id >> 4, cc = id & 15;
      *(short8*)&Bst[row * SR + SWZ(row, cc)] = vb_r[it];
      *(short8*)&Cst[row * SR + SWZ(row, cc)] = vc_r[it];
    }
    {
      int row = t >> 3, c = t & 7;
      xtT[(c * 4 + 0) * TST + row] = vx_r.x;
      xtT[(c * 4 + 1) * TST + row] = vx_r.y;
      xtT[(c * 4 + 2) * TST + row] = vx_r.z;
      xtT[(c * 4 + 3) * TST + row] = vx_r.w;
    }
    if (t < 64) { dtvL[t] = dv_r.x; dtaL[t] = dv_r.y; }
    __syncthreads();   // S1: staging visible

    // ---- cooperative Btt build from Bst (conflict-free under SWZ) ----
#pragma unroll
    for (int bi = 0; bi < 2; ++bi) {
      int q = t + 512 * bi;
      int n = q & 127, jc = q >> 7;          // 128 n-rows x 8 j-chunks
      short8 o;
#pragma unroll
      for (int s = 0; s < 8; ++s)
        o[s] = (short)Bst[(jc * 8 + s) * SR + SWZ(jc * 8 + s, n >> 3) + (n & 7)];
      *(short8*)&Btt[n * BR + SWZ(n, jc)] = o;
    }

    // ---- issue next chunk's global loads (latency hides under compute) ----
    if (c0 + LCH < SEQ) {
#pragma unroll
      for (int it = 0; it < 2; ++it) {
        int id = t + 512 * it;
        int row = id >> 4, cc = id & 15;
        size_t g = (row0 + c0 + LCH + row) * CONV_DIM + INTER;
        vb_r[it] = *(const short8*)&convo[g + cc * 8];
        vc_r[it] = *(const short8*)&convo[g + STATE + cc * 8];
      }
      int row = t >> 3, c = t & 7;
      vx_r = *(const ushort4*)&convo[(row0 + c0 + LCH + row) * CONV_DIM + xcol + c * 4];
      if (t < 64) dv_r = dts[((row0 + c0 + LCH + t) << 6) + h];
    }

    // ---- per-wave cumulative log-decay scan ----
    float v = dtaL[lane];
#pragma unroll
    for (int off = 1; off < 64; off <<= 1) {
      float u = __shfl_up(v, off);
      if (lane >= off) v += u;
    }
    float tot = __shfl(v, 63);

    __syncthreads();   // S2: Btt visible

    if (wv < 4) {
      // ================= Y-path =================
      short8 afC[4];
#pragma unroll
      for (int kt = 0; kt < 4; kt++)
        afC[kt] = *(const short8*)&Cst[(16 * wv + tq) * SR + SWZ(16 * wv + tq, kt * 4 + quad)];
      f32x4 g_acc[4];
#pragma unroll
      for (int nj = 0; nj < 4; nj++) g_acc[nj] = (f32x4){0.f, 0.f, 0.f, 0.f};
#pragma unroll
      for (int kt = 0; kt < 4; kt++) {
#pragma unroll
        for (int nj = 0; nj < 4; nj++) {
          short8 bfr = *(const short8*)&Bst[(16 * nj + tq) * SR + SWZ(16 * nj + tq, kt * 4 + quad)];
          g_acc[nj] = __builtin_amdgcn_mfma_f32_16x16x32_bf16(afC[kt], bfr, g_acc[nj], 0, 0, 0);
        }
      }
      float ci[4], pex[4];
#pragma unroll
      for (int r = 0; r < 4; r++) {
        ci[r] = __shfl(v, 16 * wv + quad * 4 + r);
        pex[r] = __expf(ci[r]);
      }
#pragma unroll
      for (int nj = 0; nj < 4; nj++) {
        int j = 16 * nj + tq;
        float cj = __shfl(v, j);
        float dj = dtvL[j];
#pragma unroll
        for (int r = 0; r < 4; r++) {
          int i = 16 * wv + quad * 4 + r;
          float val = (j <= i) ? g_acc[nj][r] * __expf(ci[r] - cj) * dj : 0.f;
          Msh[i * TST + j] = f2bf(val);
        }
      }
      // Y = Pex*(C*Sb^T) + Ms*x^T
      f32x4 yac[2];
      yac[0] = (f32x4){0.f, 0.f, 0.f, 0.f};
      yac[1] = (f32x4){0.f, 0.f, 0.f, 0.f};
#pragma unroll
      for (int kt = 0; kt < 4; kt++) {
#pragma unroll
        for (int np = 0; np < 2; np++) {
          short8 bs = *(const short8*)&Sb[pp][(16 * np + tq) * SR + SWZ(16 * np + tq, kt * 4 + quad)];
          yac[np] = __builtin_amdgcn_mfma_f32_16x16x32_bf16(afC[kt], bs, yac[np], 0, 0, 0);
        }
      }
#pragma unroll
      for (int np = 0; np < 2; np++)
#pragma unroll
        for (int r = 0; r < 4; r++) yac[np][r] *= pex[r];
#pragma unroll
      for (int kt2 = 0; kt2 < 2; kt2++) {
        short8 am = *(const short8*)&Msh[(16 * wv + tq) * TST + kt2 * 32 + quad * 8];
#pragma unroll
        for (int np = 0; np < 2; np++) {
          short8 bx = *(const short8*)&xtT[(16 * np + tq) * TST + kt2 * 32 + quad * 8];
          yac[np] = __builtin_amdgcn_mfma_f32_16x16x32_bf16(am, bx, yac[np], 0, 0, 0);
        }
      }
#pragma unroll
      for (int np = 0; np < 2; np++) {
#pragma unroll
        for (int r = 0; r < 4; r++) {
          int i = 16 * wv + quad * 4 + r;
          int p = ph * 32 + 16 * np + tq;
          yp[(row0 + c0 + i) * INTER + h * 64 + p] = f2bf(yac[np][r]);
        }
      }
    } else {
      // ================= S-path =================
      float ptot = __expf(tot);
      short8 ax[2];
#pragma unroll
      for (int kt2 = 0; kt2 < 2; kt2++) {
        short8 xv = *(const short8*)&xtT[(16 * pt + tq) * TST + kt2 * 32 + quad * 8];
#pragma unroll
        for (int e = 0; e < 8; e++) {
          int j = kt2 * 32 + quad * 8 + e;
          float cj = __shfl(v, j);
          float wj = __expf(tot - cj) * dtvL[j];
          ax[kt2][e] = (short)f2bf(bf2f((unsigned short)xv[e]) * wj);
        }
      }
#pragma unroll
      for (int c = 0; c < 4; c++)
#pragma unroll
        for (int r = 0; r < 4; r++) s_acc[c][r] *= ptot;
#pragma unroll
      for (int kt2 = 0; kt2 < 2; kt2++) {
#pragma unroll
        for (int c = 0; c < 4; c++) {
          short8 bb = *(const short8*)&Btt[(16 * (ntb + c) + tq) * BR + SWZ(16 * (ntb + c) + tq, kt2 * 4 + quad)];
          s_acc[c] = __builtin_amdgcn_mfma_f32_16x16x32_bf16(ax[kt2], bb, s_acc[c], 0, 0, 0);
        }
      }
#pragma unroll
      for (int c = 0; c < 4; c++)
#pragma unroll
        for (int r = 0; r < 4; r++) {
          int p = 16 * pt + quad * 4 + r;
          int n = 16 * (ntb + c) + tq;
          Sb[pp ^ 1][p * SR + SWZ(p, n >> 3) + (n & 7)] = f2bf(s_acc[c][r]);
        }
    }
    // next chunk's B0 protects Sb[pp^1] writes before Y reads them
  }
}

// ---------------- y = yp + D*x; gated RMSNorm -> bf16 (registers, no LDS buf) ----------------
// Round 6: fast SiLU (__expf + rcp).
__global__ __launch_bounds__(256)
void gated_norm_kernel(const unsigned short* __restrict__ yp,
                       const unsigned short* __restrict__ convo, const unsigned short* __restrict__ proj,
                       const float* __restrict__ Dv, const float* __restrict__ gnw,
                       unsigned short* __restrict__ yn) {
  int row = blockIdx.x;
  int t = threadIdx.x;
  __shared__ float red[4];
  __shared__ float scl;
  size_t yo = (size_t)row * INTER;
  size_t co = (size_t)row * CONV_DIM;
  size_t po = (size_t)row * PROJ;
  float vv[16];
  float ss = 0.f;
#pragma unroll
  for (int c = 0; c < 4; c++) {
    int i = t * 4 + c * 1024;
    ushort4 y0 = *(const ushort4*)&yp[yo + i];
    ushort4 xs = *(const ushort4*)&convo[co + i];
    ushort4 g  = *(const ushort4*)&proj[po + i];
    float Dh = Dv[i >> 6];
    float yv[4] = { bf2f(y0.x) + Dh * bf2f(xs.x),
                    bf2f(y0.y) + Dh * bf2f(xs.y),
                    bf2f(y0.z) + Dh * bf2f(xs.z),
                    bf2f(y0.w) + Dh * bf2f(xs.w) };
    float gv[4] = { bf2f(g.x), bf2f(g.y), bf2f(g.z), bf2f(g.w) };
#pragma unroll
    for (int k = 0; k < 4; k++) {
      float val = yv[k] * (gv[k] * __builtin_amdgcn_rcpf(1.f + __expf(-gv[k])));
      vv[c * 4 + k] = val;
      ss += val * val;
    }
  }
  for (int o = 32; o > 0; o >>= 1) ss += __shfl_down(ss, o);
  if ((t & 63) == 0) red[t >> 6] = ss;
  __syncthreads();
  if (t == 0) scl = rsqrtf((red[0]+red[1]+red[2]+red[3]) / (float)INTER + EPS);
  __syncthreads();
  float s = scl;
#pragma unroll
  for (int c = 0; c < 4; c++) {
    int i = t * 4 + c * 1024;
    ushort4 o;
    o.x = f2bf(vv[c*4+0] * s * gnw[i + 0]);
    o.y = f2bf(vv[c*4+1] * s * gnw[i + 1]);
    o.z = f2bf(vv[c*4+2] * s * gnw[i + 2]);
    o.w = f2bf(vv[c*4+3] * s * gnw[i + 3]);
    *(ushort4*)&yn[po + i] = o;
  }
}

// ---------------- launch ----------------
extern "C" void kernel_launch(void* const* d_in, const int* in_sizes, int n_in,
                              void* d_out, int out_size, void* d_ws, size_t ws_size,
                              hipStream_t stream) {
  const float* hidden  = (const float*)d_in[0];
  const float* norm_w  = (const float*)d_in[1];
  const float* w1      = (const float*)d_in[2];
  const float* convw   = (const float*)d_in[3];
  const float* convb   = (const float*)d_in[4];
  const float* dt_bias = (const float*)d_in[5];
  const float* A_log   = (const float*)d_in[6];
  const float* Dv      = (const float*)d_in[7];
  const float* gnw     = (const float*)d_in[8];
  const float* w2      = (const float*)d_in[9];
  float* out = (float*)d_out;

  char* ws = (char*)d_ws;
  size_t off = 0;
  auto alloc = [&](size_t bytes) {
    void* p = ws + off;
    off += (bytes + 255) & ~(size_t)255;
    return p;
  };
  unsigned short* XN  = (unsigned short*)alloc((size_t)BS * HID * 2);      // 16.8 MB
  unsigned short* W1B = (unsigned short*)alloc((size_t)PROJ * HID * 2);    // 34.9 MB
  unsigned short* W2B = (unsigned short*)alloc((size_t)HID * INTER * 2);   // 16.8 MB
  unsigned short* PRJ = (unsigned short*)alloc((size_t)BS * PROJ * 2);     // 69.7 MB
  unsigned short* CVO = (unsigned short*)alloc((size_t)BS * CONV_DIM * 2); // 35.7 MB
  float2*         DTS = (float2*)alloc((size_t)BS * HEADS * 8);            //  2.1 MB
  unsigned short* YP  = XN;                    // overlay: XN+W1B dead after GEMM1
  unsigned short* YN  = PRJ + YN_COL;          // in-row overlay, stride PROJ
  if (off > ws_size) return;
  (void)in_sizes; (void)n_in; (void)out_size;

  int n1 = PROJ * HID / 4;
  cast_bf16_kernel<<<(n1 + 255) / 256, 256, 0, stream>>>((const float4*)w1, (ushort4*)W1B, n1);
  int n2 = HID * INTER / 4;
  cast_bf16_kernel<<<(n2 + 255) / 256, 256, 0, stream>>>((const float4*)w2, (ushort4*)W2B, n2);

  rmsnorm_in_kernel<<<BS, 256, 0, stream>>>(hidden, norm_w, XN);

  // GEMM1: [4096 x 8512] = XN[4096 x 2048] * W1B^T ; 32 x 67 = 2144 blocks
  gemm128_kernel<<<dim3((BS / 128) * ((PROJ + 127) / 128)), 256, 0, stream>>>(
      XN, HID, W1B, nullptr, PRJ, PROJ, BS, PROJ, HID, nullptr);

  conv_dt_kernel<<<(CONV_DIM / CONV_BC) * (BS / CONV_BS) + (BS * HEADS) / 256, 256, 0, stream>>>(
      PRJ, convw, convb, dt_bias, A_log, CVO, DTS);

  ssd_scan_kernel<<<256, 512, 0, stream>>>(CVO, DTS, YP);

  gated_norm_kernel<<<BS, 256, 0, stream>>>(YP, CVO, PRJ, Dv, gnw, YN);

  // GEMM2: [4096 x 2048] = YN[4096 x 4096] * W2B^T + residual ; 32 x 16 = 512 blocks
  gemm128_kernel<<<dim3((BS / 128) * (HID / 128)), 256, 0, stream>>>(
      YN, PROJ, W2B, out, nullptr, HID, BS, HID, INTER, hidden);
}

// Round 7
// 520.148 us; speedup vs baseline: 1.4447x; 1.0230x over previous
//
#include <hip/hip_runtime.h>
#include <math.h>

#define HID      2048
#define STATE    128
#define HEADS    64
#define HEADDIM  64
#define INTER    4096
#define CONV_DIM 4352
#define PROJ     8512
#define NBATCH   2
#define SEQ      2048
#define BS       (NBATCH*SEQ)   /* 4096 token rows */
#define EPS      1e-5f
#define YN_COL   4160           /* YN lives in PRJ cols [4160, 8256) after conv/dt are dead */

typedef __attribute__((ext_vector_type(8))) short short8;
typedef __attribute__((ext_vector_type(4))) float f32x4;

__device__ inline unsigned short f2bf(float f) {
  union { float f; unsigned int u; } v; v.f = f;
  unsigned int r = v.u + 0x7fffu + ((v.u >> 16) & 1u);   // RNE
  return (unsigned short)(r >> 16);
}
__device__ inline float bf2f(unsigned short b) {
  union { unsigned int u; float f; } v; v.u = ((unsigned int)b) << 16;
  return v.f;
}

// ---------------- f32 -> bf16 cast (weights) ----------------
__global__ __launch_bounds__(256)
void cast_bf16_kernel(const float4* __restrict__ src, ushort4* __restrict__ dst, int n4) {
  int i = blockIdx.x * 256 + threadIdx.x;
  if (i >= n4) return;
  float4 v = src[i];
  ushort4 o;
  o.x = f2bf(v.x); o.y = f2bf(v.y); o.z = f2bf(v.z); o.w = f2bf(v.w);
  dst[i] = o;
}

// ---------------- input RMSNorm -> bf16 ----------------
__global__ __launch_bounds__(256)
void rmsnorm_in_kernel(const float* __restrict__ x, const float* __restrict__ w,
                       unsigned short* __restrict__ xn) {
  int row = blockIdx.x;
  int t = threadIdx.x;
  const float* xr = x + (size_t)row * HID;
  float4 a = ((const float4*)xr)[t];
  float4 b = ((const float4*)xr)[t + 256];
  float ss = a.x*a.x + a.y*a.y + a.z*a.z + a.w*a.w
           + b.x*b.x + b.y*b.y + b.z*b.z + b.w*b.w;
  for (int o = 32; o > 0; o >>= 1) ss += __shfl_down(ss, o);
  __shared__ float red[4];
  __shared__ float scl;
  if ((t & 63) == 0) red[t >> 6] = ss;
  __syncthreads();
  if (t == 0) scl = rsqrtf((red[0]+red[1]+red[2]+red[3]) / (float)HID + EPS);
  __syncthreads();
  float s = scl;
  float4 w0 = ((const float4*)w)[t];
  float4 w1 = ((const float4*)w)[t + 256];
  ushort4 o0, o1;
  o0.x = f2bf(a.x*s*w0.x); o0.y = f2bf(a.y*s*w0.y); o0.z = f2bf(a.z*s*w0.z); o0.w = f2bf(a.w*s*w0.w);
  o1.x = f2bf(b.x*s*w1.x); o1.y = f2bf(b.y*s*w1.y); o1.z = f2bf(b.z*s*w1.z); o1.w = f2bf(b.w*s*w1.w);
  ushort4* dst = (ushort4*)(xn + (size_t)row * HID);
  dst[t] = o0;
  dst[t + 256] = o1;
}

// ---------------- 128x128 / BK=64 / 4-wave / 8-phase / 2-blocks-per-CU bf16 BT-GEMM ----
// (unchanged from round 5 — at the 64x64-per-wave LDS-BW structural ceiling)

__device__ __forceinline__ void stage_half64(const unsigned short* __restrict__ G, int ld,
                                             int row0, int rmax, int kt,
                                             unsigned short* lbase, int half, int t) {
  const int w = t >> 6;
#pragma unroll
  for (int it = 0; it < 2; ++it) {
    int id = it * 256 + t;          // chunk id 0..511
    int rl = id >> 3;               // local row 0..63
    int sl = id & 7;                // 16B slot 0..7
    int grow = row0 + half * 64 + rl;
    if (grow > rmax) grow = rmax;
    const unsigned short* g = G + (size_t)grow * ld + kt * 64 + ((sl ^ (rl & 7)) << 3);
    unsigned short* l = lbase + half * (64 * 64) + (it * 256 + w * 64) * 8;  // wave-uniform
    __builtin_amdgcn_global_load_lds((const __attribute__((address_space(1))) void*)g,
                                     (__attribute__((address_space(3))) void*)l, 16, 0, 0);
  }
}

#define VMW4 asm volatile("s_waitcnt vmcnt(4)" ::: "memory")

#define PHASE(BUF, MH, NH, RA, RB, STG, VMW_)                                        \
  {                                                                                  \
    const unsigned short* bufA = lds + (BUF)*16384;                                  \
    const unsigned short* bufB = lds + (BUF)*16384 + 8192;                           \
    if (RA) {                                                                        \
      _Pragma("unroll")                                                              \
      for (int ml = 0; ml < 2; ++ml) {                                               \
        _Pragma("unroll")                                                            \
        for (int kk = 0; kk < 2; ++kk) {                                             \
          const int r = wr*64 + (MH)*32 + ml*16 + tq;                                \
          aR[ml][kk] = *(const short8*)(bufA + r*64 + (((kk<<2)|quad)^(r&7))*8);     \
        }                                                                            \
      }                                                                              \
    }                                                                                \
    if (RB) {                                                                        \
      _Pragma("unroll")                                                              \
      for (int nl = 0; nl < 2; ++nl) {                                               \
        _Pragma("unroll")                                                            \
        for (int kk = 0; kk < 2; ++kk) {                                             \
          const int r = wc*64 + (NH)*32 + nl*16 + tq;                                \
          bR[NH][nl][kk] = *(const short8*)(bufB + r*64 + (((kk<<2)|quad)^(r&7))*8); \
        }                                                                            \
      }                                                                              \
    }                                                                                \
    STG;                                                                             \
    __builtin_amdgcn_s_barrier();                                                    \
    asm volatile("s_waitcnt lgkmcnt(0)" ::: "memory");                               \
    __builtin_amdgcn_sched_barrier(0);                                               \
    __builtin_amdgcn_s_setprio(1);                                                   \
    _Pragma("unroll")                                                                \
    for (int ml = 0; ml < 2; ++ml) {                                                 \
      _Pragma("unroll")                                                              \
      for (int nl = 0; nl < 2; ++nl) {                                               \
        _Pragma("unroll")                                                            \
        for (int kk = 0; kk < 2; ++kk) {                                             \
          acc[(MH)*2+ml][(NH)*2+nl] = __builtin_amdgcn_mfma_f32_16x16x32_bf16(       \
              aR[ml][kk], bR[NH][nl][kk], acc[(MH)*2+ml][(NH)*2+nl], 0, 0, 0);       \
        }                                                                            \
      }                                                                              \
    }                                                                                \
    __builtin_amdgcn_s_setprio(0);                                                   \
    VMW_;                                                                            \
    __builtin_amdgcn_s_barrier();                                                    \
  }

__global__ __launch_bounds__(256, 2)
void gemm128_kernel(const unsigned short* __restrict__ A, int lda,
                    const unsigned short* __restrict__ B,
                    float* __restrict__ Cf, unsigned short* __restrict__ Cb, int ldc,
                    int M, int N, int Kd, const float* __restrict__ residual) {
  __shared__ unsigned short lds[32768];   // 64 KiB: [buf][A(128x64)|B(128x64)] x2
  const int t = threadIdx.x;
  const int lane = t & 63;
  const int quad = lane >> 4;
  const int tq = lane & 15;
  const int w = t >> 6;
  const int wr = w >> 1;    // 2 M-waves x 2 N-waves; per-wave C = 64x64
  const int wc = w & 1;

  const int Mtiles = M >> 7;
  const int Ntiles = (N + 127) >> 7;
  const int nwg = (int)gridDim.x;
  const int cpx = nwg >> 3;
  const int bid = (int)blockIdx.x;
  const int sw = (bid & 7) * cpx + (bid >> 3);
  const int NBfull = Ntiles & ~7;
  int m0, n0;
  if (sw < Mtiles * NBfull) {
    int brick = sw >> 6;               // 64 tiles per 8x8 brick
    int inner = sw & 63;
    int bm = brick % (Mtiles >> 3);
    int bn = brick / (Mtiles >> 3);
    m0 = (bm * 8 + (inner & 7)) << 7;
    n0 = (bn * 8 + (inner >> 3)) << 7;
  } else {
    int r = sw - Mtiles * NBfull;
    m0 = (r % Mtiles) << 7;
    n0 = (NBfull + r / Mtiles) << 7;
  }

  f32x4 acc[4][4];
#pragma unroll
  for (int i = 0; i < 4; ++i)
#pragma unroll
    for (int j = 0; j < 4; ++j) acc[i][j] = (f32x4){0.f, 0.f, 0.f, 0.f};

  short8 aR[2][2];
  short8 bR[2][2][2];

  unsigned short* A0 = lds;
  unsigned short* B0 = lds + 8192;
  unsigned short* A1 = lds + 16384;
  unsigned short* B1 = lds + 24576;

  const int kIters = Kd >> 6;
  const int nIter  = kIters >> 1;

  stage_half64(A, lda, m0, M - 1, 0, A0, 0, t);
  stage_half64(A, lda, m0, M - 1, 0, A0, 1, t);
  stage_half64(B, Kd,  n0, N - 1, 0, B0, 0, t);
  stage_half64(B, Kd,  n0, N - 1, 0, B0, 1, t);
  stage_half64(B, Kd,  n0, N - 1, 1, B1, 0, t);
  stage_half64(B, Kd,  n0, N - 1, 1, B1, 1, t);
  VMW4;
  __builtin_amdgcn_s_barrier();

  for (int i = 0; i < nIter; ++i) {
    const int k1 = 2 * i + 1;
    int k2 = 2 * i + 2; if (k2 > kIters - 1) k2 = kIters - 1;
    int k3 = 2 * i + 3; if (k3 > kIters - 1) k3 = kIters - 1;
    PHASE(0, 0, 0, 1, 1, stage_half64(A, lda, m0, M - 1, k1, A1, 0, t), ((void)0))
    PHASE(0, 0, 1, 0, 1, stage_half64(A, lda, m0, M - 1, k1, A1, 1, t), ((void)0))
    PHASE(0, 1, 1, 1, 0, stage_half64(B, Kd,  n0, N - 1, k2, B0, 0, t), ((void)0))
    PHASE(0, 1, 0, 0, 0, stage_half64(B, Kd,  n0, N - 1, k2, B0, 1, t), VMW4)
    PHASE(1, 0, 0, 1, 1, stage_half64(A, lda, m0, M - 1, k2, A0, 0, t), ((void)0))
    PHASE(1, 0, 1, 0, 1, stage_half64(A, lda, m0, M - 1, k2, A0, 1, t), ((void)0))
    PHASE(1, 1, 1, 1, 0, stage_half64(B, Kd,  n0, N - 1, k3, B1, 0, t), ((void)0))
    PHASE(1, 1, 0, 0, 0, stage_half64(B, Kd,  n0, N - 1, k3, B1, 1, t), VMW4)
  }
  asm volatile("s_waitcnt vmcnt(0)" ::: "memory");

#pragma unroll
  for (int mf = 0; mf < 4; ++mf) {
    const int rowb = m0 + wr * 64 + mf * 16 + quad * 4;
#pragma unroll
    for (int nf = 0; nf < 4; ++nf) {
      const int col = n0 + wc * 64 + nf * 16 + tq;
      if (col < N) {
        if (Cb) {
#pragma unroll
          for (int r = 0; r < 4; ++r)
            Cb[(size_t)(rowb + r) * ldc + col] = f2bf(acc[mf][nf][r]);
        } else {
#pragma unroll
          for (int r = 0; r < 4; ++r) {
            size_t idx = (size_t)(rowb + r) * N + col;
            float v = acc[mf][nf][r];
            if (residual) v += residual[idx];
            Cf[idx] = v;
          }
        }
      }
    }
  }
}

// ---------------- fused causal conv(K=4)+SiLU (LDS row-tiled) and dt=softplus ----------------
#define CONV_BC 128
#define CONV_BS 64
#define CXS 136   /* padded LDS row stride (shorts) */

__global__ __launch_bounds__(256)
void conv_dt_kernel(const unsigned short* __restrict__ proj, const float* __restrict__ cw,
                    const float* __restrict__ cb, const float* __restrict__ dtb,
                    const float* __restrict__ A_log,
                    unsigned short* __restrict__ convo, float2* __restrict__ dts) {
  const int NCB = CONV_DIM / CONV_BC;            // 34 channel-blocks
  const int NCONVB = NCB * (BS / CONV_BS);       // 2176 conv blocks
  int blk = blockIdx.x;
  int t = threadIdx.x;
  if (blk < NCONVB) {
    __shared__ unsigned short xs[67 * CXS];
    int cblk = blk % NCB;
    int rblk = blk / NCB;
    int ch0 = cblk * CONV_BC;
    int rs0 = rblk * CONV_BS;
    int s0 = rs0 & (SEQ - 1);
    const int c8 = t & 15;
    const int co = c8 * 8;
    float cwr[4][8], cbr[8];
#pragma unroll
    for (int e = 0; e < 8; e++) {
      cbr[e] = cb[ch0 + co + e];
#pragma unroll
      for (int k = 0; k < 4; k++) cwr[k][e] = cw[(ch0 + co + e) * 4 + k];
    }
    for (int i = t; i < 67 * 16; i += 256) {
      int row = i >> 4, sl = i & 15;
      short8 v;
      if (s0 == 0 && row < 3) v = (short8){0,0,0,0,0,0,0,0};
      else v = *(const short8*)&proj[(size_t)(rs0 - 3 + row) * PROJ + INTER + ch0 + sl * 8];
      *(short8*)&xs[row * CXS + sl * 8] = v;
    }
    __syncthreads();
#pragma unroll
    for (int it = 0; it < 4; ++it) {
      int r = (t >> 4) + it * 16;
      float acc[8];
#pragma unroll
      for (int e = 0; e < 8; e++) acc[e] = cbr[e];
#pragma unroll
      for (int k = 0; k < 4; k++) {
        short8 v = *(const short8*)&xs[(r + k) * CXS + co];
#pragma unroll
        for (int e = 0; e < 8; e++) acc[e] += bf2f((unsigned short)v[e]) * cwr[k][e];
      }
      short8 o;
#pragma unroll
      for (int e = 0; e < 8; e++) {
        float a = acc[e];
        o[e] = (short)f2bf(a * __builtin_amdgcn_rcpf(1.f + __expf(-a)));   // fast SiLU
      }
      *(short8*)&convo[(size_t)(rs0 + r) * CONV_DIM + ch0 + co] = o;
    }
  } else {
    int k = (blk - NCONVB) * 256 + t;
    if (k < BS * HEADS) {
      int h  = k & 63;
      int rs = k >> 6;
      float x = bf2f(proj[(size_t)rs * PROJ + INTER + CONV_DIM + h]) + dtb[h];
      float dt = (x > 20.f) ? x : log1pf(__expf(x));
      float Ah = -__expf(A_log[h]);
      dts[k] = make_float2(dt, dt * Ah);   // {dt, log-decay increment}
    }
  }
}

// ---------------- SSD chunked scan (MFMA), 8 waves: Y-path || S-path ----------------
// Round 7: in-loop barriers are raw s_barrier + lgkmcnt(0) ONLY (no vmcnt drain).
// __syncthreads was draining the T14 prefetch (~700 cyc HBM latency exposed at S2
// every chunk) and the yp stores (at B0). Global ops now stay in flight until their
// register consumers. Prefetch issue moved after S2 so it spans the compute phase.
// Arithmetic identical to round 6 -> absmax must be bit-identical.
#define LCH 64
#define SR  128   /* row stride (shorts) for Cst/Bst/Sb (chunk-XOR swizzled) */
#define BR  64    /* row stride (shorts) for Btt (chunk-XOR swizzled) */
#define TST 72    /* row stride (shorts) for xtT/Msh */
#define SWZ(r,c) ((((c) ^ ((r) & 7)) << 3))
#define LBAR do { asm volatile("s_waitcnt lgkmcnt(0)" ::: "memory"); \
                  __builtin_amdgcn_s_barrier(); } while (0)

__global__ __launch_bounds__(512)
void ssd_scan_kernel(const unsigned short* __restrict__ convo, const float2* __restrict__ dts,
                     unsigned short* __restrict__ yp) {
  __shared__ unsigned short Cst[64 * SR];
  __shared__ unsigned short Bst[64 * SR];
  __shared__ unsigned short Btt[128 * BR];    // B transposed [n][j], built post-S1
  __shared__ unsigned short xtT[32 * TST];    // x transposed [p_local][j]
  __shared__ unsigned short Msh[64 * TST];    // masked decay-weighted G [i][j]
  __shared__ unsigned short Sb[2][32 * SR];   // state bf16 [p_local][n], double-buffered
  __shared__ float dtaL[64], dtvL[64];

  const int ph = blockIdx.x & 1;
  const int h  = (blockIdx.x >> 1) & 63;
  const int b  = blockIdx.x >> 7;
  const int t  = threadIdx.x;
  const int wv = t >> 6;
  const int lane = t & 63;
  const int quad = lane >> 4;
  const int tq   = lane & 15;
  const size_t row0 = (size_t)b * SEQ;
  const int xcol = h * 64 + ph * 32;

  for (int i = t; i < 32 * SR; i += 512) Sb[0][i] = 0;

  f32x4 s_acc[4];
#pragma unroll
  for (int c = 0; c < 4; c++) s_acc[c] = (f32x4){0.f, 0.f, 0.f, 0.f};
  const int pt  = wv & 1;
  const int ntb = ((wv >> 1) & 1) * 4;

  // ---- prefetch chunk 0 into registers (T14) ----
  short8 vb_r[2], vc_r[2]; ushort4 vx_r; float2 dv_r = make_float2(0.f, 0.f);
  {
#pragma unroll
    for (int it = 0; it < 2; ++it) {
      int id = t + 512 * it;
      int row = id >> 4, cc = id & 15;
      size_t g = (row0 + row) * CONV_DIM + INTER;
      vb_r[it] = *(const short8*)&convo[g + cc * 8];
      vc_r[it] = *(const short8*)&convo[g + STATE + cc * 8];
    }
    int row = t >> 3, c = t & 7;
    vx_r = *(const ushort4*)&convo[(row0 + row) * CONV_DIM + xcol + c * 4];
    if (t < 64) dv_r = dts[((row0 + t) << 6) + h];
  }

  int pp = 0;
  for (int c0 = 0; c0 < SEQ; c0 += LCH, pp ^= 1) {
    LBAR;   // B0: prior chunk's LDS reads done before restaging (lgkm only)
    // ---- write register-staged B, C (swizzled), x^T, dt into LDS ----
    // (compiler inserts vmcnt waits for vb_r/vc_r/vx_r/dv_r here)
#pragma unroll
    for (int it = 0; it < 2; ++it) {
      int id = t + 512 * it;
      int row = id >> 4, cc = id & 15;
      *(short8*)&Bst[row * SR + SWZ(row, cc)] = vb_r[it];
      *(short8*)&Cst[row * SR + SWZ(row, cc)] = vc_r[it];
    }
    {
      int row = t >> 3, c = t & 7;
      xtT[(c * 4 + 0) * TST + row] = vx_r.x;
      xtT[(c * 4 + 1) * TST + row] = vx_r.y;
      xtT[(c * 4 + 2) * TST + row] = vx_r.z;
      xtT[(c * 4 + 3) * TST + row] = vx_r.w;
    }
    if (t < 64) { dtvL[t] = dv_r.x; dtaL[t] = dv_r.y; }
    LBAR;   // S1: staging visible

    // ---- cooperative Btt build from Bst (conflict-free under SWZ) ----
#pragma unroll
    for (int bi = 0; bi < 2; ++bi) {
      int q = t + 512 * bi;
      int n = q & 127, jc = q >> 7;          // 128 n-rows x 8 j-chunks
      short8 o;
#pragma unroll
      for (int s = 0; s < 8; ++s)
        o[s] = (short)Bst[(jc * 8 + s) * SR + SWZ(jc * 8 + s, n >> 3) + (n & 7)];
      *(short8*)&Btt[n * BR + SWZ(n, jc)] = o;
    }

    // ---- per-wave cumulative log-decay scan ----
    float v = dtaL[lane];
#pragma unroll
    for (int off = 1; off < 64; off <<= 1) {
      float u = __shfl_up(v, off);
      if (lane >= off) v += u;
    }
    float tot = __shfl(v, 63);

    LBAR;   // S2: Btt visible (lgkm only — no global drain)

    // ---- issue next chunk's global loads AFTER the last barrier:
    //      their latency now spans the whole compute phase ----
    if (c0 + LCH < SEQ) {
#pragma unroll
      for (int it = 0; it < 2; ++it) {
        int id = t + 512 * it;
        int row = id >> 4, cc = id & 15;
        size_t g = (row0 + c0 + LCH + row) * CONV_DIM + INTER;
        vb_r[it] = *(const short8*)&convo[g + cc * 8];
        vc_r[it] = *(const short8*)&convo[g + STATE + cc * 8];
      }
      int row = t >> 3, c = t & 7;
      vx_r = *(const ushort4*)&convo[(row0 + c0 + LCH + row) * CONV_DIM + xcol + c * 4];
      if (t < 64) dv_r = dts[((row0 + c0 + LCH + t) << 6) + h];
    }

    if (wv < 4) {
      // ================= Y-path =================
      short8 afC[4];
#pragma unroll
      for (int kt = 0; kt < 4; kt++)
        afC[kt] = *(const short8*)&Cst[(16 * wv + tq) * SR + SWZ(16 * wv + tq, kt * 4 + quad)];
      f32x4 g_acc[4];
#pragma unroll
      for (int nj = 0; nj < 4; nj++) g_acc[nj] = (f32x4){0.f, 0.f, 0.f, 0.f};
#pragma unroll
      for (int kt = 0; kt < 4; kt++) {
#pragma unroll
        for (int nj = 0; nj < 4; nj++) {
          short8 bfr = *(const short8*)&Bst[(16 * nj + tq) * SR + SWZ(16 * nj + tq, kt * 4 + quad)];
          g_acc[nj] = __builtin_amdgcn_mfma_f32_16x16x32_bf16(afC[kt], bfr, g_acc[nj], 0, 0, 0);
        }
      }
      float ci[4], pex[4];
#pragma unroll
      for (int r = 0; r < 4; r++) {
        ci[r] = __shfl(v, 16 * wv + quad * 4 + r);
        pex[r] = __expf(ci[r]);
      }
#pragma unroll
      for (int nj = 0; nj < 4; nj++) {
        int j = 16 * nj + tq;
        float cj = __shfl(v, j);
        float dj = dtvL[j];
#pragma unroll
        for (int r = 0; r < 4; r++) {
          int i = 16 * wv + quad * 4 + r;
          float val = (j <= i) ? g_acc[nj][r] * __expf(ci[r] - cj) * dj : 0.f;
          Msh[i * TST + j] = f2bf(val);
        }
      }
      // Y = Pex*(C*Sb^T) + Ms*x^T
      f32x4 yac[2];
      yac[0] = (f32x4){0.f, 0.f, 0.f, 0.f};
      yac[1] = (f32x4){0.f, 0.f, 0.f, 0.f};
#pragma unroll
      for (int kt = 0; kt < 4; kt++) {
#pragma unroll
        for (int np = 0; np < 2; np++) {
          short8 bs = *(const short8*)&Sb[pp][(16 * np + tq) * SR + SWZ(16 * np + tq, kt * 4 + quad)];
          yac[np] = __builtin_amdgcn_mfma_f32_16x16x32_bf16(afC[kt], bs, yac[np], 0, 0, 0);
        }
      }
#pragma unroll
      for (int np = 0; np < 2; np++)
#pragma unroll
        for (int r = 0; r < 4; r++) yac[np][r] *= pex[r];
#pragma unroll
      for (int kt2 = 0; kt2 < 2; kt2++) {
        short8 am = *(const short8*)&Msh[(16 * wv + tq) * TST + kt2 * 32 + quad * 8];
#pragma unroll
        for (int np = 0; np < 2; np++) {
          short8 bx = *(const short8*)&xtT[(16 * np + tq) * TST + kt2 * 32 + quad * 8];
          yac[np] = __builtin_amdgcn_mfma_f32_16x16x32_bf16(am, bx, yac[np], 0, 0, 0);
        }
      }
      // yp stores float across later barriers (no in-loop vmcnt drain)
#pragma unroll
      for (int np = 0; np < 2; np++) {
#pragma unroll
        for (int r = 0; r < 4; r++) {
          int i = 16 * wv + quad * 4 + r;
          int p = ph * 32 + 16 * np + tq;
          yp[(row0 + c0 + i) * INTER + h * 64 + p] = f2bf(yac[np][r]);
        }
      }
    } else {
      // ================= S-path =================
      float ptot = __expf(tot);
      short8 ax[2];
#pragma unroll
      for (int kt2 = 0; kt2 < 2; kt2++) {
        short8 xv = *(const short8*)&xtT[(16 * pt + tq) * TST + kt2 * 32 + quad * 8];
#pragma unroll
        for (int e = 0; e < 8; e++) {
          int j = kt2 * 32 + quad * 8 + e;
          float cj = __shfl(v, j);
          float wj = __expf(tot - cj) * dtvL[j];
          ax[kt2][e] = (short)f2bf(bf2f((unsigned short)xv[e]) * wj);
        }
      }
#pragma unroll
      for (int c = 0; c < 4; c++)
#pragma unroll
        for (int r = 0; r < 4; r++) s_acc[c][r] *= ptot;
#pragma unroll
      for (int kt2 = 0; kt2 < 2; kt2++) {
#pragma unroll
        for (int c = 0; c < 4; c++) {
          short8 bb = *(const short8*)&Btt[(16 * (ntb + c) + tq) * BR + SWZ(16 * (ntb + c) + tq, kt2 * 4 + quad)];
          s_acc[c] = __builtin_amdgcn_mfma_f32_16x16x32_bf16(ax[kt2], bb, s_acc[c], 0, 0, 0);
        }
      }
#pragma unroll
      for (int c = 0; c < 4; c++)
#pragma unroll
        for (int r = 0; r < 4; r++) {
          int p = 16 * pt + quad * 4 + r;
          int n = 16 * (ntb + c) + tq;
          Sb[pp ^ 1][p * SR + SWZ(p, n >> 3) + (n & 7)] = f2bf(s_acc[c][r]);
        }
    }
    // next chunk's B0 (lgkm barrier) protects Sb[pp^1] writes before Y reads them
  }
}

// ---------------- y = yp + D*x; gated RMSNorm -> bf16 (registers, no LDS buf) ----------------
__global__ __launch_bounds__(256)
void gated_norm_kernel(const unsigned short* __restrict__ yp,
                       const unsigned short* __restrict__ convo, const unsigned short* __restrict__ proj,
                       const float* __restrict__ Dv, const float* __restrict__ gnw,
                       unsigned short* __restrict__ yn) {
  int row = blockIdx.x;
  int t = threadIdx.x;
  __shared__ float red[4];
  __shared__ float scl;
  size_t yo = (size_t)row * INTER;
  size_t co = (size_t)row * CONV_DIM;
  size_t po = (size_t)row * PROJ;
  float vv[16];
  float ss = 0.f;
#pragma unroll
  for (int c = 0; c < 4; c++) {
    int i = t * 4 + c * 1024;
    ushort4 y0 = *(const ushort4*)&yp[yo + i];
    ushort4 xs = *(const ushort4*)&convo[co + i];
    ushort4 g  = *(const ushort4*)&proj[po + i];
    float Dh = Dv[i >> 6];
    float yv[4] = { bf2f(y0.x) + Dh * bf2f(xs.x),
                    bf2f(y0.y) + Dh * bf2f(xs.y),
                    bf2f(y0.z) + Dh * bf2f(xs.z),
                    bf2f(y0.w) + Dh * bf2f(xs.w) };
    float gv[4] = { bf2f(g.x), bf2f(g.y), bf2f(g.z), bf2f(g.w) };
#pragma unroll
    for (int k = 0; k < 4; k++) {
      float val = yv[k] * (gv[k] * __builtin_amdgcn_rcpf(1.f + __expf(-gv[k])));
      vv[c * 4 + k] = val;
      ss += val * val;
    }
  }
  for (int o = 32; o > 0; o >>= 1) ss += __shfl_down(ss, o);
  if ((t & 63) == 0) red[t >> 6] = ss;
  __syncthreads();
  if (t == 0) scl = rsqrtf((red[0]+red[1]+red[2]+red[3]) / (float)INTER + EPS);
  __syncthreads();
  float s = scl;
#pragma unroll
  for (int c = 0; c < 4; c++) {
    int i = t * 4 + c * 1024;
    ushort4 o;
    o.x = f2bf(vv[c*4+0] * s * gnw[i + 0]);
    o.y = f2bf(vv[c*4+1] * s * gnw[i + 1]);
    o.z = f2bf(vv[c*4+2] * s * gnw[i + 2]);
    o.w = f2bf(vv[c*4+3] * s * gnw[i + 3]);
    *(ushort4*)&yn[po + i] = o;
  }
}

// ---------------- launch ----------------
extern "C" void kernel_launch(void* const* d_in, const int* in_sizes, int n_in,
                              void* d_out, int out_size, void* d_ws, size_t ws_size,
                              hipStream_t stream) {
  const float* hidden  = (const float*)d_in[0];
  const float* norm_w  = (const float*)d_in[1];
  const float* w1      = (const float*)d_in[2];
  const float* convw   = (const float*)d_in[3];
  const float* convb   = (const float*)d_in[4];
  const float* dt_bias = (const float*)d_in[5];
  const float* A_log   = (const float*)d_in[6];
  const float* Dv      = (const float*)d_in[7];
  const float* gnw     = (const float*)d_in[8];
  const float* w2      = (const float*)d_in[9];
  float* out = (float*)d_out;

  char* ws = (char*)d_ws;
  size_t off = 0;
  auto alloc = [&](size_t bytes) {
    void* p = ws + off;
    off += (bytes + 255) & ~(size_t)255;
    return p;
  };
  unsigned short* XN  = (unsigned short*)alloc((size_t)BS * HID * 2);      // 16.8 MB
  unsigned short* W1B = (unsigned short*)alloc((size_t)PROJ * HID * 2);    // 34.9 MB
  unsigned short* W2B = (unsigned short*)alloc((size_t)HID * INTER * 2);   // 16.8 MB
  unsigned short* PRJ = (unsigned short*)alloc((size_t)BS * PROJ * 2);     // 69.7 MB
  unsigned short* CVO = (unsigned short*)alloc((size_t)BS * CONV_DIM * 2); // 35.7 MB
  float2*         DTS = (float2*)alloc((size_t)BS * HEADS * 8);            //  2.1 MB
  unsigned short* YP  = XN;                    // overlay: XN+W1B dead after GEMM1
  unsigned short* YN  = PRJ + YN_COL;          // in-row overlay, stride PROJ
  if (off > ws_size) return;
  (void)in_sizes; (void)n_in; (void)out_size;

  int n1 = PROJ * HID / 4;
  cast_bf16_kernel<<<(n1 + 255) / 256, 256, 0, stream>>>((const float4*)w1, (ushort4*)W1B, n1);
  int n2 = HID * INTER / 4;
  cast_bf16_kernel<<<(n2 + 255) / 256, 256, 0, stream>>>((const float4*)w2, (ushort4*)W2B, n2);

  rmsnorm_in_kernel<<<BS, 256, 0, stream>>>(hidden, norm_w, XN);

  // GEMM1: [4096 x 8512] = XN[4096 x 2048] * W1B^T ; 32 x 67 = 2144 blocks
  gemm128_kernel<<<dim3((BS / 128) * ((PROJ + 127) / 128)), 256, 0, stream>>>(
      XN, HID, W1B, nullptr, PRJ, PROJ, BS, PROJ, HID, nullptr);

  conv_dt_kernel<<<(CONV_DIM / CONV_BC) * (BS / CONV_BS) + (BS * HEADS) / 256, 256, 0, stream>>>(
      PRJ, convw, convb, dt_bias, A_log, CVO, DTS);

  ssd_scan_kernel<<<256, 512, 0, stream>>>(CVO, DTS, YP);

  gated_norm_kernel<<<BS, 256, 0, stream>>>(YP, CVO, PRJ, Dv, gnw, YN);

  // GEMM2: [4096 x 2048] = YN[4096 x 4096] * W2B^T + residual ; 32 x 16 = 512 blocks
  gemm128_kernel<<<dim3((BS / 128) * (HID / 128)), 256, 0, stream>>>(
      YN, PROJ, W2B, out, nullptr, HID, BS, HID, INTER, hidden);
}